// Round 3
// baseline (2480.586 us; speedup 1.0000x reference)
//
#include <hip/hip_runtime.h>

#define FDIM 32
#define BSHIFT 8
#define BMASK 255

// ================= new 2-level counting sort =================

// bucket histogram: bcount[col>>8] += 1
__global__ void k_bhist(const int* __restrict__ col, unsigned int* __restrict__ bcount, int E) {
    int i = blockIdx.x * blockDim.x + threadIdx.x;
    if (i < E) atomicAdd(&bcount[col[i] >> BSHIFT], 1u);
}

// exclusive scan of bucket counts (1 WG, chunked) -> bptr, bcur
__global__ void k_bscan(const unsigned int* __restrict__ bcount, int* __restrict__ bptr,
                        int* __restrict__ bcur, int NBUK, int E) {
    __shared__ unsigned int s[256];
    __shared__ unsigned int carry;
    int t = threadIdx.x;
    if (t == 0) carry = 0u;
    __syncthreads();
    for (int base = 0; base < NBUK; base += 256) {
        int i = base + t;
        unsigned int v = (i < NBUK) ? bcount[i] : 0u;
        s[t] = v;
        __syncthreads();
        for (int off = 1; off < 256; off <<= 1) {
            unsigned int u = (t >= off) ? s[t - off] : 0u;
            __syncthreads();
            s[t] += u;
            __syncthreads();
        }
        unsigned int c = carry;
        if (i < NBUK) { int ex = (int)(c + s[t] - v); bptr[i] = ex; bcur[i] = ex; }
        __syncthreads();
        if (t == 255) carry = c + s[255];
        __syncthreads();
    }
    if (t == 0) bptr[NBUK] = E;
}

// bin edges into bucket regions, packed: (col & 255) << 24 | row   (needs N < 2^24)
__global__ void k_bin(const int* __restrict__ row, const int* __restrict__ col,
                      int* bcur, unsigned int* __restrict__ pairs, int E) {
    int e = blockIdx.x * blockDim.x + threadIdx.x;
    if (e < E) {
        int c = col[e];
        int pos = atomicAdd(&bcur[c >> BSHIFT], 1);
        pairs[pos] = ((unsigned int)(c & BMASK) << 24) | (unsigned int)row[e];
    }
}

// per-bucket fine counting sort in LDS; also emits row_ptr[c] and count[c]
__global__ void k_csort(const unsigned int* __restrict__ pairs, const int* __restrict__ bptr,
                        int* __restrict__ row_ptr, unsigned int* __restrict__ count,
                        int* __restrict__ sorted_row, int N) {
    __shared__ unsigned int lh[256];   // local histogram / scan buffer
    __shared__ int lofs[256];          // local cursors
    int b = blockIdx.x;
    int t = threadIdx.x;
    int c0 = b << BSHIFT;
    int s = bptr[b], e = bptr[b + 1];
    lh[t] = 0u;
    __syncthreads();
    for (int j = s + t; j < e; j += 256)
        atomicAdd(&lh[pairs[j] >> 24], 1u);
    __syncthreads();
    unsigned int v = lh[t];
    // inclusive scan (Hillis-Steele)
    for (int off = 1; off < 256; off <<= 1) {
        unsigned int u = (t >= off) ? lh[t - off] : 0u;
        __syncthreads();
        lh[t] += u;
        __syncthreads();
    }
    int excl = s + (int)(lh[t] - v);
    if (c0 + t < N) {
        row_ptr[c0 + t] = excl;
        count[c0 + t] = v;
    }
    lofs[t] = excl;
    __syncthreads();
    for (int j = s + t; j < e; j += 256) {
        unsigned int u = pairs[j];
        int pos = atomicAdd(&lofs[u >> 24], 1);
        sorted_row[pos] = (int)(u & 0x00FFFFFFu);
    }
}

// ================= legacy fallback kernels (R1/R0 proven) =================

__global__ void k_hist(const int* __restrict__ col, unsigned int* __restrict__ count, int E) {
    int i = blockIdx.x * blockDim.x + threadIdx.x;
    if (i < E) atomicAdd(&count[col[i]], 1u);
}

__global__ void k_scan1(const unsigned int* __restrict__ count, unsigned int* __restrict__ bsum, int N) {
    __shared__ unsigned int s[256];
    int i = blockIdx.x * 256 + threadIdx.x;
    s[threadIdx.x] = (i < N) ? count[i] : 0u;
    __syncthreads();
    for (int off = 128; off > 0; off >>= 1) {
        if (threadIdx.x < off) s[threadIdx.x] += s[threadIdx.x + off];
        __syncthreads();
    }
    if (threadIdx.x == 0) bsum[blockIdx.x] = s[0];
}

__global__ void k_scan2(unsigned int* bsum, int NB) {
    __shared__ unsigned int s[256];
    __shared__ unsigned int carry;
    int t = threadIdx.x;
    if (t == 0) carry = 0u;
    __syncthreads();
    for (int base = 0; base < NB; base += 256) {
        int i = base + t;
        unsigned int v = (i < NB) ? bsum[i] : 0u;
        s[t] = v;
        __syncthreads();
        for (int off = 1; off < 256; off <<= 1) {
            unsigned int u = (t >= off) ? s[t - off] : 0u;
            __syncthreads();
            s[t] += u;
            __syncthreads();
        }
        unsigned int c = carry;
        if (i < NB) bsum[i] = c + s[t] - v;
        __syncthreads();
        if (t == 255) carry = c + s[255];
        __syncthreads();
    }
}

__global__ void k_scan3(const unsigned int* __restrict__ count, const unsigned int* __restrict__ bsum,
                        int* __restrict__ row_ptr, int* __restrict__ cursor, int N) {
    __shared__ unsigned int s[256];
    int t = threadIdx.x;
    int i = blockIdx.x * 256 + t;
    unsigned int v = (i < N) ? count[i] : 0u;
    s[t] = v;
    __syncthreads();
    for (int off = 1; off < 256; off <<= 1) {
        unsigned int u = (t >= off) ? s[t - off] : 0u;
        __syncthreads();
        s[t] += u;
        __syncthreads();
    }
    if (i < N) {
        int start = (int)(bsum[blockIdx.x] + s[t] - v);
        row_ptr[i] = start;
        cursor[i] = start;
    }
}

__global__ void k_permute(const int* __restrict__ row, const int* __restrict__ col,
                          int* cursor, int* __restrict__ sorted_row, int E) {
    int e = blockIdx.x * blockDim.x + threadIdx.x;
    if (e < E) {
        int c = col[e];
        int pos = atomicAdd(&cursor[c], 1);
        sorted_row[pos] = row[e];
    }
}

__global__ void k_scatter(const int* __restrict__ row, const int* __restrict__ col,
                          const float* __restrict__ g, float* acc, int total) {
    int idx = blockIdx.x * blockDim.x + threadIdx.x;
    if (idx >= total) return;
    int e = idx >> 5, f = idx & 31;
    atomicAdd(&acc[col[e] * FDIM + f], g[row[e] * FDIM + f]);
}

// ================= dense layers / aggregation / pool =================

__global__ void k_l1(const float* __restrict__ x, const float* __restrict__ W1,
                     const unsigned int* __restrict__ count, float* __restrict__ dinv,
                     float* __restrict__ g, float* acc, int N) {
    int idx = blockIdx.x * blockDim.x + threadIdx.x;
    int i = idx >> 5, f = idx & 31;
    if (i >= N) return;
    float dv = rsqrtf((float)count[i] + 1.0f);
    if (f == 0) dinv[i] = dv;
    float v = fmaf(x[2 * i], W1[f], x[2 * i + 1] * W1[FDIM + f]);
    float gg = dv * v;
    g[idx] = gg;
    if (acc) acc[idx] = gg;
}

__global__ void k_agg(const int* __restrict__ row_ptr, const unsigned int* __restrict__ count,
                      const int* __restrict__ sorted_row, const float* __restrict__ g,
                      float* __restrict__ out, int N) {
    int t = threadIdx.x;
    int i = blockIdx.x * 8 + (t >> 5), f = t & 31;
    if (i >= N) return;
    int s = row_ptr[i];
    int e = s + (int)count[i];
    float acc = g[i * FDIM + f];
    int j = s;
    for (; j + 4 <= e; j += 4) {
        int r0 = sorted_row[j], r1 = sorted_row[j + 1], r2 = sorted_row[j + 2], r3 = sorted_row[j + 3];
        float a0 = g[r0 * FDIM + f], a1 = g[r1 * FDIM + f];
        float a2 = g[r2 * FDIM + f], a3 = g[r3 * FDIM + f];
        acc += a0; acc += a1; acc += a2; acc += a3;
    }
    for (; j < e; ++j) acc += g[sorted_row[j] * FDIM + f];
    out[i * FDIM + f] = acc;
}

__global__ void k_l2(const float* __restrict__ dinv, const float* agg1,
                     const float* __restrict__ b1, const float* __restrict__ W2,
                     float* __restrict__ g2, float* acc2, int N) {
    __shared__ float sW[FDIM * FDIM];
    __shared__ float sh[8][FDIM];
    int t = threadIdx.x;
    for (int k = t; k < FDIM * FDIM; k += 256) sW[k] = W2[k];
    int i = blockIdx.x * 8 + (t >> 5), f = t & 31;
    float o = 0.0f, dv = 0.0f;
    if (i < N) {
        dv = dinv[i];
        o = fmaxf(fmaf(dv, agg1[i * FDIM + f], b1[f]), 0.0f);
    }
    sh[t >> 5][f] = o;
    __syncthreads();
    if (i < N) {
        float s = 0.0f;
        #pragma unroll
        for (int k = 0; k < FDIM; ++k) s = fmaf(sh[t >> 5][k], sW[k * FDIM + f], s);
        float gg = dv * s;
        g2[i * FDIM + f] = gg;
        if (acc2) acc2[i * FDIM + f] = gg;
    }
}

// pool with segmented pre-reduction (batch is sorted -> few distinct per WG)
__global__ void k_pool(const float* __restrict__ dinv, const float* __restrict__ acc,
                       const float* __restrict__ b2, const int* __restrict__ batch,
                       float* __restrict__ pool, float* __restrict__ cnt, int N) {
    __shared__ float sh[8][FDIM];
    __shared__ int sb[8];
    int t = threadIdx.x;
    int n = t >> 5, f = t & 31;
    int i = blockIdx.x * 8 + n;
    float h = 0.0f;
    int b = -1;
    if (i < N) {
        h = fmaf(dinv[i], acc[i * FDIM + f], b2[f]);
        b = batch[i];
    }
    sh[n][f] = h;
    if (f == 0) sb[n] = b;
    __syncthreads();
    if (b >= 0 && (n == 0 || sb[n - 1] != b)) {   // segment leader
        float sum = h;
        int m = n + 1;
        for (; m < 8 && sb[m] == b; ++m) sum += sh[m][f];
        atomicAdd(&pool[b * FDIM + f], sum);
        if (f == 0) atomicAdd(&cnt[b], (float)(m - n));
    }
}

__global__ void k_out(const float* __restrict__ pool, const float* __restrict__ cnt,
                      float* __restrict__ out, int total) {
    int idx = blockIdx.x * blockDim.x + threadIdx.x;
    if (idx >= total) return;
    out[idx] = pool[idx] / fmaxf(cnt[idx >> 5], 1.0f);
}

extern "C" void kernel_launch(void* const* d_in, const int* in_sizes, int n_in,
                              void* d_out, int out_size, void* d_ws, size_t ws_size,
                              hipStream_t stream) {
    const float* x   = (const float*)d_in[0];
    const int*   ei  = (const int*)d_in[1];
    const int* batch = (const int*)d_in[2];
    const float* W1  = (const float*)d_in[4];
    const float* b1  = (const float*)d_in[5];
    const float* W2  = (const float*)d_in[6];
    const float* b2  = (const float*)d_in[7];
    float* out = (float*)d_out;

    int N = in_sizes[0] / 2;
    int E = in_sizes[1] / 2;
    int G = out_size / FDIM;

    const int* row = ei;
    const int* col = ei + E;

    int nt = N * FDIM;
    int NB = (N + 255) / 256;
    int NBUK = (N + BMASK) >> BSHIFT;

    // new-path workspace (elements):
    size_t elemsNew = (size_t)NBUK      // bcount
                    + (size_t)NBUK + 1  // bptr
                    + (size_t)NBUK      // bcur
                    + (size_t)N         // count
                    + (size_t)N         // row_ptr
                    + (size_t)E         // pairs
                    + (size_t)E         // sorted_row
                    + (size_t)N         // dinv
                    + 64ull * N         // bufG + bufA
                    + 33ull * G;        // pool + cnt
    size_t elemsCSR = 68ull * (size_t)N + (size_t)E + 1024 + 33ull * (size_t)G;

    if (ws_size >= elemsNew * 4 && N < (1 << 24)) {
        unsigned int* bcount = (unsigned int*)d_ws;            // NBUK
        int* bptr            = (int*)(bcount + NBUK);          // NBUK+1
        int* bcur            = bptr + NBUK + 1;                // NBUK
        unsigned int* count  = (unsigned int*)(bcur + NBUK);   // N
        int* row_ptr         = (int*)(count + N);              // N
        unsigned int* pairs  = (unsigned int*)(row_ptr + N);   // E
        int* sorted_row      = (int*)(pairs + E);              // E
        float* dinv          = (float*)(sorted_row + E);       // N
        float* bufG          = dinv + N;                       // 32N
        float* bufA          = bufG + (size_t)N * FDIM;        // 32N
        float* pool          = bufA + (size_t)N * FDIM;        // 32G
        float* cnt           = pool + (size_t)G * FDIM;        // G

        hipMemsetAsync(bcount, 0, (size_t)NBUK * 4, stream);
        hipMemsetAsync(pool, 0, (size_t)(G * FDIM + G) * 4, stream);

        k_bhist<<<(E + 255) / 256, 256, 0, stream>>>(col, bcount, E);
        k_bscan<<<1, 256, 0, stream>>>(bcount, bptr, bcur, NBUK, E);
        k_bin<<<(E + 255) / 256, 256, 0, stream>>>(row, col, bcur, pairs, E);
        k_csort<<<NBUK, 256, 0, stream>>>(pairs, bptr, row_ptr, count, sorted_row, N);

        k_l1<<<(nt + 255) / 256, 256, 0, stream>>>(x, W1, count, dinv, bufG, nullptr, N);
        k_agg<<<(N + 7) / 8, 256, 0, stream>>>(row_ptr, count, sorted_row, bufG, bufA, N);
        k_l2<<<(N + 7) / 8, 256, 0, stream>>>(dinv, bufA, b1, W2, bufG, nullptr, N);
        k_agg<<<(N + 7) / 8, 256, 0, stream>>>(row_ptr, count, sorted_row, bufG, bufA, N);
        k_pool<<<(N + 7) / 8, 256, 0, stream>>>(dinv, bufA, b2, batch, pool, cnt, N);
        k_out<<<(out_size + 255) / 256, 256, 0, stream>>>(pool, cnt, out, out_size);
    } else if (ws_size >= elemsCSR * 4) {
        // R1-proven CSR path
        unsigned int* count  = (unsigned int*)d_ws;
        int* row_ptr         = (int*)(count + N);
        int* cursor          = row_ptr + N;
        unsigned int* bsum   = (unsigned int*)(cursor + N);
        int* sorted_row      = (int*)(bsum + 1024);
        float* dinv          = (float*)(sorted_row + E);
        float* bufG          = dinv + N;
        float* bufA          = bufG + (size_t)N * FDIM;
        float* pool          = bufA + (size_t)N * FDIM;
        float* cnt           = pool + (size_t)G * FDIM;

        hipMemsetAsync(count, 0, (size_t)N * 4, stream);
        hipMemsetAsync(pool, 0, (size_t)(G * FDIM + G) * 4, stream);

        k_hist<<<(E + 255) / 256, 256, 0, stream>>>(col, count, E);
        k_scan1<<<NB, 256, 0, stream>>>(count, bsum, N);
        k_scan2<<<1, 256, 0, stream>>>(bsum, NB);
        k_scan3<<<NB, 256, 0, stream>>>(count, bsum, row_ptr, cursor, N);
        k_permute<<<(E + 255) / 256, 256, 0, stream>>>(row, col, cursor, sorted_row, E);

        k_l1<<<(nt + 255) / 256, 256, 0, stream>>>(x, W1, count, dinv, bufG, nullptr, N);
        k_agg<<<(N + 7) / 8, 256, 0, stream>>>(row_ptr, count, sorted_row, bufG, bufA, N);
        k_l2<<<(N + 7) / 8, 256, 0, stream>>>(dinv, bufA, b1, W2, bufG, nullptr, N);
        k_agg<<<(N + 7) / 8, 256, 0, stream>>>(row_ptr, count, sorted_row, bufG, bufA, N);
        k_pool<<<(N + 7) / 8, 256, 0, stream>>>(dinv, bufA, b2, batch, pool, cnt, N);
        k_out<<<(out_size + 255) / 256, 256, 0, stream>>>(pool, cnt, out, out_size);
    } else {
        // R0-proven atomic-scatter path
        unsigned int* count = (unsigned int*)d_ws;
        float* dinv         = (float*)(count + N);
        float* bufG         = dinv + N;
        float* bufA         = bufG + (size_t)N * FDIM;
        float* pool         = bufA + (size_t)N * FDIM;
        float* cnt          = pool + (size_t)G * FDIM;

        hipMemsetAsync(count, 0, (size_t)N * 4, stream);
        hipMemsetAsync(pool, 0, (size_t)(G * FDIM + G) * 4, stream);

        k_hist<<<(E + 255) / 256, 256, 0, stream>>>(col, count, E);
        k_l1<<<(nt + 255) / 256, 256, 0, stream>>>(x, W1, count, dinv, bufG, bufA, N);
        int ts = E * FDIM;
        k_scatter<<<(ts + 255) / 256, 256, 0, stream>>>(row, col, bufG, bufA, ts);
        k_l2<<<(N + 7) / 8, 256, 0, stream>>>(dinv, bufA, b1, W2, bufG, bufA, N);
        k_scatter<<<(ts + 255) / 256, 256, 0, stream>>>(row, col, bufG, bufA, ts);
        k_pool<<<(N + 7) / 8, 256, 0, stream>>>(dinv, bufA, b2, batch, pool, cnt, N);
        k_out<<<(out_size + 255) / 256, 256, 0, stream>>>(pool, cnt, out, out_size);
    }
}

// Round 4
// 576.604 us; speedup vs baseline: 4.3021x; 4.3021x over previous
//
#include <hip/hip_runtime.h>

#define FDIM 32
#define BSHIFT 5                 // 32 cols per bucket
#define CPB (1 << BSHIFT)
#define CMASK (CPB - 1)
#define PAD 16                   // cursor stride: 16 u32 = 64B (one cacheline)

// ---------- padded-atomic bucket histogram ----------
__global__ void k_bhist(const int* __restrict__ col, unsigned int* __restrict__ bcount, int E) {
    int i = blockIdx.x * blockDim.x + threadIdx.x;
    if (i < E) atomicAdd(&bcount[(col[i] >> BSHIFT) * PAD], 1u);
}

// ---------- exclusive scan of bucket counts (1 WG, chunked) -> bptr, padded bcur ----------
__global__ void k_bscan(const unsigned int* __restrict__ bcount, int* __restrict__ bptr,
                        int* __restrict__ bcur, int NBUK, int E) {
    __shared__ unsigned int s[256];
    __shared__ unsigned int carry;
    int t = threadIdx.x;
    if (t == 0) carry = 0u;
    __syncthreads();
    for (int base = 0; base < NBUK; base += 256) {
        int i = base + t;
        unsigned int v = (i < NBUK) ? bcount[i * PAD] : 0u;
        s[t] = v;
        __syncthreads();
        for (int off = 1; off < 256; off <<= 1) {
            unsigned int u = (t >= off) ? s[t - off] : 0u;
            __syncthreads();
            s[t] += u;
            __syncthreads();
        }
        unsigned int c = carry;
        if (i < NBUK) { int ex = (int)(c + s[t] - v); bptr[i] = ex; bcur[i * PAD] = ex; }
        __syncthreads();
        if (t == 255) carry = c + s[255];
        __syncthreads();
    }
    if (t == 0) bptr[NBUK] = E;
}

// ---------- bin edges into bucket regions, packed: (col&31)<<27 | row  (needs N < 2^27) ----------
__global__ void k_bin(const int* __restrict__ row, const int* __restrict__ col,
                      int* bcur, unsigned int* __restrict__ pairs, int E) {
    int e = blockIdx.x * blockDim.x + threadIdx.x;
    if (e < E) {
        int c = col[e];
        int pos = atomicAdd(&bcur[(c >> BSHIFT) * PAD], 1);
        pairs[pos] = ((unsigned int)(c & CMASK) << 27) | (unsigned int)row[e];
    }
}

// ---------- per-bucket fine counting sort in LDS; emits row_ptr[c], count[c], sorted_row ----------
__global__ void k_csort(const unsigned int* __restrict__ pairs, const int* __restrict__ bptr,
                        int* __restrict__ row_ptr, unsigned int* __restrict__ count,
                        int* __restrict__ sorted_row, int N) {
    __shared__ unsigned int lh[CPB];
    __shared__ int lofs[CPB];
    int b = blockIdx.x;
    int t = threadIdx.x;
    int c0 = b << BSHIFT;
    int s = bptr[b], e = bptr[b + 1];
    if (t < CPB) lh[t] = 0u;
    __syncthreads();
    for (int j = s + t; j < e; j += 256)
        atomicAdd(&lh[pairs[j] >> 27], 1u);
    __syncthreads();
    unsigned int v = (t < CPB) ? lh[t] : 0u;
    // inclusive Hillis-Steele over CPB entries (full-block syncs)
    for (int off = 1; off < CPB; off <<= 1) {
        unsigned int u = (t < CPB && t >= off) ? lh[t - off] : 0u;
        __syncthreads();
        if (t < CPB) lh[t] += u;
        __syncthreads();
    }
    if (t < CPB) {
        int excl = s + (int)(lh[t] - v);
        if (c0 + t < N) {
            row_ptr[c0 + t] = excl;
            count[c0 + t] = v;
        }
        lofs[t] = excl;
    }
    __syncthreads();
    for (int j = s + t; j < e; j += 256) {
        unsigned int u = pairs[j];
        int pos = atomicAdd(&lofs[u >> 27], 1);
        sorted_row[pos] = (int)(u & 0x07FFFFFFu);
    }
}

// ================= legacy fallback kernels (R1/R0 proven) =================

__global__ void k_hist(const int* __restrict__ col, unsigned int* __restrict__ count, int E) {
    int i = blockIdx.x * blockDim.x + threadIdx.x;
    if (i < E) atomicAdd(&count[col[i]], 1u);
}

__global__ void k_scan1(const unsigned int* __restrict__ count, unsigned int* __restrict__ bsum, int N) {
    __shared__ unsigned int s[256];
    int i = blockIdx.x * 256 + threadIdx.x;
    s[threadIdx.x] = (i < N) ? count[i] : 0u;
    __syncthreads();
    for (int off = 128; off > 0; off >>= 1) {
        if (threadIdx.x < off) s[threadIdx.x] += s[threadIdx.x + off];
        __syncthreads();
    }
    if (threadIdx.x == 0) bsum[blockIdx.x] = s[0];
}

__global__ void k_scan2(unsigned int* bsum, int NB) {
    __shared__ unsigned int s[256];
    __shared__ unsigned int carry;
    int t = threadIdx.x;
    if (t == 0) carry = 0u;
    __syncthreads();
    for (int base = 0; base < NB; base += 256) {
        int i = base + t;
        unsigned int v = (i < NB) ? bsum[i] : 0u;
        s[t] = v;
        __syncthreads();
        for (int off = 1; off < 256; off <<= 1) {
            unsigned int u = (t >= off) ? s[t - off] : 0u;
            __syncthreads();
            s[t] += u;
            __syncthreads();
        }
        unsigned int c = carry;
        if (i < NB) bsum[i] = c + s[t] - v;
        __syncthreads();
        if (t == 255) carry = c + s[255];
        __syncthreads();
    }
}

__global__ void k_scan3(const unsigned int* __restrict__ count, const unsigned int* __restrict__ bsum,
                        int* __restrict__ row_ptr, int* __restrict__ cursor, int N) {
    __shared__ unsigned int s[256];
    int t = threadIdx.x;
    int i = blockIdx.x * 256 + t;
    unsigned int v = (i < N) ? count[i] : 0u;
    s[t] = v;
    __syncthreads();
    for (int off = 1; off < 256; off <<= 1) {
        unsigned int u = (t >= off) ? s[t - off] : 0u;
        __syncthreads();
        s[t] += u;
        __syncthreads();
    }
    if (i < N) {
        int start = (int)(bsum[blockIdx.x] + s[t] - v);
        row_ptr[i] = start;
        cursor[i] = start;
    }
}

__global__ void k_permute(const int* __restrict__ row, const int* __restrict__ col,
                          int* cursor, int* __restrict__ sorted_row, int E) {
    int e = blockIdx.x * blockDim.x + threadIdx.x;
    if (e < E) {
        int c = col[e];
        int pos = atomicAdd(&cursor[c], 1);
        sorted_row[pos] = row[e];
    }
}

__global__ void k_scatter(const int* __restrict__ row, const int* __restrict__ col,
                          const float* __restrict__ g, float* acc, int total) {
    int idx = blockIdx.x * blockDim.x + threadIdx.x;
    if (idx >= total) return;
    int e = idx >> 5, f = idx & 31;
    atomicAdd(&acc[col[e] * FDIM + f], g[row[e] * FDIM + f]);
}

// ================= dense layers / aggregation / pool =================

__global__ void k_l1(const float* __restrict__ x, const float* __restrict__ W1,
                     const unsigned int* __restrict__ count, float* __restrict__ dinv,
                     float* __restrict__ g, float* acc, int N) {
    int idx = blockIdx.x * blockDim.x + threadIdx.x;
    int i = idx >> 5, f = idx & 31;
    if (i >= N) return;
    float dv = rsqrtf((float)count[i] + 1.0f);
    if (f == 0) dinv[i] = dv;
    float v = fmaf(x[2 * i], W1[f], x[2 * i + 1] * W1[FDIM + f]);
    float gg = dv * v;
    g[idx] = gg;
    if (acc) acc[idx] = gg;
}

__global__ void k_agg(const int* __restrict__ row_ptr, const unsigned int* __restrict__ count,
                      const int* __restrict__ sorted_row, const float* __restrict__ g,
                      float* __restrict__ out, int N) {
    int t = threadIdx.x;
    int i = blockIdx.x * 8 + (t >> 5), f = t & 31;
    if (i >= N) return;
    int s = row_ptr[i];
    int e = s + (int)count[i];
    float acc = g[i * FDIM + f];
    int j = s;
    for (; j + 4 <= e; j += 4) {
        int r0 = sorted_row[j], r1 = sorted_row[j + 1], r2 = sorted_row[j + 2], r3 = sorted_row[j + 3];
        float a0 = g[r0 * FDIM + f], a1 = g[r1 * FDIM + f];
        float a2 = g[r2 * FDIM + f], a3 = g[r3 * FDIM + f];
        acc += a0; acc += a1; acc += a2; acc += a3;
    }
    for (; j < e; ++j) acc += g[sorted_row[j] * FDIM + f];
    out[i * FDIM + f] = acc;
}

__global__ void k_l2(const float* __restrict__ dinv, const float* agg1,
                     const float* __restrict__ b1, const float* __restrict__ W2,
                     float* __restrict__ g2, float* acc2, int N) {
    __shared__ float sW[FDIM * FDIM];
    __shared__ float sh[8][FDIM];
    int t = threadIdx.x;
    for (int k = t; k < FDIM * FDIM; k += 256) sW[k] = W2[k];
    int i = blockIdx.x * 8 + (t >> 5), f = t & 31;
    float o = 0.0f, dv = 0.0f;
    if (i < N) {
        dv = dinv[i];
        o = fmaxf(fmaf(dv, agg1[i * FDIM + f], b1[f]), 0.0f);
    }
    sh[t >> 5][f] = o;
    __syncthreads();
    if (i < N) {
        float s = 0.0f;
        #pragma unroll
        for (int k = 0; k < FDIM; ++k) s = fmaf(sh[t >> 5][k], sW[k * FDIM + f], s);
        float gg = dv * s;
        g2[i * FDIM + f] = gg;
        if (acc2) acc2[i * FDIM + f] = gg;
    }
}

__global__ void k_pool(const float* __restrict__ dinv, const float* __restrict__ acc,
                       const float* __restrict__ b2, const int* __restrict__ batch,
                       float* __restrict__ pool, float* __restrict__ cnt, int N) {
    __shared__ float sh[8][FDIM];
    __shared__ int sb[8];
    int t = threadIdx.x;
    int n = t >> 5, f = t & 31;
    int i = blockIdx.x * 8 + n;
    float h = 0.0f;
    int b = -1;
    if (i < N) {
        h = fmaf(dinv[i], acc[i * FDIM + f], b2[f]);
        b = batch[i];
    }
    sh[n][f] = h;
    if (f == 0) sb[n] = b;
    __syncthreads();
    if (b >= 0 && (n == 0 || sb[n - 1] != b)) {
        float sum = h;
        int m = n + 1;
        for (; m < 8 && sb[m] == b; ++m) sum += sh[m][f];
        atomicAdd(&pool[b * FDIM + f], sum);
        if (f == 0) atomicAdd(&cnt[b], (float)(m - n));
    }
}

__global__ void k_out(const float* __restrict__ pool, const float* __restrict__ cnt,
                      float* __restrict__ out, int total) {
    int idx = blockIdx.x * blockDim.x + threadIdx.x;
    if (idx >= total) return;
    out[idx] = pool[idx] / fmaxf(cnt[idx >> 5], 1.0f);
}

extern "C" void kernel_launch(void* const* d_in, const int* in_sizes, int n_in,
                              void* d_out, int out_size, void* d_ws, size_t ws_size,
                              hipStream_t stream) {
    const float* x   = (const float*)d_in[0];
    const int*   ei  = (const int*)d_in[1];
    const int* batch = (const int*)d_in[2];
    const float* W1  = (const float*)d_in[4];
    const float* b1  = (const float*)d_in[5];
    const float* W2  = (const float*)d_in[6];
    const float* b2  = (const float*)d_in[7];
    float* out = (float*)d_out;

    int N = in_sizes[0] / 2;
    int E = in_sizes[1] / 2;
    int G = out_size / FDIM;

    const int* row = ei;
    const int* col = ei + E;

    int nt = N * FDIM;
    int NB = (N + 255) / 256;
    int NBUK = (N + CMASK) >> BSHIFT;

    size_t un = (size_t)(E > 32 * N ? E : 32 * N);   // pairs U bufG
    size_t elemsNew = 33ull * NBUK + 1 + 3ull * N + (size_t)E + un + 32ull * (size_t)N + 33ull * G;
    size_t elemsCSR = 68ull * (size_t)N + (size_t)E + 1024 + 33ull * (size_t)G;

    if (ws_size >= elemsNew * 4 && N < (1 << 27)) {
        unsigned int* bcount = (unsigned int*)d_ws;               // 16*NBUK (padded)
        int* bcur            = (int*)(bcount + (size_t)NBUK * PAD); // 16*NBUK (padded)
        int* bptr            = bcur + (size_t)NBUK * PAD;         // NBUK+1
        unsigned int* count  = (unsigned int*)(bptr + NBUK + 1);  // N
        int* row_ptr         = (int*)(count + N);                 // N
        int* sorted_row      = row_ptr + N;                       // E
        float* dinv          = (float*)(sorted_row + E);          // N
        float* unbuf         = dinv + N;                          // max(E, 32N): pairs, later bufG
        unsigned int* pairs  = (unsigned int*)unbuf;
        float* bufG          = unbuf;
        float* bufA          = unbuf + un;                        // 32N
        float* pool          = bufA + (size_t)N * FDIM;           // 32G
        float* cnt           = pool + (size_t)G * FDIM;           // G

        hipMemsetAsync(bcount, 0, (size_t)NBUK * PAD * 4, stream);
        hipMemsetAsync(pool, 0, (size_t)(G * FDIM + G) * 4, stream);

        k_bhist<<<(E + 255) / 256, 256, 0, stream>>>(col, bcount, E);
        k_bscan<<<1, 256, 0, stream>>>(bcount, bptr, bcur, NBUK, E);
        k_bin<<<(E + 255) / 256, 256, 0, stream>>>(row, col, bcur, pairs, E);
        k_csort<<<NBUK, 256, 0, stream>>>(pairs, bptr, row_ptr, count, sorted_row, N);

        k_l1<<<(nt + 255) / 256, 256, 0, stream>>>(x, W1, count, dinv, bufG, nullptr, N);
        k_agg<<<(N + 7) / 8, 256, 0, stream>>>(row_ptr, count, sorted_row, bufG, bufA, N);
        k_l2<<<(N + 7) / 8, 256, 0, stream>>>(dinv, bufA, b1, W2, bufG, nullptr, N);
        k_agg<<<(N + 7) / 8, 256, 0, stream>>>(row_ptr, count, sorted_row, bufG, bufA, N);
        k_pool<<<(N + 7) / 8, 256, 0, stream>>>(dinv, bufA, b2, batch, pool, cnt, N);
        k_out<<<(out_size + 255) / 256, 256, 0, stream>>>(pool, cnt, out, out_size);
    } else if (ws_size >= elemsCSR * 4) {
        // R1-proven CSR path
        unsigned int* count  = (unsigned int*)d_ws;
        int* row_ptr         = (int*)(count + N);
        int* cursor          = row_ptr + N;
        unsigned int* bsum   = (unsigned int*)(cursor + N);
        int* sorted_row      = (int*)(bsum + 1024);
        float* dinv          = (float*)(sorted_row + E);
        float* bufG          = dinv + N;
        float* bufA          = bufG + (size_t)N * FDIM;
        float* pool          = bufA + (size_t)N * FDIM;
        float* cnt           = pool + (size_t)G * FDIM;

        hipMemsetAsync(count, 0, (size_t)N * 4, stream);
        hipMemsetAsync(pool, 0, (size_t)(G * FDIM + G) * 4, stream);

        k_hist<<<(E + 255) / 256, 256, 0, stream>>>(col, count, E);
        k_scan1<<<NB, 256, 0, stream>>>(count, bsum, N);
        k_scan2<<<1, 256, 0, stream>>>(bsum, NB);
        k_scan3<<<NB, 256, 0, stream>>>(count, bsum, row_ptr, cursor, N);
        k_permute<<<(E + 255) / 256, 256, 0, stream>>>(row, col, cursor, sorted_row, E);

        k_l1<<<(nt + 255) / 256, 256, 0, stream>>>(x, W1, count, dinv, bufG, nullptr, N);
        k_agg<<<(N + 7) / 8, 256, 0, stream>>>(row_ptr, count, sorted_row, bufG, bufA, N);
        k_l2<<<(N + 7) / 8, 256, 0, stream>>>(dinv, bufA, b1, W2, bufG, nullptr, N);
        k_agg<<<(N + 7) / 8, 256, 0, stream>>>(row_ptr, count, sorted_row, bufG, bufA, N);
        k_pool<<<(N + 7) / 8, 256, 0, stream>>>(dinv, bufA, b2, batch, pool, cnt, N);
        k_out<<<(out_size + 255) / 256, 256, 0, stream>>>(pool, cnt, out, out_size);
    } else {
        // R0-proven atomic-scatter path
        unsigned int* count = (unsigned int*)d_ws;
        float* dinv         = (float*)(count + N);
        float* bufG         = dinv + N;
        float* bufA         = bufG + (size_t)N * FDIM;
        float* pool         = bufA + (size_t)N * FDIM;
        float* cnt          = pool + (size_t)G * FDIM;

        hipMemsetAsync(count, 0, (size_t)N * 4, stream);
        hipMemsetAsync(pool, 0, (size_t)(G * FDIM + G) * 4, stream);

        k_hist<<<(E + 255) / 256, 256, 0, stream>>>(col, count, E);
        k_l1<<<(nt + 255) / 256, 256, 0, stream>>>(x, W1, count, dinv, bufG, bufA, N);
        int ts = E * FDIM;
        k_scatter<<<(ts + 255) / 256, 256, 0, stream>>>(row, col, bufG, bufA, ts);
        k_l2<<<(N + 7) / 8, 256, 0, stream>>>(dinv, bufA, b1, W2, bufG, bufA, N);
        k_scatter<<<(ts + 255) / 256, 256, 0, stream>>>(row, col, bufG, bufA, ts);
        k_pool<<<(N + 7) / 8, 256, 0, stream>>>(dinv, bufA, b2, batch, pool, cnt, N);
        k_out<<<(out_size + 255) / 256, 256, 0, stream>>>(pool, cnt, out, out_size);
    }
}

// Round 5
// 337.498 us; speedup vs baseline: 7.3499x; 1.7085x over previous
//
#include <hip/hip_runtime.h>

#define FDIM 32
#define BSHIFT 8                 // 256 cols per bucket
#define CPB (1 << BSHIFT)
#define CMASK (CPB - 1)
#define PAD 16                   // cursor stride: 16 u32 = 64B (one cacheline)
#define MAXBUK 512
#define BHT 8192                 // bhist tile (edges per WG)
#define BNT 4096                 // binsort tile (edges per WG, 16/thread)

// ---------- tile-aggregated bucket histogram ----------
__global__ void k_bhist(const int* __restrict__ col, unsigned int* __restrict__ bcount,
                        int E, int NBUK) {
    __shared__ unsigned int lh[MAXBUK];
    int t = threadIdx.x;
    int base = blockIdx.x * BHT;
    for (int b = t; b < NBUK; b += 256) lh[b] = 0u;
    __syncthreads();
    int end = min(base + BHT, E);
    for (int e = base + t; e < end; e += 256)
        atomicAdd(&lh[col[e] >> BSHIFT], 1u);
    __syncthreads();
    for (int b = t; b < NBUK; b += 256) {
        unsigned int c = lh[b];
        if (c) atomicAdd(&bcount[b * PAD], c);
    }
}

// ---------- exclusive scan of bucket counts (1 WG) -> bptr, padded bcur ----------
__global__ void k_bscan(const unsigned int* __restrict__ bcount, int* __restrict__ bptr,
                        int* __restrict__ bcur, int NBUK, int E) {
    __shared__ unsigned int s[256];
    __shared__ unsigned int carry;
    int t = threadIdx.x;
    if (t == 0) carry = 0u;
    __syncthreads();
    for (int base = 0; base < NBUK; base += 256) {
        int i = base + t;
        unsigned int v = (i < NBUK) ? bcount[i * PAD] : 0u;
        s[t] = v;
        __syncthreads();
        for (int off = 1; off < 256; off <<= 1) {
            unsigned int u = (t >= off) ? s[t - off] : 0u;
            __syncthreads();
            s[t] += u;
            __syncthreads();
        }
        unsigned int c = carry;
        if (i < NBUK) { int ex = (int)(c + s[t] - v); bptr[i] = ex; bcur[i * PAD] = ex; }
        __syncthreads();
        if (t == 255) carry = c + s[255];
        __syncthreads();
    }
    if (t == 0) bptr[NBUK] = E;
}

// ---------- tile-aggregated binning: dense per-(tile,bucket) segments ----------
// pack: (col & 255) << 24 | row   (needs N < 2^24)
__global__ void k_binsort(const int* __restrict__ row, const int* __restrict__ col,
                          int* bcur, unsigned int* __restrict__ pairs, int E, int NBUK) {
    __shared__ unsigned int lh[MAXBUK];
    __shared__ int gbase[MAXBUK];
    int t = threadIdx.x;
    int base = blockIdx.x * BNT;
    for (int b = t; b < NBUK; b += 256) lh[b] = 0u;
    __syncthreads();
    int rk[16], rw[16], cl[16];
    #pragma unroll
    for (int k = 0; k < 16; ++k) {
        int e = base + t + k * 256;
        if (e < E) {
            int c = col[e];
            rw[k] = row[e];
            cl[k] = c;
            rk[k] = (int)atomicAdd(&lh[c >> BSHIFT], 1u);
        }
    }
    __syncthreads();
    for (int b = t; b < NBUK; b += 256) {
        unsigned int c = lh[b];
        gbase[b] = c ? atomicAdd(&bcur[b * PAD], (int)c) : 0;
    }
    __syncthreads();
    #pragma unroll
    for (int k = 0; k < 16; ++k) {
        int e = base + t + k * 256;
        if (e < E) {
            int b = cl[k] >> BSHIFT;
            pairs[gbase[b] + rk[k]] = ((unsigned int)(cl[k] & CMASK) << 24) | (unsigned int)rw[k];
        }
    }
}

// ---------- per-bucket fine counting sort in LDS (R2-verified) ----------
__global__ void k_csort(const unsigned int* __restrict__ pairs, const int* __restrict__ bptr,
                        int* __restrict__ row_ptr, unsigned int* __restrict__ count,
                        int* __restrict__ sorted_row, int N) {
    __shared__ unsigned int lh[CPB];
    __shared__ int lofs[CPB];
    int b = blockIdx.x;
    int t = threadIdx.x;
    int c0 = b << BSHIFT;
    int s = bptr[b], e = bptr[b + 1];
    lh[t] = 0u;
    __syncthreads();
    for (int j = s + t; j < e; j += 256)
        atomicAdd(&lh[pairs[j] >> 24], 1u);
    __syncthreads();
    unsigned int v = lh[t];
    for (int off = 1; off < 256; off <<= 1) {
        unsigned int u = (t >= off) ? lh[t - off] : 0u;
        __syncthreads();
        lh[t] += u;
        __syncthreads();
    }
    int excl = s + (int)(lh[t] - v);
    if (c0 + t < N) {
        row_ptr[c0 + t] = excl;
        count[c0 + t] = v;
    }
    lofs[t] = excl;
    __syncthreads();
    for (int j = s + t; j < e; j += 256) {
        unsigned int u = pairs[j];
        int pos = atomicAdd(&lofs[u >> 24], 1);
        sorted_row[pos] = (int)(u & 0x00FFFFFFu);
    }
}

// ================= legacy fallback kernels (R1-proven) =================

__global__ void k_hist(const int* __restrict__ col, unsigned int* __restrict__ count, int E) {
    int i = blockIdx.x * blockDim.x + threadIdx.x;
    if (i < E) atomicAdd(&count[col[i]], 1u);
}

__global__ void k_scan1(const unsigned int* __restrict__ count, unsigned int* __restrict__ bsum, int N) {
    __shared__ unsigned int s[256];
    int i = blockIdx.x * 256 + threadIdx.x;
    s[threadIdx.x] = (i < N) ? count[i] : 0u;
    __syncthreads();
    for (int off = 128; off > 0; off >>= 1) {
        if (threadIdx.x < off) s[threadIdx.x] += s[threadIdx.x + off];
        __syncthreads();
    }
    if (threadIdx.x == 0) bsum[blockIdx.x] = s[0];
}

__global__ void k_scan2(unsigned int* bsum, int NB) {
    __shared__ unsigned int s[256];
    __shared__ unsigned int carry;
    int t = threadIdx.x;
    if (t == 0) carry = 0u;
    __syncthreads();
    for (int base = 0; base < NB; base += 256) {
        int i = base + t;
        unsigned int v = (i < NB) ? bsum[i] : 0u;
        s[t] = v;
        __syncthreads();
        for (int off = 1; off < 256; off <<= 1) {
            unsigned int u = (t >= off) ? s[t - off] : 0u;
            __syncthreads();
            s[t] += u;
            __syncthreads();
        }
        unsigned int c = carry;
        if (i < NB) bsum[i] = c + s[t] - v;
        __syncthreads();
        if (t == 255) carry = c + s[255];
        __syncthreads();
    }
}

__global__ void k_scan3(const unsigned int* __restrict__ count, const unsigned int* __restrict__ bsum,
                        int* __restrict__ row_ptr, int* __restrict__ cursor, int N) {
    __shared__ unsigned int s[256];
    int t = threadIdx.x;
    int i = blockIdx.x * 256 + t;
    unsigned int v = (i < N) ? count[i] : 0u;
    s[t] = v;
    __syncthreads();
    for (int off = 1; off < 256; off <<= 1) {
        unsigned int u = (t >= off) ? s[t - off] : 0u;
        __syncthreads();
        s[t] += u;
        __syncthreads();
    }
    if (i < N) {
        int start = (int)(bsum[blockIdx.x] + s[t] - v);
        row_ptr[i] = start;
        cursor[i] = start;
    }
}

__global__ void k_permute(const int* __restrict__ row, const int* __restrict__ col,
                          int* cursor, int* __restrict__ sorted_row, int E) {
    int e = blockIdx.x * blockDim.x + threadIdx.x;
    if (e < E) {
        int c = col[e];
        int pos = atomicAdd(&cursor[c], 1);
        sorted_row[pos] = row[e];
    }
}

// ================= dense layers / aggregation / pool =================

__global__ void k_l1(const float* __restrict__ x, const float* __restrict__ W1,
                     const unsigned int* __restrict__ count, float* __restrict__ dinv,
                     float* __restrict__ g, float* acc, int N) {
    int idx = blockIdx.x * blockDim.x + threadIdx.x;
    int i = idx >> 5, f = idx & 31;
    if (i >= N) return;
    float dv = rsqrtf((float)count[i] + 1.0f);
    if (f == 0) dinv[i] = dv;
    float v = fmaf(x[2 * i], W1[f], x[2 * i + 1] * W1[FDIM + f]);
    float gg = dv * v;
    g[idx] = gg;
    if (acc) acc[idx] = gg;
}

__global__ void k_agg(const int* __restrict__ row_ptr, const unsigned int* __restrict__ count,
                      const int* __restrict__ sorted_row, const float* __restrict__ g,
                      float* __restrict__ out, int N) {
    int t = threadIdx.x;
    int i = blockIdx.x * 8 + (t >> 5), f = t & 31;
    if (i >= N) return;
    int s = row_ptr[i];
    int e = s + (int)count[i];
    float acc = g[i * FDIM + f];
    int j = s;
    for (; j + 4 <= e; j += 4) {
        int r0 = sorted_row[j], r1 = sorted_row[j + 1], r2 = sorted_row[j + 2], r3 = sorted_row[j + 3];
        float a0 = g[r0 * FDIM + f], a1 = g[r1 * FDIM + f];
        float a2 = g[r2 * FDIM + f], a3 = g[r3 * FDIM + f];
        acc += a0; acc += a1; acc += a2; acc += a3;
    }
    for (; j < e; ++j) acc += g[sorted_row[j] * FDIM + f];
    out[i * FDIM + f] = acc;
}

__global__ void k_l2(const float* __restrict__ dinv, const float* agg1,
                     const float* __restrict__ b1, const float* __restrict__ W2,
                     float* __restrict__ g2, float* acc2, int N) {
    __shared__ float sW[FDIM * FDIM];
    __shared__ float sh[8][FDIM];
    int t = threadIdx.x;
    for (int k = t; k < FDIM * FDIM; k += 256) sW[k] = W2[k];
    int i = blockIdx.x * 8 + (t >> 5), f = t & 31;
    float o = 0.0f, dv = 0.0f;
    if (i < N) {
        dv = dinv[i];
        o = fmaxf(fmaf(dv, agg1[i * FDIM + f], b1[f]), 0.0f);
    }
    sh[t >> 5][f] = o;
    __syncthreads();
    if (i < N) {
        float s = 0.0f;
        #pragma unroll
        for (int k = 0; k < FDIM; ++k) s = fmaf(sh[t >> 5][k], sW[k * FDIM + f], s);
        float gg = dv * s;
        g2[i * FDIM + f] = gg;
        if (acc2) acc2[i * FDIM + f] = gg;
    }
}

__global__ void k_pool(const float* __restrict__ dinv, const float* __restrict__ acc,
                       const float* __restrict__ b2, const int* __restrict__ batch,
                       float* __restrict__ pool, float* __restrict__ cnt, int N) {
    __shared__ float sh[8][FDIM];
    __shared__ int sb[8];
    int t = threadIdx.x;
    int n = t >> 5, f = t & 31;
    int i = blockIdx.x * 8 + n;
    float h = 0.0f;
    int b = -1;
    if (i < N) {
        h = fmaf(dinv[i], acc[i * FDIM + f], b2[f]);
        b = batch[i];
    }
    sh[n][f] = h;
    if (f == 0) sb[n] = b;
    __syncthreads();
    if (b >= 0 && (n == 0 || sb[n - 1] != b)) {
        float sum = h;
        int m = n + 1;
        for (; m < 8 && sb[m] == b; ++m) sum += sh[m][f];
        atomicAdd(&pool[b * FDIM + f], sum);
        if (f == 0) atomicAdd(&cnt[b], (float)(m - n));
    }
}

__global__ void k_out(const float* __restrict__ pool, const float* __restrict__ cnt,
                      float* __restrict__ out, int total) {
    int idx = blockIdx.x * blockDim.x + threadIdx.x;
    if (idx >= total) return;
    out[idx] = pool[idx] / fmaxf(cnt[idx >> 5], 1.0f);
}

extern "C" void kernel_launch(void* const* d_in, const int* in_sizes, int n_in,
                              void* d_out, int out_size, void* d_ws, size_t ws_size,
                              hipStream_t stream) {
    const float* x   = (const float*)d_in[0];
    const int*   ei  = (const int*)d_in[1];
    const int* batch = (const int*)d_in[2];
    const float* W1  = (const float*)d_in[4];
    const float* b1  = (const float*)d_in[5];
    const float* W2  = (const float*)d_in[6];
    const float* b2  = (const float*)d_in[7];
    float* out = (float*)d_out;

    int N = in_sizes[0] / 2;
    int E = in_sizes[1] / 2;
    int G = out_size / FDIM;

    const int* row = ei;
    const int* col = ei + E;

    int nt = N * FDIM;
    int NB = (N + 255) / 256;
    int NBUK = (N + CMASK) >> BSHIFT;

    size_t un = (size_t)(E > 32 * N ? E : 32 * N);   // pairs U bufG
    size_t elemsNew = 2ull * MAXBUK * PAD + (size_t)NBUK + 1 + 3ull * N + (size_t)E + un
                    + 32ull * (size_t)N + 33ull * G;
    size_t elemsCSR = 68ull * (size_t)N + (size_t)E + 1024 + 33ull * (size_t)G;

    if (ws_size >= elemsNew * 4 && N < (1 << 24) && NBUK <= MAXBUK) {
        unsigned int* bcount = (unsigned int*)d_ws;                  // MAXBUK*PAD
        int* bcur            = (int*)(bcount + (size_t)MAXBUK * PAD);// MAXBUK*PAD
        int* bptr            = bcur + (size_t)MAXBUK * PAD;          // NBUK+1
        unsigned int* count  = (unsigned int*)(bptr + NBUK + 1);     // N
        int* row_ptr         = (int*)(count + N);                    // N
        int* sorted_row      = row_ptr + N;                          // E
        float* dinv          = (float*)(sorted_row + E);             // N
        float* unbuf         = dinv + N;                             // max(E,32N)
        unsigned int* pairs  = (unsigned int*)unbuf;
        float* bufG          = unbuf;
        float* bufA          = unbuf + un;                           // 32N
        float* pool          = bufA + (size_t)N * FDIM;              // 32G
        float* cnt           = pool + (size_t)G * FDIM;              // G

        hipMemsetAsync(bcount, 0, (size_t)NBUK * PAD * 4, stream);
        hipMemsetAsync(pool, 0, (size_t)(G * FDIM + G) * 4, stream);

        k_bhist<<<(E + BHT - 1) / BHT, 256, 0, stream>>>(col, bcount, E, NBUK);
        k_bscan<<<1, 256, 0, stream>>>(bcount, bptr, bcur, NBUK, E);
        k_binsort<<<(E + BNT - 1) / BNT, 256, 0, stream>>>(row, col, bcur, pairs, E, NBUK);
        k_csort<<<NBUK, 256, 0, stream>>>(pairs, bptr, row_ptr, count, sorted_row, N);

        k_l1<<<(nt + 255) / 256, 256, 0, stream>>>(x, W1, count, dinv, bufG, nullptr, N);
        k_agg<<<(N + 7) / 8, 256, 0, stream>>>(row_ptr, count, sorted_row, bufG, bufA, N);
        k_l2<<<(N + 7) / 8, 256, 0, stream>>>(dinv, bufA, b1, W2, bufG, nullptr, N);
        k_agg<<<(N + 7) / 8, 256, 0, stream>>>(row_ptr, count, sorted_row, bufG, bufA, N);
        k_pool<<<(N + 7) / 8, 256, 0, stream>>>(dinv, bufA, b2, batch, pool, cnt, N);
        k_out<<<(out_size + 255) / 256, 256, 0, stream>>>(pool, cnt, out, out_size);
    } else if (ws_size >= elemsCSR * 4) {
        // R1-proven CSR path
        unsigned int* count  = (unsigned int*)d_ws;
        int* row_ptr         = (int*)(count + N);
        int* cursor          = row_ptr + N;
        unsigned int* bsum   = (unsigned int*)(cursor + N);
        int* sorted_row      = (int*)(bsum + 1024);
        float* dinv          = (float*)(sorted_row + E);
        float* bufG          = dinv + N;
        float* bufA          = bufG + (size_t)N * FDIM;
        float* pool          = bufA + (size_t)N * FDIM;
        float* cnt           = pool + (size_t)G * FDIM;

        hipMemsetAsync(count, 0, (size_t)N * 4, stream);
        hipMemsetAsync(pool, 0, (size_t)(G * FDIM + G) * 4, stream);

        k_hist<<<(E + 255) / 256, 256, 0, stream>>>(col, count, E);
        k_scan1<<<NB, 256, 0, stream>>>(count, bsum, N);
        k_scan2<<<1, 256, 0, stream>>>(bsum, NB);
        k_scan3<<<NB, 256, 0, stream>>>(count, bsum, row_ptr, cursor, N);
        k_permute<<<(E + 255) / 256, 256, 0, stream>>>(row, col, cursor, sorted_row, E);

        k_l1<<<(nt + 255) / 256, 256, 0, stream>>>(x, W1, count, dinv, bufG, nullptr, N);
        k_agg<<<(N + 7) / 8, 256, 0, stream>>>(row_ptr, count, sorted_row, bufG, bufA, N);
        k_l2<<<(N + 7) / 8, 256, 0, stream>>>(dinv, bufA, b1, W2, bufG, nullptr, N);
        k_agg<<<(N + 7) / 8, 256, 0, stream>>>(row_ptr, count, sorted_row, bufG, bufA, N);
        k_pool<<<(N + 7) / 8, 256, 0, stream>>>(dinv, bufA, b2, batch, pool, cnt, N);
        k_out<<<(out_size + 255) / 256, 256, 0, stream>>>(pool, cnt, out, out_size);
    }
}

// Round 6
// 260.277 us; speedup vs baseline: 9.5306x; 1.2967x over previous
//
#include <hip/hip_runtime.h>
#include <hip/hip_fp16.h>

#define FDIM 32
#define BSHIFT 8                 // 256 cols per bucket
#define CPB (1 << BSHIFT)
#define CMASK (CPB - 1)
#define PAD 16                   // cursor stride: 16 u32 = 64B (one cacheline)
#define MAXBUK 512
#define BHT 8192                 // bhist tile (edges per WG)
#define BNT 4096                 // binsort tile (edges per WG, 16/thread)

// ---------- tile-aggregated bucket histogram ----------
__global__ void k_bhist(const int* __restrict__ col, unsigned int* __restrict__ bcount,
                        int E, int NBUK) {
    __shared__ unsigned int lh[MAXBUK];
    int t = threadIdx.x;
    int base = blockIdx.x * BHT;
    for (int b = t; b < NBUK; b += 256) lh[b] = 0u;
    __syncthreads();
    int end = min(base + BHT, E);
    for (int e = base + t; e < end; e += 256)
        atomicAdd(&lh[col[e] >> BSHIFT], 1u);
    __syncthreads();
    for (int b = t; b < NBUK; b += 256) {
        unsigned int c = lh[b];
        if (c) atomicAdd(&bcount[b * PAD], c);
    }
}

// ---------- exclusive scan of bucket counts (1 WG) -> bptr, padded bcur ----------
__global__ void k_bscan(const unsigned int* __restrict__ bcount, int* __restrict__ bptr,
                        int* __restrict__ bcur, int NBUK, int E) {
    __shared__ unsigned int s[256];
    __shared__ unsigned int carry;
    int t = threadIdx.x;
    if (t == 0) carry = 0u;
    __syncthreads();
    for (int base = 0; base < NBUK; base += 256) {
        int i = base + t;
        unsigned int v = (i < NBUK) ? bcount[i * PAD] : 0u;
        s[t] = v;
        __syncthreads();
        for (int off = 1; off < 256; off <<= 1) {
            unsigned int u = (t >= off) ? s[t - off] : 0u;
            __syncthreads();
            s[t] += u;
            __syncthreads();
        }
        unsigned int c = carry;
        if (i < NBUK) { int ex = (int)(c + s[t] - v); bptr[i] = ex; bcur[i * PAD] = ex; }
        __syncthreads();
        if (t == 255) carry = c + s[255];
        __syncthreads();
    }
    if (t == 0) bptr[NBUK] = E;
}

// ---------- tile-aggregated binning: dense per-(tile,bucket) segments ----------
// pack: (col & 255) << 24 | row   (needs N < 2^24)
__global__ void k_binsort(const int* __restrict__ row, const int* __restrict__ col,
                          int* bcur, unsigned int* __restrict__ pairs, int E, int NBUK) {
    __shared__ unsigned int lh[MAXBUK];
    __shared__ int gbase[MAXBUK];
    int t = threadIdx.x;
    int base = blockIdx.x * BNT;
    for (int b = t; b < NBUK; b += 256) lh[b] = 0u;
    __syncthreads();
    int rk[16], rw[16], cl[16];
    #pragma unroll
    for (int k = 0; k < 16; ++k) {
        int e = base + t + k * 256;
        if (e < E) {
            int c = col[e];
            rw[k] = row[e];
            cl[k] = c;
            rk[k] = (int)atomicAdd(&lh[c >> BSHIFT], 1u);
        }
    }
    __syncthreads();
    for (int b = t; b < NBUK; b += 256) {
        unsigned int c = lh[b];
        gbase[b] = c ? atomicAdd(&bcur[b * PAD], (int)c) : 0;
    }
    __syncthreads();
    #pragma unroll
    for (int k = 0; k < 16; ++k) {
        int e = base + t + k * 256;
        if (e < E) {
            int b = cl[k] >> BSHIFT;
            pairs[gbase[b] + rk[k]] = ((unsigned int)(cl[k] & CMASK) << 24) | (unsigned int)rw[k];
        }
    }
}

// ---------- per-bucket fine counting sort in LDS ----------
__global__ void k_csort(const unsigned int* __restrict__ pairs, const int* __restrict__ bptr,
                        int* __restrict__ row_ptr, unsigned int* __restrict__ count,
                        int* __restrict__ sorted_row, int N) {
    __shared__ unsigned int lh[CPB];
    __shared__ int lofs[CPB];
    int b = blockIdx.x;
    int t = threadIdx.x;
    int c0 = b << BSHIFT;
    int s = bptr[b], e = bptr[b + 1];
    lh[t] = 0u;
    __syncthreads();
    for (int j = s + t; j < e; j += 256)
        atomicAdd(&lh[pairs[j] >> 24], 1u);
    __syncthreads();
    unsigned int v = lh[t];
    for (int off = 1; off < 256; off <<= 1) {
        unsigned int u = (t >= off) ? lh[t - off] : 0u;
        __syncthreads();
        lh[t] += u;
        __syncthreads();
    }
    int excl = s + (int)(lh[t] - v);
    if (c0 + t < N) {
        row_ptr[c0 + t] = excl;
        count[c0 + t] = v;
    }
    lofs[t] = excl;
    __syncthreads();
    for (int j = s + t; j < e; j += 256) {
        unsigned int u = pairs[j];
        int pos = atomicAdd(&lofs[u >> 24], 1);
        sorted_row[pos] = (int)(u & 0x00FFFFFFu);
    }
}

// ================= legacy sort fallback (R1-proven) =================

__global__ void k_hist(const int* __restrict__ col, unsigned int* __restrict__ count, int E) {
    int i = blockIdx.x * blockDim.x + threadIdx.x;
    if (i < E) atomicAdd(&count[col[i]], 1u);
}

__global__ void k_scan1(const unsigned int* __restrict__ count, unsigned int* __restrict__ bsum, int N) {
    __shared__ unsigned int s[256];
    int i = blockIdx.x * 256 + threadIdx.x;
    s[threadIdx.x] = (i < N) ? count[i] : 0u;
    __syncthreads();
    for (int off = 128; off > 0; off >>= 1) {
        if (threadIdx.x < off) s[threadIdx.x] += s[threadIdx.x + off];
        __syncthreads();
    }
    if (threadIdx.x == 0) bsum[blockIdx.x] = s[0];
}

__global__ void k_scan2(unsigned int* bsum, int NB) {
    __shared__ unsigned int s[256];
    __shared__ unsigned int carry;
    int t = threadIdx.x;
    if (t == 0) carry = 0u;
    __syncthreads();
    for (int base = 0; base < NB; base += 256) {
        int i = base + t;
        unsigned int v = (i < NB) ? bsum[i] : 0u;
        s[t] = v;
        __syncthreads();
        for (int off = 1; off < 256; off <<= 1) {
            unsigned int u = (t >= off) ? s[t - off] : 0u;
            __syncthreads();
            s[t] += u;
            __syncthreads();
        }
        unsigned int c = carry;
        if (i < NB) bsum[i] = c + s[t] - v;
        __syncthreads();
        if (t == 255) carry = c + s[255];
        __syncthreads();
    }
}

__global__ void k_scan3(const unsigned int* __restrict__ count, const unsigned int* __restrict__ bsum,
                        int* __restrict__ row_ptr, int* __restrict__ cursor, int N) {
    __shared__ unsigned int s[256];
    int t = threadIdx.x;
    int i = blockIdx.x * 256 + t;
    unsigned int v = (i < N) ? count[i] : 0u;
    s[t] = v;
    __syncthreads();
    for (int off = 1; off < 256; off <<= 1) {
        unsigned int u = (t >= off) ? s[t - off] : 0u;
        __syncthreads();
        s[t] += u;
        __syncthreads();
    }
    if (i < N) {
        int start = (int)(bsum[blockIdx.x] + s[t] - v);
        row_ptr[i] = start;
        cursor[i] = start;
    }
}

__global__ void k_permute(const int* __restrict__ row, const int* __restrict__ col,
                          int* cursor, int* __restrict__ sorted_row, int E) {
    int e = blockIdx.x * blockDim.x + threadIdx.x;
    if (e < E) {
        int c = col[e];
        int pos = atomicAdd(&cursor[c], 1);
        sorted_row[pos] = row[e];
    }
}

// ================= dense layers / aggregation / pool (fp16 messages) =================

// layer 1: dinv = rsqrt(count+1); g = fp16(dinv * (x @ W1)); thread per (node, feature-pair)
__global__ void k_l1(const float* __restrict__ x, const float* __restrict__ W1,
                     const unsigned int* __restrict__ count, float* __restrict__ dinv,
                     __half2* __restrict__ g, int N) {
    int idx = blockIdx.x * blockDim.x + threadIdx.x;
    int i = idx >> 4, f2 = idx & 15;
    if (i >= N) return;
    float dv = rsqrtf((float)count[i] + 1.0f);
    if (f2 == 0) dinv[i] = dv;
    float x0 = x[2 * i], x1 = x[2 * i + 1];
    int f = 2 * f2;
    float va = dv * fmaf(x0, W1[f],     x1 * W1[FDIM + f]);
    float vb = dv * fmaf(x0, W1[f + 1], x1 * W1[FDIM + f + 1]);
    g[i * 16 + f2] = __floats2half2_rn(va, vb);
}

// CSR gather segment-sum, fp16 source, f32 accum: 16 lanes/node, half2 loads
__global__ void k_agg(const int* __restrict__ row_ptr, const unsigned int* __restrict__ count,
                      const int* __restrict__ sorted_row, const __half2* __restrict__ g,
                      float2* __restrict__ out, int N) {
    int t = threadIdx.x;
    int i = blockIdx.x * 16 + (t >> 4), f2 = t & 15;
    if (i >= N) return;
    int s = row_ptr[i];
    int e = s + (int)count[i];
    __half2 hv = g[i * 16 + f2];            // self loop
    float a = __low2float(hv), b = __high2float(hv);
    int j = s;
    for (; j + 4 <= e; j += 4) {
        int r0 = sorted_row[j], r1 = sorted_row[j + 1];
        int r2 = sorted_row[j + 2], r3 = sorted_row[j + 3];
        __half2 h0 = g[r0 * 16 + f2], h1 = g[r1 * 16 + f2];
        __half2 h2 = g[r2 * 16 + f2], h3 = g[r3 * 16 + f2];
        a += __low2float(h0); b += __high2float(h0);
        a += __low2float(h1); b += __high2float(h1);
        a += __low2float(h2); b += __high2float(h2);
        a += __low2float(h3); b += __high2float(h3);
    }
    for (; j < e; ++j) {
        __half2 h = g[sorted_row[j] * 16 + f2];
        a += __low2float(h); b += __high2float(h);
    }
    out[i * 16 + f2] = make_float2(a, b);
}

// layer 2: h1 = relu(dinv*agg1 + b1); g2 = fp16(dinv * (h1 @ W2))
__global__ void k_l2(const float* __restrict__ dinv, const float* __restrict__ agg1,
                     const float* __restrict__ b1, const float* __restrict__ W2,
                     __half* __restrict__ g2, int N) {
    __shared__ float sW[FDIM * FDIM];
    __shared__ float sh[8][FDIM];
    int t = threadIdx.x;
    for (int k = t; k < FDIM * FDIM; k += 256) sW[k] = W2[k];
    int i = blockIdx.x * 8 + (t >> 5), f = t & 31;
    float o = 0.0f, dv = 0.0f;
    if (i < N) {
        dv = dinv[i];
        o = fmaxf(fmaf(dv, agg1[i * FDIM + f], b1[f]), 0.0f);
    }
    sh[t >> 5][f] = o;
    __syncthreads();
    if (i < N) {
        float s = 0.0f;
        #pragma unroll
        for (int k = 0; k < FDIM; ++k) s = fmaf(sh[t >> 5][k], sW[k * FDIM + f], s);
        g2[i * FDIM + f] = __float2half(dv * s);
    }
}

// finalize layer 2 + pool scatter (segmented pre-reduction; batch sorted)
__global__ void k_pool(const float* __restrict__ dinv, const float* __restrict__ acc,
                       const float* __restrict__ b2, const int* __restrict__ batch,
                       float* __restrict__ pool, float* __restrict__ cnt, int N) {
    __shared__ float sh[8][FDIM];
    __shared__ int sb[8];
    int t = threadIdx.x;
    int n = t >> 5, f = t & 31;
    int i = blockIdx.x * 8 + n;
    float h = 0.0f;
    int b = -1;
    if (i < N) {
        h = fmaf(dinv[i], acc[i * FDIM + f], b2[f]);
        b = batch[i];
    }
    sh[n][f] = h;
    if (f == 0) sb[n] = b;
    __syncthreads();
    if (b >= 0 && (n == 0 || sb[n - 1] != b)) {
        float sum = h;
        int m = n + 1;
        for (; m < 8 && sb[m] == b; ++m) sum += sh[m][f];
        atomicAdd(&pool[b * FDIM + f], sum);
        if (f == 0) atomicAdd(&cnt[b], (float)(m - n));
    }
}

__global__ void k_out(const float* __restrict__ pool, const float* __restrict__ cnt,
                      float* __restrict__ out, int total) {
    int idx = blockIdx.x * blockDim.x + threadIdx.x;
    if (idx >= total) return;
    out[idx] = pool[idx] / fmaxf(cnt[idx >> 5], 1.0f);
}

extern "C" void kernel_launch(void* const* d_in, const int* in_sizes, int n_in,
                              void* d_out, int out_size, void* d_ws, size_t ws_size,
                              hipStream_t stream) {
    const float* x   = (const float*)d_in[0];
    const int*   ei  = (const int*)d_in[1];
    const int* batch = (const int*)d_in[2];
    const float* W1  = (const float*)d_in[4];
    const float* b1  = (const float*)d_in[5];
    const float* W2  = (const float*)d_in[6];
    const float* b2  = (const float*)d_in[7];
    float* out = (float*)d_out;

    int N = in_sizes[0] / 2;
    int E = in_sizes[1] / 2;
    int G = out_size / FDIM;

    const int* row = ei;
    const int* col = ei + E;

    int nt16 = N * 16;
    int NB = (N + 255) / 256;
    int NBUK = (N + CMASK) >> BSHIFT;

    // unbuf (u32 units): pairs E  U  bufG 16N (N*32 halves)
    size_t un = (size_t)(E > 16 * N ? E : 16 * N);
    size_t elemsNew = 2ull * MAXBUK * PAD + (size_t)NBUK + 1 + 3ull * N + (size_t)E + un
                    + 32ull * (size_t)N + 33ull * G;
    size_t elemsCSR = 4ull * N + 1024 + (size_t)E + un + 32ull * (size_t)N + 33ull * G;

    if (ws_size >= elemsNew * 4 && N < (1 << 24) && NBUK <= MAXBUK) {
        unsigned int* bcount = (unsigned int*)d_ws;                  // MAXBUK*PAD
        int* bcur            = (int*)(bcount + (size_t)MAXBUK * PAD);// MAXBUK*PAD
        int* bptr            = bcur + (size_t)MAXBUK * PAD;          // NBUK+1
        unsigned int* count  = (unsigned int*)(bptr + NBUK + 1);     // N
        int* row_ptr         = (int*)(count + N);                    // N
        int* sorted_row      = row_ptr + N;                          // E
        float* dinv          = (float*)(sorted_row + E);             // N
        unsigned int* unbuf  = (unsigned int*)(dinv + N);            // max(E, 16N)
        unsigned int* pairs  = unbuf;
        __half* bufG         = (__half*)unbuf;                       // N*32 halves
        float* bufA          = (float*)(unbuf + un);                 // 32N
        float* pool          = bufA + (size_t)N * FDIM;              // 32G
        float* cnt           = pool + (size_t)G * FDIM;              // G

        hipMemsetAsync(bcount, 0, (size_t)NBUK * PAD * 4, stream);
        hipMemsetAsync(pool, 0, (size_t)(G * FDIM + G) * 4, stream);

        k_bhist<<<(E + BHT - 1) / BHT, 256, 0, stream>>>(col, bcount, E, NBUK);
        k_bscan<<<1, 256, 0, stream>>>(bcount, bptr, bcur, NBUK, E);
        k_binsort<<<(E + BNT - 1) / BNT, 256, 0, stream>>>(row, col, bcur, pairs, E, NBUK);
        k_csort<<<NBUK, 256, 0, stream>>>(pairs, bptr, row_ptr, count, sorted_row, N);

        k_l1<<<(nt16 + 255) / 256, 256, 0, stream>>>(x, W1, count, dinv, (__half2*)bufG, N);
        k_agg<<<(N + 15) / 16, 256, 0, stream>>>(row_ptr, count, sorted_row, (const __half2*)bufG, (float2*)bufA, N);
        k_l2<<<(N + 7) / 8, 256, 0, stream>>>(dinv, bufA, b1, W2, bufG, N);
        k_agg<<<(N + 15) / 16, 256, 0, stream>>>(row_ptr, count, sorted_row, (const __half2*)bufG, (float2*)bufA, N);
        k_pool<<<(N + 7) / 8, 256, 0, stream>>>(dinv, bufA, b2, batch, pool, cnt, N);
        k_out<<<(out_size + 255) / 256, 256, 0, stream>>>(pool, cnt, out, out_size);
    } else if (ws_size >= elemsCSR * 4) {
        // fallback: R1-proven per-col sort pipeline + fp16 compute kernels
        unsigned int* count  = (unsigned int*)d_ws;                  // N
        int* row_ptr         = (int*)(count + N);                    // N
        int* cursor          = row_ptr + N;                          // N
        unsigned int* bsum   = (unsigned int*)(cursor + N);          // 1024
        int* sorted_row      = (int*)(bsum + 1024);                  // E
        float* dinv          = (float*)(sorted_row + E);             // N
        unsigned int* unbuf  = (unsigned int*)(dinv + N);            // max(E,16N)
        __half* bufG         = (__half*)unbuf;
        float* bufA          = (float*)(unbuf + un);
        float* pool          = bufA + (size_t)N * FDIM;
        float* cnt           = pool + (size_t)G * FDIM;

        hipMemsetAsync(count, 0, (size_t)N * 4, stream);
        hipMemsetAsync(pool, 0, (size_t)(G * FDIM + G) * 4, stream);

        k_hist<<<(E + 255) / 256, 256, 0, stream>>>(col, count, E);
        k_scan1<<<NB, 256, 0, stream>>>(count, bsum, N);
        k_scan2<<<1, 256, 0, stream>>>(bsum, NB);
        k_scan3<<<NB, 256, 0, stream>>>(count, bsum, row_ptr, cursor, N);
        k_permute<<<(E + 255) / 256, 256, 0, stream>>>(row, col, cursor, sorted_row, E);

        k_l1<<<(nt16 + 255) / 256, 256, 0, stream>>>(x, W1, count, dinv, (__half2*)bufG, N);
        k_agg<<<(N + 15) / 16, 256, 0, stream>>>(row_ptr, count, sorted_row, (const __half2*)bufG, (float2*)bufA, N);
        k_l2<<<(N + 7) / 8, 256, 0, stream>>>(dinv, bufA, b1, W2, bufG, N);
        k_agg<<<(N + 15) / 16, 256, 0, stream>>>(row_ptr, count, sorted_row, (const __half2*)bufG, (float2*)bufA, N);
        k_pool<<<(N + 7) / 8, 256, 0, stream>>>(dinv, bufA, b2, batch, pool, cnt, N);
        k_out<<<(out_size + 255) / 256, 256, 0, stream>>>(pool, cnt, out, out_size);
    }
}

// Round 7
// 246.045 us; speedup vs baseline: 10.0819x; 1.0578x over previous
//
#include <hip/hip_runtime.h>
#include <hip/hip_fp16.h>

#define FDIM 32
#define BSHIFT 8                 // 256 cols per bucket
#define CPB (1 << BSHIFT)
#define CMASK (CPB - 1)
#define PAD 16                   // cursor stride: 16 u32 = 64B (one cacheline)
#define MAXBUK 512
#define BHT 8192                 // bhist tile (edges per WG)
#define BNT 8192                 // binsort tile (edges per WG)

// ---------- tile-aggregated bucket histogram ----------
__global__ void k_bhist(const int* __restrict__ col, unsigned int* __restrict__ bcount,
                        int E, int NBUK) {
    __shared__ unsigned int lh[MAXBUK];
    int t = threadIdx.x;
    int base = blockIdx.x * BHT;
    for (int b = t; b < NBUK; b += 256) lh[b] = 0u;
    __syncthreads();
    int end = min(base + BHT, E);
    for (int e = base + t; e < end; e += 256)
        atomicAdd(&lh[col[e] >> BSHIFT], 1u);
    __syncthreads();
    for (int b = t; b < NBUK; b += 256) {
        unsigned int c = lh[b];
        if (c) atomicAdd(&bcount[b * PAD], c);
    }
}

// ---------- exclusive scan of bucket counts (1 WG) -> bptr, padded bcur ----------
__global__ void k_bscan(const unsigned int* __restrict__ bcount, int* __restrict__ bptr,
                        int* __restrict__ bcur, int NBUK, int E) {
    __shared__ unsigned int s[256];
    __shared__ unsigned int carry;
    int t = threadIdx.x;
    if (t == 0) carry = 0u;
    __syncthreads();
    for (int base = 0; base < NBUK; base += 256) {
        int i = base + t;
        unsigned int v = (i < NBUK) ? bcount[i * PAD] : 0u;
        s[t] = v;
        __syncthreads();
        for (int off = 1; off < 256; off <<= 1) {
            unsigned int u = (t >= off) ? s[t - off] : 0u;
            __syncthreads();
            s[t] += u;
            __syncthreads();
        }
        unsigned int c = carry;
        if (i < NBUK) { int ex = (int)(c + s[t] - v); bptr[i] = ex; bcur[i * PAD] = ex; }
        __syncthreads();
        if (t == 255) carry = c + s[255];
        __syncthreads();
    }
    if (t == 0) bptr[NBUK] = E;
}

// ---------- three-phase LDS-staged binning: dense, coalesced segment writes ----------
// pack: (col & 255) << 24 | row   (needs N < 2^24)
__global__ void k_binsort(const int* __restrict__ row, const int* __restrict__ col,
                          int* bcur, unsigned int* __restrict__ pairs, int E, int NBUK) {
    __shared__ unsigned int lh[MAXBUK];      // hist -> global cursor
    __shared__ int lbase[MAXBUK];            // local exclusive base
    __shared__ int gbase[MAXBUK];            // global segment base
    __shared__ unsigned int s[256];
    __shared__ unsigned int carry;
    __shared__ unsigned int lpair[BNT];      // staged packed pairs (rank order)
    __shared__ unsigned short lbuk[BNT];     // bucket id per staged entry
    int t = threadIdx.x;
    int base = blockIdx.x * BNT;
    int end = min(base + BNT, E);

    // phase 1: tile histogram
    for (int b = t; b < NBUK; b += 256) lh[b] = 0u;
    __syncthreads();
    for (int e = base + t; e < end; e += 256)
        atomicAdd(&lh[col[e] >> BSHIFT], 1u);
    if (t == 0) carry = 0u;
    __syncthreads();

    // local exclusive scan of lh -> lbase (chunked Hillis-Steele)
    for (int cb = 0; cb < NBUK; cb += 256) {
        int b = cb + t;
        unsigned int v = (b < NBUK) ? lh[b] : 0u;
        s[t] = v;
        __syncthreads();
        for (int off = 1; off < 256; off <<= 1) {
            unsigned int u = (t >= off) ? s[t - off] : 0u;
            __syncthreads();
            s[t] += u;
            __syncthreads();
        }
        unsigned int c = carry;
        if (b < NBUK) lbase[b] = (int)(c + s[t] - v);
        __syncthreads();
        if (t == 255) carry = c + s[255];
        __syncthreads();
    }

    // phase 2: reserve dense global segments; lh becomes global cursor
    for (int b = t; b < NBUK; b += 256) {
        unsigned int c = lh[b];
        int g = c ? atomicAdd(&bcur[b * PAD], (int)c) : 0;
        gbase[b] = g;
        lh[b] = (unsigned int)g;
    }
    __syncthreads();

    // phase 3a: scatter into LDS by rank
    for (int e = base + t; e < end; e += 256) {
        int c = col[e];
        int b = c >> BSHIFT;
        int gpos = (int)atomicAdd(&lh[b], 1u);
        int lslot = gpos - gbase[b] + lbase[b];
        lpair[lslot] = ((unsigned int)(c & CMASK) << 24) | (unsigned int)row[e];
        lbuk[lslot] = (unsigned short)b;
    }
    __syncthreads();

    // phase 3b: linear LDS -> coalesced global segment writes
    int tilesz = end - base;
    for (int j = t; j < tilesz; j += 256) {
        int b = lbuk[j];
        pairs[gbase[b] + (j - lbase[b])] = lpair[j];
    }
}

// ---------- per-bucket fine counting sort in LDS ----------
__global__ void k_csort(const unsigned int* __restrict__ pairs, const int* __restrict__ bptr,
                        int* __restrict__ row_ptr, unsigned int* __restrict__ count,
                        int* __restrict__ sorted_row, int N) {
    __shared__ unsigned int lh[CPB];
    __shared__ int lofs[CPB];
    int b = blockIdx.x;
    int t = threadIdx.x;
    int c0 = b << BSHIFT;
    int s = bptr[b], e = bptr[b + 1];
    lh[t] = 0u;
    __syncthreads();
    for (int j = s + t; j < e; j += 256)
        atomicAdd(&lh[pairs[j] >> 24], 1u);
    __syncthreads();
    unsigned int v = lh[t];
    for (int off = 1; off < 256; off <<= 1) {
        unsigned int u = (t >= off) ? lh[t - off] : 0u;
        __syncthreads();
        lh[t] += u;
        __syncthreads();
    }
    int excl = s + (int)(lh[t] - v);
    if (c0 + t < N) {
        row_ptr[c0 + t] = excl;
        count[c0 + t] = v;
    }
    lofs[t] = excl;
    __syncthreads();
    for (int j = s + t; j < e; j += 256) {
        unsigned int u = pairs[j];
        int pos = atomicAdd(&lofs[u >> 24], 1);
        sorted_row[pos] = (int)(u & 0x00FFFFFFu);
    }
}

// ================= legacy sort fallback (R1-proven) =================

__global__ void k_hist(const int* __restrict__ col, unsigned int* __restrict__ count, int E) {
    int i = blockIdx.x * blockDim.x + threadIdx.x;
    if (i < E) atomicAdd(&count[col[i]], 1u);
}

__global__ void k_scan1(const unsigned int* __restrict__ count, unsigned int* __restrict__ bsum, int N) {
    __shared__ unsigned int s[256];
    int i = blockIdx.x * 256 + threadIdx.x;
    s[threadIdx.x] = (i < N) ? count[i] : 0u;
    __syncthreads();
    for (int off = 128; off > 0; off >>= 1) {
        if (threadIdx.x < off) s[threadIdx.x] += s[threadIdx.x + off];
        __syncthreads();
    }
    if (threadIdx.x == 0) bsum[blockIdx.x] = s[0];
}

__global__ void k_scan2(unsigned int* bsum, int NB) {
    __shared__ unsigned int s[256];
    __shared__ unsigned int carry;
    int t = threadIdx.x;
    if (t == 0) carry = 0u;
    __syncthreads();
    for (int base = 0; base < NB; base += 256) {
        int i = base + t;
        unsigned int v = (i < NB) ? bsum[i] : 0u;
        s[t] = v;
        __syncthreads();
        for (int off = 1; off < 256; off <<= 1) {
            unsigned int u = (t >= off) ? s[t - off] : 0u;
            __syncthreads();
            s[t] += u;
            __syncthreads();
        }
        unsigned int c = carry;
        if (i < NB) bsum[i] = c + s[t] - v;
        __syncthreads();
        if (t == 255) carry = c + s[255];
        __syncthreads();
    }
}

__global__ void k_scan3(const unsigned int* __restrict__ count, const unsigned int* __restrict__ bsum,
                        int* __restrict__ row_ptr, int* __restrict__ cursor, int N) {
    __shared__ unsigned int s[256];
    int t = threadIdx.x;
    int i = blockIdx.x * 256 + t;
    unsigned int v = (i < N) ? count[i] : 0u;
    s[t] = v;
    __syncthreads();
    for (int off = 1; off < 256; off <<= 1) {
        unsigned int u = (t >= off) ? s[t - off] : 0u;
        __syncthreads();
        s[t] += u;
        __syncthreads();
    }
    if (i < N) {
        int start = (int)(bsum[blockIdx.x] + s[t] - v);
        row_ptr[i] = start;
        cursor[i] = start;
    }
}

__global__ void k_permute(const int* __restrict__ row, const int* __restrict__ col,
                          int* cursor, int* __restrict__ sorted_row, int E) {
    int e = blockIdx.x * blockDim.x + threadIdx.x;
    if (e < E) {
        int c = col[e];
        int pos = atomicAdd(&cursor[c], 1);
        sorted_row[pos] = row[e];
    }
}

// ================= dense layers / aggregation / pool (fp16 messages) =================

__global__ void k_l1(const float* __restrict__ x, const float* __restrict__ W1,
                     const unsigned int* __restrict__ count, float* __restrict__ dinv,
                     __half2* __restrict__ g, int N) {
    int idx = blockIdx.x * blockDim.x + threadIdx.x;
    int i = idx >> 4, f2 = idx & 15;
    if (i >= N) return;
    float dv = rsqrtf((float)count[i] + 1.0f);
    if (f2 == 0) dinv[i] = dv;
    float x0 = x[2 * i], x1 = x[2 * i + 1];
    int f = 2 * f2;
    float va = dv * fmaf(x0, W1[f],     x1 * W1[FDIM + f]);
    float vb = dv * fmaf(x0, W1[f + 1], x1 * W1[FDIM + f + 1]);
    g[i * 16 + f2] = __floats2half2_rn(va, vb);
}

__global__ void k_agg(const int* __restrict__ row_ptr, const unsigned int* __restrict__ count,
                      const int* __restrict__ sorted_row, const __half2* __restrict__ g,
                      float2* __restrict__ out, int N) {
    int t = threadIdx.x;
    int i = blockIdx.x * 16 + (t >> 4), f2 = t & 15;
    if (i >= N) return;
    int s = row_ptr[i];
    int e = s + (int)count[i];
    __half2 hv = g[i * 16 + f2];            // self loop
    float a = __low2float(hv), b = __high2float(hv);
    int j = s;
    for (; j + 4 <= e; j += 4) {
        int r0 = sorted_row[j], r1 = sorted_row[j + 1];
        int r2 = sorted_row[j + 2], r3 = sorted_row[j + 3];
        __half2 h0 = g[r0 * 16 + f2], h1 = g[r1 * 16 + f2];
        __half2 h2 = g[r2 * 16 + f2], h3 = g[r3 * 16 + f2];
        a += __low2float(h0); b += __high2float(h0);
        a += __low2float(h1); b += __high2float(h1);
        a += __low2float(h2); b += __high2float(h2);
        a += __low2float(h3); b += __high2float(h3);
    }
    for (; j < e; ++j) {
        __half2 h = g[sorted_row[j] * 16 + f2];
        a += __low2float(h); b += __high2float(h);
    }
    out[i * 16 + f2] = make_float2(a, b);
}

__global__ void k_l2(const float* __restrict__ dinv, const float* __restrict__ agg1,
                     const float* __restrict__ b1, const float* __restrict__ W2,
                     __half* __restrict__ g2, int N) {
    __shared__ float sW[FDIM * FDIM];
    __shared__ float sh[8][FDIM];
    int t = threadIdx.x;
    for (int k = t; k < FDIM * FDIM; k += 256) sW[k] = W2[k];
    int i = blockIdx.x * 8 + (t >> 5), f = t & 31;
    float o = 0.0f, dv = 0.0f;
    if (i < N) {
        dv = dinv[i];
        o = fmaxf(fmaf(dv, agg1[i * FDIM + f], b1[f]), 0.0f);
    }
    sh[t >> 5][f] = o;
    __syncthreads();
    if (i < N) {
        float s = 0.0f;
        #pragma unroll
        for (int k = 0; k < FDIM; ++k) s = fmaf(sh[t >> 5][k], sW[k * FDIM + f], s);
        g2[i * FDIM + f] = __float2half(dv * s);
    }
}

__global__ void k_pool(const float* __restrict__ dinv, const float* __restrict__ acc,
                       const float* __restrict__ b2, const int* __restrict__ batch,
                       float* __restrict__ pool, float* __restrict__ cnt, int N) {
    __shared__ float sh[8][FDIM];
    __shared__ int sb[8];
    int t = threadIdx.x;
    int n = t >> 5, f = t & 31;
    int i = blockIdx.x * 8 + n;
    float h = 0.0f;
    int b = -1;
    if (i < N) {
        h = fmaf(dinv[i], acc[i * FDIM + f], b2[f]);
        b = batch[i];
    }
    sh[n][f] = h;
    if (f == 0) sb[n] = b;
    __syncthreads();
    if (b >= 0 && (n == 0 || sb[n - 1] != b)) {
        float sum = h;
        int m = n + 1;
        for (; m < 8 && sb[m] == b; ++m) sum += sh[m][f];
        atomicAdd(&pool[b * FDIM + f], sum);
        if (f == 0) atomicAdd(&cnt[b], (float)(m - n));
    }
}

__global__ void k_out(const float* __restrict__ pool, const float* __restrict__ cnt,
                      float* __restrict__ out, int total) {
    int idx = blockIdx.x * blockDim.x + threadIdx.x;
    if (idx >= total) return;
    out[idx] = pool[idx] / fmaxf(cnt[idx >> 5], 1.0f);
}

extern "C" void kernel_launch(void* const* d_in, const int* in_sizes, int n_in,
                              void* d_out, int out_size, void* d_ws, size_t ws_size,
                              hipStream_t stream) {
    const float* x   = (const float*)d_in[0];
    const int*   ei  = (const int*)d_in[1];
    const int* batch = (const int*)d_in[2];
    const float* W1  = (const float*)d_in[4];
    const float* b1  = (const float*)d_in[5];
    const float* W2  = (const float*)d_in[6];
    const float* b2  = (const float*)d_in[7];
    float* out = (float*)d_out;

    int N = in_sizes[0] / 2;
    int E = in_sizes[1] / 2;
    int G = out_size / FDIM;

    const int* row = ei;
    const int* col = ei + E;

    int nt16 = N * 16;
    int NB = (N + 255) / 256;
    int NBUK = (N + CMASK) >> BSHIFT;

    // unbuf (u32 units): pairs E  U  bufG 16N (N*32 halves)
    size_t un = (size_t)(E > 16 * N ? E : 16 * N);
    size_t elemsNew = 2ull * MAXBUK * PAD + (size_t)NBUK + 1 + 3ull * N + (size_t)E + un
                    + 32ull * (size_t)N + 33ull * G;
    size_t elemsCSR = 4ull * N + 1024 + (size_t)E + un + 32ull * (size_t)N + 33ull * G;

    if (ws_size >= elemsNew * 4 && N < (1 << 24) && NBUK <= MAXBUK) {
        unsigned int* bcount = (unsigned int*)d_ws;                  // MAXBUK*PAD
        int* bcur            = (int*)(bcount + (size_t)MAXBUK * PAD);// MAXBUK*PAD
        int* bptr            = bcur + (size_t)MAXBUK * PAD;          // NBUK+1
        unsigned int* count  = (unsigned int*)(bptr + NBUK + 1);     // N
        int* row_ptr         = (int*)(count + N);                    // N
        int* sorted_row      = row_ptr + N;                          // E
        float* dinv          = (float*)(sorted_row + E);             // N
        unsigned int* unbuf  = (unsigned int*)(dinv + N);            // max(E, 16N)
        unsigned int* pairs  = unbuf;
        __half* bufG         = (__half*)unbuf;                       // N*32 halves
        float* bufA          = (float*)(unbuf + un);                 // 32N
        float* pool          = bufA + (size_t)N * FDIM;              // 32G
        float* cnt           = pool + (size_t)G * FDIM;              // G

        hipMemsetAsync(bcount, 0, (size_t)NBUK * PAD * 4, stream);
        hipMemsetAsync(pool, 0, (size_t)(G * FDIM + G) * 4, stream);

        k_bhist<<<(E + BHT - 1) / BHT, 256, 0, stream>>>(col, bcount, E, NBUK);
        k_bscan<<<1, 256, 0, stream>>>(bcount, bptr, bcur, NBUK, E);
        k_binsort<<<(E + BNT - 1) / BNT, 256, 0, stream>>>(row, col, bcur, pairs, E, NBUK);
        k_csort<<<NBUK, 256, 0, stream>>>(pairs, bptr, row_ptr, count, sorted_row, N);

        k_l1<<<(nt16 + 255) / 256, 256, 0, stream>>>(x, W1, count, dinv, (__half2*)bufG, N);
        k_agg<<<(N + 15) / 16, 256, 0, stream>>>(row_ptr, count, sorted_row, (const __half2*)bufG, (float2*)bufA, N);
        k_l2<<<(N + 7) / 8, 256, 0, stream>>>(dinv, bufA, b1, W2, bufG, N);
        k_agg<<<(N + 15) / 16, 256, 0, stream>>>(row_ptr, count, sorted_row, (const __half2*)bufG, (float2*)bufA, N);
        k_pool<<<(N + 7) / 8, 256, 0, stream>>>(dinv, bufA, b2, batch, pool, cnt, N);
        k_out<<<(out_size + 255) / 256, 256, 0, stream>>>(pool, cnt, out, out_size);
    } else if (ws_size >= elemsCSR * 4) {
        // fallback: R1-proven per-col sort pipeline + fp16 compute kernels
        unsigned int* count  = (unsigned int*)d_ws;                  // N
        int* row_ptr         = (int*)(count + N);                    // N
        int* cursor          = row_ptr + N;                          // N
        unsigned int* bsum   = (unsigned int*)(cursor + N);          // 1024
        int* sorted_row      = (int*)(bsum + 1024);                  // E
        float* dinv          = (float*)(sorted_row + E);             // N
        unsigned int* unbuf  = (unsigned int*)(dinv + N);            // max(E,16N)
        __half* bufG         = (__half*)unbuf;
        float* bufA          = (float*)(unbuf + un);
        float* pool          = bufA + (size_t)N * FDIM;
        float* cnt           = pool + (size_t)G * FDIM;

        hipMemsetAsync(count, 0, (size_t)N * 4, stream);
        hipMemsetAsync(pool, 0, (size_t)(G * FDIM + G) * 4, stream);

        k_hist<<<(E + 255) / 256, 256, 0, stream>>>(col, count, E);
        k_scan1<<<NB, 256, 0, stream>>>(count, bsum, N);
        k_scan2<<<1, 256, 0, stream>>>(bsum, NB);
        k_scan3<<<NB, 256, 0, stream>>>(count, bsum, row_ptr, cursor, N);
        k_permute<<<(E + 255) / 256, 256, 0, stream>>>(row, col, cursor, sorted_row, E);

        k_l1<<<(nt16 + 255) / 256, 256, 0, stream>>>(x, W1, count, dinv, (__half2*)bufG, N);
        k_agg<<<(N + 15) / 16, 256, 0, stream>>>(row_ptr, count, sorted_row, (const __half2*)bufG, (float2*)bufA, N);
        k_l2<<<(N + 7) / 8, 256, 0, stream>>>(dinv, bufA, b1, W2, bufG, N);
        k_agg<<<(N + 15) / 16, 256, 0, stream>>>(row_ptr, count, sorted_row, (const __half2*)bufG, (float2*)bufA, N);
        k_pool<<<(N + 7) / 8, 256, 0, stream>>>(dinv, bufA, b2, batch, pool, cnt, N);
        k_out<<<(out_size + 255) / 256, 256, 0, stream>>>(pool, cnt, out, out_size);
    }
}

// Round 8
// 221.837 us; speedup vs baseline: 11.1820x; 1.1091x over previous
//
#include <hip/hip_runtime.h>
#include <hip/hip_fp16.h>

#define FDIM 32
#define BSHIFT 8                 // 256 cols per bucket
#define CPB (1 << BSHIFT)
#define CMASK (CPB - 1)
#define PAD 16                   // cursor stride: 16 u32 = 64B (one cacheline)
#define MAXBUK 512
#define BHT 8192                 // bhist tile (edges per WG)
#define BNT 8192                 // binsort tile (edges per WG)

// ---------- tile-aggregated bucket histogram ----------
__global__ void k_bhist(const int* __restrict__ col, unsigned int* __restrict__ bcount,
                        int E, int NBUK) {
    __shared__ unsigned int lh[MAXBUK];
    int t = threadIdx.x;
    int base = blockIdx.x * BHT;
    for (int b = t; b < NBUK; b += 256) lh[b] = 0u;
    __syncthreads();
    int end = min(base + BHT, E);
    for (int e = base + t; e < end; e += 256)
        atomicAdd(&lh[col[e] >> BSHIFT], 1u);
    __syncthreads();
    for (int b = t; b < NBUK; b += 256) {
        unsigned int c = lh[b];
        if (c) atomicAdd(&bcount[b * PAD], c);
    }
}

// ---------- exclusive scan of bucket counts (1 WG) -> bptr, padded bcur ----------
__global__ void k_bscan(const unsigned int* __restrict__ bcount, int* __restrict__ bptr,
                        int* __restrict__ bcur, int NBUK, int E) {
    __shared__ unsigned int s[256];
    __shared__ unsigned int carry;
    int t = threadIdx.x;
    if (t == 0) carry = 0u;
    __syncthreads();
    for (int base = 0; base < NBUK; base += 256) {
        int i = base + t;
        unsigned int v = (i < NBUK) ? bcount[i * PAD] : 0u;
        s[t] = v;
        __syncthreads();
        for (int off = 1; off < 256; off <<= 1) {
            unsigned int u = (t >= off) ? s[t - off] : 0u;
            __syncthreads();
            s[t] += u;
            __syncthreads();
        }
        unsigned int c = carry;
        if (i < NBUK) { int ex = (int)(c + s[t] - v); bptr[i] = ex; bcur[i * PAD] = ex; }
        __syncthreads();
        if (t == 255) carry = c + s[255];
        __syncthreads();
    }
    if (t == 0) bptr[NBUK] = E;
}

// ---------- three-phase LDS-staged binning: dense, coalesced segment writes ----------
// pack: (col & 255) << 24 | row   (needs N < 2^24)
__global__ void k_binsort(const int* __restrict__ row, const int* __restrict__ col,
                          int* bcur, unsigned int* __restrict__ pairs, int E, int NBUK) {
    __shared__ unsigned int lh[MAXBUK];      // hist -> global cursor
    __shared__ int lbase[MAXBUK];            // local exclusive base
    __shared__ int gbase[MAXBUK];            // global segment base
    __shared__ unsigned int s[256];
    __shared__ unsigned int carry;
    __shared__ unsigned int lpair[BNT];      // staged packed pairs (rank order)
    __shared__ unsigned short lbuk[BNT];     // bucket id per staged entry
    int t = threadIdx.x;
    int base = blockIdx.x * BNT;
    int end = min(base + BNT, E);

    for (int b = t; b < NBUK; b += 256) lh[b] = 0u;
    __syncthreads();
    for (int e = base + t; e < end; e += 256)
        atomicAdd(&lh[col[e] >> BSHIFT], 1u);
    if (t == 0) carry = 0u;
    __syncthreads();

    for (int cb = 0; cb < NBUK; cb += 256) {
        int b = cb + t;
        unsigned int v = (b < NBUK) ? lh[b] : 0u;
        s[t] = v;
        __syncthreads();
        for (int off = 1; off < 256; off <<= 1) {
            unsigned int u = (t >= off) ? s[t - off] : 0u;
            __syncthreads();
            s[t] += u;
            __syncthreads();
        }
        unsigned int c = carry;
        if (b < NBUK) lbase[b] = (int)(c + s[t] - v);
        __syncthreads();
        if (t == 255) carry = c + s[255];
        __syncthreads();
    }

    for (int b = t; b < NBUK; b += 256) {
        unsigned int c = lh[b];
        int g = c ? atomicAdd(&bcur[b * PAD], (int)c) : 0;
        gbase[b] = g;
        lh[b] = (unsigned int)g;
    }
    __syncthreads();

    for (int e = base + t; e < end; e += 256) {
        int c = col[e];
        int b = c >> BSHIFT;
        int gpos = (int)atomicAdd(&lh[b], 1u);
        int lslot = gpos - gbase[b] + lbase[b];
        lpair[lslot] = ((unsigned int)(c & CMASK) << 24) | (unsigned int)row[e];
        lbuk[lslot] = (unsigned short)b;
    }
    __syncthreads();

    int tilesz = end - base;
    for (int j = t; j < tilesz; j += 256) {
        int b = lbuk[j];
        pairs[gbase[b] + (j - lbase[b])] = lpair[j];
    }
}

// ---------- per-bucket fine counting sort in LDS ----------
__global__ void k_csort(const unsigned int* __restrict__ pairs, const int* __restrict__ bptr,
                        int* __restrict__ row_ptr, unsigned int* __restrict__ count,
                        int* __restrict__ sorted_row, int N) {
    __shared__ unsigned int lh[CPB];
    __shared__ int lofs[CPB];
    int b = blockIdx.x;
    int t = threadIdx.x;
    int c0 = b << BSHIFT;
    int s = bptr[b], e = bptr[b + 1];
    lh[t] = 0u;
    __syncthreads();
    for (int j = s + t; j < e; j += 256)
        atomicAdd(&lh[pairs[j] >> 24], 1u);
    __syncthreads();
    unsigned int v = lh[t];
    for (int off = 1; off < 256; off <<= 1) {
        unsigned int u = (t >= off) ? lh[t - off] : 0u;
        __syncthreads();
        lh[t] += u;
        __syncthreads();
    }
    int excl = s + (int)(lh[t] - v);
    if (c0 + t < N) {
        row_ptr[c0 + t] = excl;
        count[c0 + t] = v;
    }
    lofs[t] = excl;
    __syncthreads();
    for (int j = s + t; j < e; j += 256) {
        unsigned int u = pairs[j];
        int pos = atomicAdd(&lofs[u >> 24], 1);
        sorted_row[pos] = (int)(u & 0x00FFFFFFu);
    }
}

// ================= legacy sort fallback (R1-proven) =================

__global__ void k_hist(const int* __restrict__ col, unsigned int* __restrict__ count, int E) {
    int i = blockIdx.x * blockDim.x + threadIdx.x;
    if (i < E) atomicAdd(&count[col[i]], 1u);
}

__global__ void k_scan1(const unsigned int* __restrict__ count, unsigned int* __restrict__ bsum, int N) {
    __shared__ unsigned int s[256];
    int i = blockIdx.x * 256 + threadIdx.x;
    s[threadIdx.x] = (i < N) ? count[i] : 0u;
    __syncthreads();
    for (int off = 128; off > 0; off >>= 1) {
        if (threadIdx.x < off) s[threadIdx.x] += s[threadIdx.x + off];
        __syncthreads();
    }
    if (threadIdx.x == 0) bsum[blockIdx.x] = s[0];
}

__global__ void k_scan2(unsigned int* bsum, int NB) {
    __shared__ unsigned int s[256];
    __shared__ unsigned int carry;
    int t = threadIdx.x;
    if (t == 0) carry = 0u;
    __syncthreads();
    for (int base = 0; base < NB; base += 256) {
        int i = base + t;
        unsigned int v = (i < NB) ? bsum[i] : 0u;
        s[t] = v;
        __syncthreads();
        for (int off = 1; off < 256; off <<= 1) {
            unsigned int u = (t >= off) ? s[t - off] : 0u;
            __syncthreads();
            s[t] += u;
            __syncthreads();
        }
        unsigned int c = carry;
        if (i < NB) bsum[i] = c + s[t] - v;
        __syncthreads();
        if (t == 255) carry = c + s[255];
        __syncthreads();
    }
}

__global__ void k_scan3(const unsigned int* __restrict__ count, const unsigned int* __restrict__ bsum,
                        int* __restrict__ row_ptr, int* __restrict__ cursor, int N) {
    __shared__ unsigned int s[256];
    int t = threadIdx.x;
    int i = blockIdx.x * 256 + t;
    unsigned int v = (i < N) ? count[i] : 0u;
    s[t] = v;
    __syncthreads();
    for (int off = 1; off < 256; off <<= 1) {
        unsigned int u = (t >= off) ? s[t - off] : 0u;
        __syncthreads();
        s[t] += u;
        __syncthreads();
    }
    if (i < N) {
        int start = (int)(bsum[blockIdx.x] + s[t] - v);
        row_ptr[i] = start;
        cursor[i] = start;
    }
}

__global__ void k_permute(const int* __restrict__ row, const int* __restrict__ col,
                          int* cursor, int* __restrict__ sorted_row, int E) {
    int e = blockIdx.x * blockDim.x + threadIdx.x;
    if (e < E) {
        int c = col[e];
        int pos = atomicAdd(&cursor[c], 1);
        sorted_row[pos] = row[e];
    }
}

// ================= dense layer 1 (fp16 messages) =================

__global__ void k_l1(const float* __restrict__ x, const float* __restrict__ W1,
                     const unsigned int* __restrict__ count, float* __restrict__ dinv,
                     __half2* __restrict__ g, int N) {
    int idx = blockIdx.x * blockDim.x + threadIdx.x;
    int i = idx >> 4, f2 = idx & 15;
    if (i >= N) return;
    float dv = rsqrtf((float)count[i] + 1.0f);
    if (f2 == 0) dinv[i] = dv;
    float x0 = x[2 * i], x1 = x[2 * i + 1];
    int f = 2 * f2;
    float va = dv * fmaf(x0, W1[f],     x1 * W1[FDIM + f]);
    float vb = dv * fmaf(x0, W1[f + 1], x1 * W1[FDIM + f + 1]);
    g[i * 16 + f2] = __floats2half2_rn(va, vb);
}

// ================= fused agg1 + relu/bias + W2 matmul -> g2 (fp16) =================
// 16 nodes/WG, 16 lanes/node (2 feats/lane). Gather f32 accum, epilogue in-WG.
__global__ void k_agg_l2(const int* __restrict__ row_ptr, const unsigned int* __restrict__ count,
                         const int* __restrict__ sorted_row, const __half2* __restrict__ g,
                         const float* __restrict__ dinv, const float* __restrict__ b1,
                         const float* __restrict__ W2, __half2* __restrict__ g2, int N) {
    __shared__ float sW[FDIM * FDIM];
    __shared__ float sh[16][FDIM];
    int t = threadIdx.x;
    for (int k = t; k < FDIM * FDIM; k += 256) sW[k] = W2[k];
    int n = t >> 4, f2 = t & 15;
    int i = blockIdx.x * 16 + n;
    float a = 0.0f, b = 0.0f, dv = 0.0f;
    if (i < N) {
        dv = dinv[i];
        int s = row_ptr[i];
        int e = s + (int)count[i];
        __half2 hv = g[i * 16 + f2];        // self loop
        a = __low2float(hv); b = __high2float(hv);
        int j = s;
        for (; j + 4 <= e; j += 4) {
            int r0 = sorted_row[j], r1 = sorted_row[j + 1];
            int r2 = sorted_row[j + 2], r3 = sorted_row[j + 3];
            __half2 h0 = g[r0 * 16 + f2], h1 = g[r1 * 16 + f2];
            __half2 h2 = g[r2 * 16 + f2], h3 = g[r3 * 16 + f2];
            a += __low2float(h0); b += __high2float(h0);
            a += __low2float(h1); b += __high2float(h1);
            a += __low2float(h2); b += __high2float(h2);
            a += __low2float(h3); b += __high2float(h3);
        }
        for (; j < e; ++j) {
            __half2 h = g[sorted_row[j] * 16 + f2];
            a += __low2float(h); b += __high2float(h);
        }
        // h1 = relu(dinv*agg + b1)
        a = fmaxf(fmaf(dv, a, b1[2 * f2]),     0.0f);
        b = fmaxf(fmaf(dv, b, b1[2 * f2 + 1]), 0.0f);
    }
    sh[n][2 * f2]     = a;
    sh[n][2 * f2 + 1] = b;
    __syncthreads();
    if (i < N) {
        float s0 = 0.0f, s1 = 0.0f;
        #pragma unroll
        for (int k = 0; k < FDIM; ++k) {
            float h = sh[n][k];
            s0 = fmaf(h, sW[k * FDIM + 2 * f2],     s0);
            s1 = fmaf(h, sW[k * FDIM + 2 * f2 + 1], s1);
        }
        g2[i * 16 + f2] = __floats2half2_rn(dv * s0, dv * s1);
    }
}

// ================= fused agg2 + bias + segmented pool scatter =================
__global__ void k_agg_pool(const int* __restrict__ row_ptr, const unsigned int* __restrict__ count,
                           const int* __restrict__ sorted_row, const __half2* __restrict__ g,
                           const float* __restrict__ dinv, const float* __restrict__ b2,
                           const int* __restrict__ batch, float* __restrict__ pool,
                           float* __restrict__ cnt, int N) {
    __shared__ float sh[16][FDIM];
    __shared__ int sb[16];
    int t = threadIdx.x;
    int n = t >> 4, f2 = t & 15;
    int i = blockIdx.x * 16 + n;
    float a = 0.0f, b = 0.0f;
    int bt = -1;
    if (i < N) {
        float dv = dinv[i];
        int s = row_ptr[i];
        int e = s + (int)count[i];
        __half2 hv = g[i * 16 + f2];        // self loop
        a = __low2float(hv); b = __high2float(hv);
        int j = s;
        for (; j + 4 <= e; j += 4) {
            int r0 = sorted_row[j], r1 = sorted_row[j + 1];
            int r2 = sorted_row[j + 2], r3 = sorted_row[j + 3];
            __half2 h0 = g[r0 * 16 + f2], h1 = g[r1 * 16 + f2];
            __half2 h2 = g[r2 * 16 + f2], h3 = g[r3 * 16 + f2];
            a += __low2float(h0); b += __high2float(h0);
            a += __low2float(h1); b += __high2float(h1);
            a += __low2float(h2); b += __high2float(h2);
            a += __low2float(h3); b += __high2float(h3);
        }
        for (; j < e; ++j) {
            __half2 h = g[sorted_row[j] * 16 + f2];
            a += __low2float(h); b += __high2float(h);
        }
        a = fmaf(dv, a, b2[2 * f2]);
        b = fmaf(dv, b, b2[2 * f2 + 1]);
        bt = batch[i];
    }
    sh[n][2 * f2]     = a;
    sh[n][2 * f2 + 1] = b;
    if (f2 == 0) sb[n] = bt;
    __syncthreads();
    if (bt >= 0 && (n == 0 || sb[n - 1] != bt)) {   // segment leader
        float s0 = a, s1 = b;
        int m = n + 1;
        for (; m < 16 && sb[m] == bt; ++m) {
            s0 += sh[m][2 * f2];
            s1 += sh[m][2 * f2 + 1];
        }
        atomicAdd(&pool[bt * FDIM + 2 * f2],     s0);
        atomicAdd(&pool[bt * FDIM + 2 * f2 + 1], s1);
        if (f2 == 0) atomicAdd(&cnt[bt], (float)(m - n));
    }
}

__global__ void k_out(const float* __restrict__ pool, const float* __restrict__ cnt,
                      float* __restrict__ out, int total) {
    int idx = blockIdx.x * blockDim.x + threadIdx.x;
    if (idx >= total) return;
    out[idx] = pool[idx] / fmaxf(cnt[idx >> 5], 1.0f);
}

extern "C" void kernel_launch(void* const* d_in, const int* in_sizes, int n_in,
                              void* d_out, int out_size, void* d_ws, size_t ws_size,
                              hipStream_t stream) {
    const float* x   = (const float*)d_in[0];
    const int*   ei  = (const int*)d_in[1];
    const int* batch = (const int*)d_in[2];
    const float* W1  = (const float*)d_in[4];
    const float* b1  = (const float*)d_in[5];
    const float* W2  = (const float*)d_in[6];
    const float* b2  = (const float*)d_in[7];
    float* out = (float*)d_out;

    int N = in_sizes[0] / 2;
    int E = in_sizes[1] / 2;
    int G = out_size / FDIM;

    const int* row = ei;
    const int* col = ei + E;

    int nt16 = N * 16;
    int NB = (N + 255) / 256;
    int NBUK = (N + CMASK) >> BSHIFT;

    // unbuf (u32 units): pairs E  U  bufG 16N (N*32 halves)
    size_t un = (size_t)(E > 16 * N ? E : 16 * N);
    size_t elemsNew = 2ull * MAXBUK * PAD + (size_t)NBUK + 1 + 3ull * N + (size_t)E + un
                    + 32ull * (size_t)N + 33ull * G;
    size_t elemsCSR = 4ull * N + 1024 + (size_t)E + un + 32ull * (size_t)N + 33ull * G;

    if (ws_size >= elemsNew * 4 && N < (1 << 24) && NBUK <= MAXBUK) {
        unsigned int* bcount = (unsigned int*)d_ws;                  // MAXBUK*PAD
        int* bcur            = (int*)(bcount + (size_t)MAXBUK * PAD);// MAXBUK*PAD
        int* bptr            = bcur + (size_t)MAXBUK * PAD;          // NBUK+1
        unsigned int* count  = (unsigned int*)(bptr + NBUK + 1);     // N
        int* row_ptr         = (int*)(count + N);                    // N
        int* sorted_row      = row_ptr + N;                          // E
        float* dinv          = (float*)(sorted_row + E);             // N
        unsigned int* unbuf  = (unsigned int*)(dinv + N);            // max(E, 16N)
        unsigned int* pairs  = unbuf;
        __half* bufG         = (__half*)unbuf;                       // N*32 halves (g1)
        __half* bufG2        = (__half*)(unbuf + un);                // N*32 halves (g2)
        float* pool          = (float*)(unbuf + un) + 16ull * N;     // 32G  (after g2's 16N u32)
        float* cnt           = pool + (size_t)G * FDIM;              // G

        hipMemsetAsync(bcount, 0, (size_t)NBUK * PAD * 4, stream);
        hipMemsetAsync(pool, 0, (size_t)(G * FDIM + G) * 4, stream);

        k_bhist<<<(E + BHT - 1) / BHT, 256, 0, stream>>>(col, bcount, E, NBUK);
        k_bscan<<<1, 256, 0, stream>>>(bcount, bptr, bcur, NBUK, E);
        k_binsort<<<(E + BNT - 1) / BNT, 256, 0, stream>>>(row, col, bcur, pairs, E, NBUK);
        k_csort<<<NBUK, 256, 0, stream>>>(pairs, bptr, row_ptr, count, sorted_row, N);

        k_l1<<<(nt16 + 255) / 256, 256, 0, stream>>>(x, W1, count, dinv, (__half2*)bufG, N);
        k_agg_l2<<<(N + 15) / 16, 256, 0, stream>>>(row_ptr, count, sorted_row,
                                                    (const __half2*)bufG, dinv, b1, W2,
                                                    (__half2*)bufG2, N);
        k_agg_pool<<<(N + 15) / 16, 256, 0, stream>>>(row_ptr, count, sorted_row,
                                                      (const __half2*)bufG2, dinv, b2,
                                                      batch, pool, cnt, N);
        k_out<<<(out_size + 255) / 256, 256, 0, stream>>>(pool, cnt, out, out_size);
    } else if (ws_size >= elemsCSR * 4) {
        // fallback: R1-proven per-col sort pipeline + fused compute kernels
        unsigned int* count  = (unsigned int*)d_ws;                  // N
        int* row_ptr         = (int*)(count + N);                    // N
        int* cursor          = row_ptr + N;                          // N
        unsigned int* bsum   = (unsigned int*)(cursor + N);          // 1024
        int* sorted_row      = (int*)(bsum + 1024);                  // E
        float* dinv          = (float*)(sorted_row + E);             // N
        unsigned int* unbuf  = (unsigned int*)(dinv + N);            // max(E,16N)
        __half* bufG         = (__half*)unbuf;
        __half* bufG2        = (__half*)(unbuf + un);
        float* pool          = (float*)(unbuf + un) + 16ull * N;
        float* cnt           = pool + (size_t)G * FDIM;

        hipMemsetAsync(count, 0, (size_t)N * 4, stream);
        hipMemsetAsync(pool, 0, (size_t)(G * FDIM + G) * 4, stream);

        k_hist<<<(E + 255) / 256, 256, 0, stream>>>(col, count, E);
        k_scan1<<<NB, 256, 0, stream>>>(count, bsum, N);
        k_scan2<<<1, 256, 0, stream>>>(bsum, NB);
        k_scan3<<<NB, 256, 0, stream>>>(count, bsum, row_ptr, cursor, N);
        k_permute<<<(E + 255) / 256, 256, 0, stream>>>(row, col, cursor, sorted_row, E);

        k_l1<<<(nt16 + 255) / 256, 256, 0, stream>>>(x, W1, count, dinv, (__half2*)bufG, N);
        k_agg_l2<<<(N + 15) / 16, 256, 0, stream>>>(row_ptr, count, sorted_row,
                                                    (const __half2*)bufG, dinv, b1, W2,
                                                    (__half2*)bufG2, N);
        k_agg_pool<<<(N + 15) / 16, 256, 0, stream>>>(row_ptr, count, sorted_row,
                                                      (const __half2*)bufG2, dinv, b2,
                                                      batch, pool, cnt, N);
        k_out<<<(out_size + 255) / 256, 256, 0, stream>>>(pool, cnt, out, out_size);
    }
}

// Round 9
// 179.657 us; speedup vs baseline: 13.8073x; 1.2348x over previous
//
#include <hip/hip_runtime.h>
#include <hip/hip_fp16.h>

#define FDIM 32
#define BSHIFT 8                 // 256 cols per bucket
#define CPB (1 << BSHIFT)
#define CMASK (CPB - 1)
#define PAD 16                   // cursor stride: 16 u32 = 64B (one cacheline)
#define MAXBUK 512
#define BHT 8192                 // bhist tile (edges per WG)
#define BNT 8192                 // binsort tile (edges per WG)

// ---------- tile-aggregated bucket histogram ----------
__global__ void k_bhist(const int* __restrict__ col, unsigned int* __restrict__ bcount,
                        int E, int NBUK) {
    __shared__ unsigned int lh[MAXBUK];
    int t = threadIdx.x;
    int base = blockIdx.x * BHT;
    for (int b = t; b < NBUK; b += 256) lh[b] = 0u;
    __syncthreads();
    int end = min(base + BHT, E);
    for (int e = base + t; e < end; e += 256)
        atomicAdd(&lh[col[e] >> BSHIFT], 1u);
    __syncthreads();
    for (int b = t; b < NBUK; b += 256) {
        unsigned int c = lh[b];
        if (c) atomicAdd(&bcount[b * PAD], c);
    }
}

// ---------- exclusive scan of bucket counts (1 WG) -> bptr, padded bcur ----------
__global__ void k_bscan(const unsigned int* __restrict__ bcount, int* __restrict__ bptr,
                        int* __restrict__ bcur, int NBUK, int E) {
    __shared__ unsigned int s[256];
    __shared__ unsigned int carry;
    int t = threadIdx.x;
    if (t == 0) carry = 0u;
    __syncthreads();
    for (int base = 0; base < NBUK; base += 256) {
        int i = base + t;
        unsigned int v = (i < NBUK) ? bcount[i * PAD] : 0u;
        s[t] = v;
        __syncthreads();
        for (int off = 1; off < 256; off <<= 1) {
            unsigned int u = (t >= off) ? s[t - off] : 0u;
            __syncthreads();
            s[t] += u;
            __syncthreads();
        }
        unsigned int c = carry;
        if (i < NBUK) { int ex = (int)(c + s[t] - v); bptr[i] = ex; bcur[i * PAD] = ex; }
        __syncthreads();
        if (t == 255) carry = c + s[255];
        __syncthreads();
    }
    if (t == 0) bptr[NBUK] = E;
}

// ---------- three-phase LDS-staged binning: dense, coalesced segment writes ----------
// pack: (col & 255) << 24 | row   (needs N < 2^24)
__global__ void k_binsort(const int* __restrict__ row, const int* __restrict__ col,
                          int* bcur, unsigned int* __restrict__ pairs, int E, int NBUK) {
    __shared__ unsigned int lh[MAXBUK];      // hist -> global cursor
    __shared__ int lbase[MAXBUK];            // local exclusive base
    __shared__ int gbase[MAXBUK];            // global segment base
    __shared__ unsigned int s[256];
    __shared__ unsigned int carry;
    __shared__ unsigned int lpair[BNT];      // staged packed pairs (rank order)
    __shared__ unsigned short lbuk[BNT];     // bucket id per staged entry
    int t = threadIdx.x;
    int base = blockIdx.x * BNT;
    int end = min(base + BNT, E);

    for (int b = t; b < NBUK; b += 256) lh[b] = 0u;
    __syncthreads();
    for (int e = base + t; e < end; e += 256)
        atomicAdd(&lh[col[e] >> BSHIFT], 1u);
    if (t == 0) carry = 0u;
    __syncthreads();

    for (int cb = 0; cb < NBUK; cb += 256) {
        int b = cb + t;
        unsigned int v = (b < NBUK) ? lh[b] : 0u;
        s[t] = v;
        __syncthreads();
        for (int off = 1; off < 256; off <<= 1) {
            unsigned int u = (t >= off) ? s[t - off] : 0u;
            __syncthreads();
            s[t] += u;
            __syncthreads();
        }
        unsigned int c = carry;
        if (b < NBUK) lbase[b] = (int)(c + s[t] - v);
        __syncthreads();
        if (t == 255) carry = c + s[255];
        __syncthreads();
    }

    for (int b = t; b < NBUK; b += 256) {
        unsigned int c = lh[b];
        int g = c ? atomicAdd(&bcur[b * PAD], (int)c) : 0;
        gbase[b] = g;
        lh[b] = (unsigned int)g;
    }
    __syncthreads();

    for (int e = base + t; e < end; e += 256) {
        int c = col[e];
        int b = c >> BSHIFT;
        int gpos = (int)atomicAdd(&lh[b], 1u);
        int lslot = gpos - gbase[b] + lbase[b];
        lpair[lslot] = ((unsigned int)(c & CMASK) << 24) | (unsigned int)row[e];
        lbuk[lslot] = (unsigned short)b;
    }
    __syncthreads();

    int tilesz = end - base;
    for (int j = t; j < tilesz; j += 256) {
        int b = lbuk[j];
        pairs[gbase[b] + (j - lbase[b])] = lpair[j];
    }
}

// ---------- per-bucket fine counting sort in LDS ----------
__global__ void k_csort(const unsigned int* __restrict__ pairs, const int* __restrict__ bptr,
                        int* __restrict__ row_ptr, unsigned int* __restrict__ count,
                        int* __restrict__ sorted_row, int N) {
    __shared__ unsigned int lh[CPB];
    __shared__ int lofs[CPB];
    int b = blockIdx.x;
    int t = threadIdx.x;
    int c0 = b << BSHIFT;
    int s = bptr[b], e = bptr[b + 1];
    lh[t] = 0u;
    __syncthreads();
    for (int j = s + t; j < e; j += 256)
        atomicAdd(&lh[pairs[j] >> 24], 1u);
    __syncthreads();
    unsigned int v = lh[t];
    for (int off = 1; off < 256; off <<= 1) {
        unsigned int u = (t >= off) ? lh[t - off] : 0u;
        __syncthreads();
        lh[t] += u;
        __syncthreads();
    }
    int excl = s + (int)(lh[t] - v);
    if (c0 + t < N) {
        row_ptr[c0 + t] = excl;
        count[c0 + t] = v;
    }
    lofs[t] = excl;
    __syncthreads();
    for (int j = s + t; j < e; j += 256) {
        unsigned int u = pairs[j];
        int pos = atomicAdd(&lofs[u >> 24], 1);
        sorted_row[pos] = (int)(u & 0x00FFFFFFu);
    }
}

// ================= legacy sort fallback (R1-proven) =================

__global__ void k_hist(const int* __restrict__ col, unsigned int* __restrict__ count, int E) {
    int i = blockIdx.x * blockDim.x + threadIdx.x;
    if (i < E) atomicAdd(&count[col[i]], 1u);
}

__global__ void k_scan1(const unsigned int* __restrict__ count, unsigned int* __restrict__ bsum, int N) {
    __shared__ unsigned int s[256];
    int i = blockIdx.x * 256 + threadIdx.x;
    s[threadIdx.x] = (i < N) ? count[i] : 0u;
    __syncthreads();
    for (int off = 128; off > 0; off >>= 1) {
        if (threadIdx.x < off) s[threadIdx.x] += s[threadIdx.x + off];
        __syncthreads();
    }
    if (threadIdx.x == 0) bsum[blockIdx.x] = s[0];
}

__global__ void k_scan2(unsigned int* bsum, int NB) {
    __shared__ unsigned int s[256];
    __shared__ unsigned int carry;
    int t = threadIdx.x;
    if (t == 0) carry = 0u;
    __syncthreads();
    for (int base = 0; base < NB; base += 256) {
        int i = base + t;
        unsigned int v = (i < NB) ? bsum[i] : 0u;
        s[t] = v;
        __syncthreads();
        for (int off = 1; off < 256; off <<= 1) {
            unsigned int u = (t >= off) ? s[t - off] : 0u;
            __syncthreads();
            s[t] += u;
            __syncthreads();
        }
        unsigned int c = carry;
        if (i < NB) bsum[i] = c + s[t] - v;
        __syncthreads();
        if (t == 255) carry = c + s[255];
        __syncthreads();
    }
}

__global__ void k_scan3(const unsigned int* __restrict__ count, const unsigned int* __restrict__ bsum,
                        int* __restrict__ row_ptr, int* __restrict__ cursor, int N) {
    __shared__ unsigned int s[256];
    int t = threadIdx.x;
    int i = blockIdx.x * 256 + t;
    unsigned int v = (i < N) ? count[i] : 0u;
    s[t] = v;
    __syncthreads();
    for (int off = 1; off < 256; off <<= 1) {
        unsigned int u = (t >= off) ? s[t - off] : 0u;
        __syncthreads();
        s[t] += u;
        __syncthreads();
    }
    if (i < N) {
        int start = (int)(bsum[blockIdx.x] + s[t] - v);
        row_ptr[i] = start;
        cursor[i] = start;
    }
}

__global__ void k_permute(const int* __restrict__ row, const int* __restrict__ col,
                          int* cursor, int* __restrict__ sorted_row, int E) {
    int e = blockIdx.x * blockDim.x + threadIdx.x;
    if (e < E) {
        int c = col[e];
        int pos = atomicAdd(&cursor[c], 1);
        sorted_row[pos] = row[e];
    }
}

// ================= compute pipeline =================

// y[i] = dinv_i * x[i]  (R^2, f32);  dinv[i] = rsqrt(deg+1)
__global__ void k_prep(const float* __restrict__ x, const unsigned int* __restrict__ count,
                       float* __restrict__ dinv, float2* __restrict__ y, int N) {
    int i = blockIdx.x * blockDim.x + threadIdx.x;
    if (i >= N) return;
    float dv = rsqrtf((float)count[i] + 1.0f);
    dinv[i] = dv;
    float2 xv = ((const float2*)x)[i];
    y[i] = make_float2(dv * xv.x, dv * xv.y);
}

// fused layer-1: 2-dim gather (rank-2 trick) + W1 + relu/bias -> u = fp16(dinv*h1)
// 16 nodes/WG, 16 lanes/node; lanes split the edge list, shuffle-reduce z.
__global__ void k_agg1(const int* __restrict__ row_ptr, const unsigned int* __restrict__ count,
                       const int* __restrict__ sorted_row, const float2* __restrict__ y,
                       const float* __restrict__ dinv, const float* __restrict__ W1,
                       const float* __restrict__ b1, __half2* __restrict__ u, int N) {
    int t = threadIdx.x;
    int i = blockIdx.x * 16 + (t >> 4), l = t & 15;
    if (i >= N) return;
    int s = row_ptr[i];
    int e = s + (int)count[i];
    float zx = 0.0f, zy = 0.0f;
    for (int j = s + l; j < e; j += 16) {
        float2 yv = y[sorted_row[j]];
        zx += yv.x; zy += yv.y;
    }
    #pragma unroll
    for (int m = 8; m >= 1; m >>= 1) {
        zx += __shfl_xor(zx, m);
        zy += __shfl_xor(zy, m);
    }
    float2 yi = y[i];                      // self loop
    zx += yi.x; zy += yi.y;
    float dv = dinv[i];
    int f = 2 * l;
    float h0 = fmaxf(fmaf(dv, fmaf(zx, W1[f],     zy * W1[FDIM + f]),     b1[f]),     0.0f);
    float h1 = fmaxf(fmaf(dv, fmaf(zx, W1[f + 1], zy * W1[FDIM + f + 1]), b1[f + 1]), 0.0f);
    u[i * 16 + l] = __floats2half2_rn(dv * h0, dv * h1);
}

// fused layer-2 aggregation + pool scatter: w = dinv*(u[i]+Σu[j]); pool += w (W2 hoisted)
__global__ void k_agg_pool(const int* __restrict__ row_ptr, const unsigned int* __restrict__ count,
                           const int* __restrict__ sorted_row, const __half2* __restrict__ g,
                           const float* __restrict__ dinv, const int* __restrict__ batch,
                           float* __restrict__ pool, float* __restrict__ cnt, int N) {
    __shared__ float sh[16][FDIM];
    __shared__ int sb[16];
    int t = threadIdx.x;
    int n = t >> 4, f2 = t & 15;
    int i = blockIdx.x * 16 + n;
    float a = 0.0f, b = 0.0f;
    int bt = -1;
    if (i < N) {
        float dv = dinv[i];
        int s = row_ptr[i];
        int e = s + (int)count[i];
        __half2 hv = g[i * 16 + f2];        // self loop
        a = __low2float(hv); b = __high2float(hv);
        int j = s;
        for (; j + 4 <= e; j += 4) {
            int r0 = sorted_row[j], r1 = sorted_row[j + 1];
            int r2 = sorted_row[j + 2], r3 = sorted_row[j + 3];
            __half2 h0 = g[r0 * 16 + f2], h1 = g[r1 * 16 + f2];
            __half2 h2 = g[r2 * 16 + f2], h3 = g[r3 * 16 + f2];
            a += __low2float(h0); b += __high2float(h0);
            a += __low2float(h1); b += __high2float(h1);
            a += __low2float(h2); b += __high2float(h2);
            a += __low2float(h3); b += __high2float(h3);
        }
        for (; j < e; ++j) {
            __half2 h = g[sorted_row[j] * 16 + f2];
            a += __low2float(h); b += __high2float(h);
        }
        a *= dv; b *= dv;                   // w = dinv * v_pre  (bias+W2 hoisted to k_out)
        bt = batch[i];
    }
    sh[n][2 * f2]     = a;
    sh[n][2 * f2 + 1] = b;
    if (f2 == 0) sb[n] = bt;
    __syncthreads();
    if (bt >= 0 && (n == 0 || sb[n - 1] != bt)) {   // segment leader
        float s0 = a, s1 = b;
        int m = n + 1;
        for (; m < 16 && sb[m] == bt; ++m) {
            s0 += sh[m][2 * f2];
            s1 += sh[m][2 * f2 + 1];
        }
        atomicAdd(&pool[bt * FDIM + 2 * f2],     s0);
        atomicAdd(&pool[bt * FDIM + 2 * f2 + 1], s1);
        if (f2 == 0) atomicAdd(&cnt[bt], (float)(m - n));
    }
}

// out[g] = (pool[g]/cnt[g]) @ W2 + b2   (8 graphs/WG)
__global__ void k_out(const float* __restrict__ pool, const float* __restrict__ cnt,
                      const float* __restrict__ W2, const float* __restrict__ b2,
                      float* __restrict__ out, int G) {
    __shared__ float sW[FDIM * FDIM];
    int t = threadIdx.x;
    for (int k = t; k < FDIM * FDIM; k += 256) sW[k] = W2[k];
    __syncthreads();
    int g = blockIdx.x * 8 + (t >> 5), f = t & 31;
    if (g >= G) return;
    float c = cnt[g];
    float o = 0.0f;
    if (c > 0.0f) {
        float s = 0.0f;
        #pragma unroll
        for (int k = 0; k < FDIM; ++k) s = fmaf(pool[g * FDIM + k], sW[k * FDIM + f], s);
        o = fmaf(s, 1.0f / c, b2[f]);
    }
    out[g * FDIM + f] = o;
}

extern "C" void kernel_launch(void* const* d_in, const int* in_sizes, int n_in,
                              void* d_out, int out_size, void* d_ws, size_t ws_size,
                              hipStream_t stream) {
    const float* x   = (const float*)d_in[0];
    const int*   ei  = (const int*)d_in[1];
    const int* batch = (const int*)d_in[2];
    const float* W1  = (const float*)d_in[4];
    const float* b1  = (const float*)d_in[5];
    const float* W2  = (const float*)d_in[6];
    const float* b2  = (const float*)d_in[7];
    float* out = (float*)d_out;

    int N = in_sizes[0] / 2;
    int E = in_sizes[1] / 2;
    int G = out_size / FDIM;

    const int* row = ei;
    const int* col = ei + E;

    int NB = (N + 255) / 256;
    int NBUK = (N + CMASK) >> BSHIFT;

    // unbuf (u32 units): pairs E  U  u 16N (N*32 halves)
    size_t un = (size_t)(E > 16 * N ? E : 16 * N);
    size_t elemsNew = 2ull * MAXBUK * PAD + (size_t)NBUK + 1 + 3ull * N + (size_t)E
                    + 2ull * N + un + 33ull * G;
    size_t elemsCSR = 4ull * N + 1024 + (size_t)E + 3ull * N + un + 33ull * G;

    if (ws_size >= elemsNew * 4 && N < (1 << 24) && NBUK <= MAXBUK) {
        unsigned int* bcount = (unsigned int*)d_ws;                  // MAXBUK*PAD
        int* bcur            = (int*)(bcount + (size_t)MAXBUK * PAD);// MAXBUK*PAD
        int* bptr            = bcur + (size_t)MAXBUK * PAD;          // NBUK+1
        unsigned int* count  = (unsigned int*)(bptr + NBUK + 1);     // N
        int* row_ptr         = (int*)(count + N);                    // N
        int* sorted_row      = row_ptr + N;                          // E
        float* dinv          = (float*)(sorted_row + E);             // N
        float2* y            = (float2*)(dinv + N);                  // N float2 (2N u32)
        unsigned int* unbuf  = (unsigned int*)(y + N);               // max(E, 16N)
        unsigned int* pairs  = unbuf;
        __half* bufU         = (__half*)unbuf;                       // N*32 halves
        float* pool          = (float*)(unbuf + un);                 // 32G
        float* cnt           = pool + (size_t)G * FDIM;              // G

        hipMemsetAsync(bcount, 0, (size_t)NBUK * PAD * 4, stream);
        hipMemsetAsync(pool, 0, (size_t)(G * FDIM + G) * 4, stream);

        k_bhist<<<(E + BHT - 1) / BHT, 256, 0, stream>>>(col, bcount, E, NBUK);
        k_bscan<<<1, 256, 0, stream>>>(bcount, bptr, bcur, NBUK, E);
        k_binsort<<<(E + BNT - 1) / BNT, 256, 0, stream>>>(row, col, bcur, pairs, E, NBUK);
        k_csort<<<NBUK, 256, 0, stream>>>(pairs, bptr, row_ptr, count, sorted_row, N);

        k_prep<<<NB, 256, 0, stream>>>(x, count, dinv, y, N);
        k_agg1<<<(N + 15) / 16, 256, 0, stream>>>(row_ptr, count, sorted_row, y, dinv,
                                                  W1, b1, (__half2*)bufU, N);
        k_agg_pool<<<(N + 15) / 16, 256, 0, stream>>>(row_ptr, count, sorted_row,
                                                      (const __half2*)bufU, dinv,
                                                      batch, pool, cnt, N);
        k_out<<<(G + 7) / 8, 256, 0, stream>>>(pool, cnt, W2, b2, out, G);
    } else if (ws_size >= elemsCSR * 4) {
        // fallback: R1-proven per-col sort pipeline + new compute kernels
        unsigned int* count  = (unsigned int*)d_ws;                  // N
        int* row_ptr         = (int*)(count + N);                    // N
        int* cursor          = row_ptr + N;                          // N
        unsigned int* bsum   = (unsigned int*)(cursor + N);          // 1024
        int* sorted_row      = (int*)(bsum + 1024);                  // E
        float* dinv          = (float*)(sorted_row + E);             // N
        float2* y            = (float2*)(dinv + N);                  // N float2
        unsigned int* unbuf  = (unsigned int*)(y + N);               // max(E,16N)
        __half* bufU         = (__half*)unbuf;
        float* pool          = (float*)(unbuf + un);
        float* cnt           = pool + (size_t)G * FDIM;

        hipMemsetAsync(count, 0, (size_t)N * 4, stream);
        hipMemsetAsync(pool, 0, (size_t)(G * FDIM + G) * 4, stream);

        k_hist<<<(E + 255) / 256, 256, 0, stream>>>(col, count, E);
        k_scan1<<<NB, 256, 0, stream>>>(count, bsum, N);
        k_scan2<<<1, 256, 0, stream>>>(bsum, NB);
        k_scan3<<<NB, 256, 0, stream>>>(count, bsum, row_ptr, cursor, N);
        k_permute<<<(E + 255) / 256, 256, 0, stream>>>(row, col, cursor, sorted_row, E);

        k_prep<<<NB, 256, 0, stream>>>(x, count, dinv, y, N);
        k_agg1<<<(N + 15) / 16, 256, 0, stream>>>(row_ptr, count, sorted_row, y, dinv,
                                                  W1, b1, (__half2*)bufU, N);
        k_agg_pool<<<(N + 15) / 16, 256, 0, stream>>>(row_ptr, count, sorted_row,
                                                      (const __half2*)bufU, dinv,
                                                      batch, pool, cnt, N);
        k_out<<<(G + 7) / 8, 256, 0, stream>>>(pool, cnt, W2, b2, out, G);
    }
}

// Round 10
// 170.087 us; speedup vs baseline: 14.5843x; 1.0563x over previous
//
#include <hip/hip_runtime.h>

#define FDIM 32
#define BSHIFT 8                 // 256 cols per bucket
#define CPB (1 << BSHIFT)
#define CMASK (CPB - 1)
#define PAD 16                   // cursor stride: 16 u32 = 64B (one cacheline)
#define MAXBUK 512
#define BHT 8192                 // bhist tile (edges per WG)
#define BNT 8192                 // binsort tile (edges per WG)

// ---------- tile-aggregated bucket histogram ----------
__global__ void k_bhist(const int* __restrict__ col, unsigned int* __restrict__ bcount,
                        int E, int NBUK) {
    __shared__ unsigned int lh[MAXBUK];
    int t = threadIdx.x;
    int base = blockIdx.x * BHT;
    for (int b = t; b < NBUK; b += 256) lh[b] = 0u;
    __syncthreads();
    int end = min(base + BHT, E);
    for (int e = base + t; e < end; e += 256)
        atomicAdd(&lh[col[e] >> BSHIFT], 1u);
    __syncthreads();
    for (int b = t; b < NBUK; b += 256) {
        unsigned int c = lh[b];
        if (c) atomicAdd(&bcount[b * PAD], c);
    }
}

// ---------- exclusive scan of bucket counts (1 WG) -> bptr, padded bcur ----------
__global__ void k_bscan(const unsigned int* __restrict__ bcount, int* __restrict__ bptr,
                        int* __restrict__ bcur, int NBUK, int E) {
    __shared__ unsigned int s[256];
    __shared__ unsigned int carry;
    int t = threadIdx.x;
    if (t == 0) carry = 0u;
    __syncthreads();
    for (int base = 0; base < NBUK; base += 256) {
        int i = base + t;
        unsigned int v = (i < NBUK) ? bcount[i * PAD] : 0u;
        s[t] = v;
        __syncthreads();
        for (int off = 1; off < 256; off <<= 1) {
            unsigned int u = (t >= off) ? s[t - off] : 0u;
            __syncthreads();
            s[t] += u;
            __syncthreads();
        }
        unsigned int c = carry;
        if (i < NBUK) { int ex = (int)(c + s[t] - v); bptr[i] = ex; bcur[i * PAD] = ex; }
        __syncthreads();
        if (t == 255) carry = c + s[255];
        __syncthreads();
    }
    if (t == 0) bptr[NBUK] = E;
}

// ---------- three-phase LDS-staged binning: dense, coalesced segment writes ----------
// pack: (col & 255) << 24 | row   (needs N < 2^24)
__global__ void k_binsort(const int* __restrict__ row, const int* __restrict__ col,
                          int* bcur, unsigned int* __restrict__ pairs, int E, int NBUK) {
    __shared__ unsigned int lh[MAXBUK];      // hist -> global cursor
    __shared__ int lbase[MAXBUK];            // local exclusive base
    __shared__ int gbase[MAXBUK];            // global segment base
    __shared__ unsigned int s[256];
    __shared__ unsigned int carry;
    __shared__ unsigned int lpair[BNT];      // staged packed pairs (rank order)
    __shared__ unsigned short lbuk[BNT];     // bucket id per staged entry
    int t = threadIdx.x;
    int base = blockIdx.x * BNT;
    int end = min(base + BNT, E);

    for (int b = t; b < NBUK; b += 256) lh[b] = 0u;
    __syncthreads();
    for (int e = base + t; e < end; e += 256)
        atomicAdd(&lh[col[e] >> BSHIFT], 1u);
    if (t == 0) carry = 0u;
    __syncthreads();

    for (int cb = 0; cb < NBUK; cb += 256) {
        int b = cb + t;
        unsigned int v = (b < NBUK) ? lh[b] : 0u;
        s[t] = v;
        __syncthreads();
        for (int off = 1; off < 256; off <<= 1) {
            unsigned int u = (t >= off) ? s[t - off] : 0u;
            __syncthreads();
            s[t] += u;
            __syncthreads();
        }
        unsigned int c = carry;
        if (b < NBUK) lbase[b] = (int)(c + s[t] - v);
        __syncthreads();
        if (t == 255) carry = c + s[255];
        __syncthreads();
    }

    for (int b = t; b < NBUK; b += 256) {
        unsigned int c = lh[b];
        int g = c ? atomicAdd(&bcur[b * PAD], (int)c) : 0;
        gbase[b] = g;
        lh[b] = (unsigned int)g;
    }
    __syncthreads();

    for (int e = base + t; e < end; e += 256) {
        int c = col[e];
        int b = c >> BSHIFT;
        int gpos = (int)atomicAdd(&lh[b], 1u);
        int lslot = gpos - gbase[b] + lbase[b];
        lpair[lslot] = ((unsigned int)(c & CMASK) << 24) | (unsigned int)row[e];
        lbuk[lslot] = (unsigned short)b;
    }
    __syncthreads();

    int tilesz = end - base;
    for (int j = t; j < tilesz; j += 256) {
        int b = lbuk[j];
        pairs[gbase[b] + (j - lbase[b])] = lpair[j];
    }
}

// ---------- per-bucket fine counting sort in LDS ----------
__global__ void k_csort(const unsigned int* __restrict__ pairs, const int* __restrict__ bptr,
                        int* __restrict__ row_ptr, unsigned int* __restrict__ count,
                        int* __restrict__ sorted_row, int N) {
    __shared__ unsigned int lh[CPB];
    __shared__ int lofs[CPB];
    int b = blockIdx.x;
    int t = threadIdx.x;
    int c0 = b << BSHIFT;
    int s = bptr[b], e = bptr[b + 1];
    lh[t] = 0u;
    __syncthreads();
    for (int j = s + t; j < e; j += 256)
        atomicAdd(&lh[pairs[j] >> 24], 1u);
    __syncthreads();
    unsigned int v = lh[t];
    for (int off = 1; off < 256; off <<= 1) {
        unsigned int u = (t >= off) ? lh[t - off] : 0u;
        __syncthreads();
        lh[t] += u;
        __syncthreads();
    }
    int excl = s + (int)(lh[t] - v);
    if (c0 + t < N) {
        row_ptr[c0 + t] = excl;
        count[c0 + t] = v;
    }
    lofs[t] = excl;
    __syncthreads();
    for (int j = s + t; j < e; j += 256) {
        unsigned int u = pairs[j];
        int pos = atomicAdd(&lofs[u >> 24], 1);
        sorted_row[pos] = (int)(u & 0x00FFFFFFu);
    }
}

// ================= legacy sort fallback (R1-proven) =================

__global__ void k_hist(const int* __restrict__ col, unsigned int* __restrict__ count, int E) {
    int i = blockIdx.x * blockDim.x + threadIdx.x;
    if (i < E) atomicAdd(&count[col[i]], 1u);
}

__global__ void k_scan1(const unsigned int* __restrict__ count, unsigned int* __restrict__ bsum, int N) {
    __shared__ unsigned int s[256];
    int i = blockIdx.x * 256 + threadIdx.x;
    s[threadIdx.x] = (i < N) ? count[i] : 0u;
    __syncthreads();
    for (int off = 128; off > 0; off >>= 1) {
        if (threadIdx.x < off) s[threadIdx.x] += s[threadIdx.x + off];
        __syncthreads();
    }
    if (threadIdx.x == 0) bsum[blockIdx.x] = s[0];
}

__global__ void k_scan2(unsigned int* bsum, int NB) {
    __shared__ unsigned int s[256];
    __shared__ unsigned int carry;
    int t = threadIdx.x;
    if (t == 0) carry = 0u;
    __syncthreads();
    for (int base = 0; base < NB; base += 256) {
        int i = base + t;
        unsigned int v = (i < NB) ? bsum[i] : 0u;
        s[t] = v;
        __syncthreads();
        for (int off = 1; off < 256; off <<= 1) {
            unsigned int u = (t >= off) ? s[t - off] : 0u;
            __syncthreads();
            s[t] += u;
            __syncthreads();
        }
        unsigned int c = carry;
        if (i < NB) bsum[i] = c + s[t] - v;
        __syncthreads();
        if (t == 255) carry = c + s[255];
        __syncthreads();
    }
}

__global__ void k_scan3(const unsigned int* __restrict__ count, const unsigned int* __restrict__ bsum,
                        int* __restrict__ row_ptr, int* __restrict__ cursor, int N) {
    __shared__ unsigned int s[256];
    int t = threadIdx.x;
    int i = blockIdx.x * 256 + t;
    unsigned int v = (i < N) ? count[i] : 0u;
    s[t] = v;
    __syncthreads();
    for (int off = 1; off < 256; off <<= 1) {
        unsigned int u = (t >= off) ? s[t - off] : 0u;
        __syncthreads();
        s[t] += u;
        __syncthreads();
    }
    if (i < N) {
        int start = (int)(bsum[blockIdx.x] + s[t] - v);
        row_ptr[i] = start;
        cursor[i] = start;
    }
}

__global__ void k_permute(const int* __restrict__ row, const int* __restrict__ col,
                          int* cursor, int* __restrict__ sorted_row, int E) {
    int e = blockIdx.x * blockDim.x + threadIdx.x;
    if (e < E) {
        int c = col[e];
        int pos = atomicAdd(&cursor[c], 1);
        sorted_row[pos] = row[e];
    }
}

// ================= compute pipeline (all f32) =================

// y[i] = dinv_i * x[i]  (R^2);  dinv[i] = rsqrt(deg+1)
__global__ void k_prep(const float* __restrict__ x, const unsigned int* __restrict__ count,
                       float* __restrict__ dinv, float2* __restrict__ y, int N) {
    int i = blockIdx.x * blockDim.x + threadIdx.x;
    if (i >= N) return;
    float dv = rsqrtf((float)count[i] + 1.0f);
    dinv[i] = dv;
    float2 xv = ((const float2*)x)[i];
    y[i] = make_float2(dv * xv.x, dv * xv.y);
}

// layer-1 aggregation in input space: triple[i] = (dv*zx, dv*zy, dv)
// 16 nodes/WG, 16 lanes/node; lanes split the edge list, shuffle-reduce z.
__global__ void k_agg1(const int* __restrict__ row_ptr, const unsigned int* __restrict__ count,
                       const int* __restrict__ sorted_row, const float2* __restrict__ y,
                       const float* __restrict__ dinv, float4* __restrict__ triple, int N) {
    int t = threadIdx.x;
    int i = blockIdx.x * 16 + (t >> 4), l = t & 15;
    if (i >= N) return;
    int s = row_ptr[i];
    int e = s + (int)count[i];
    float zx = 0.0f, zy = 0.0f;
    for (int j = s + l; j < e; j += 16) {
        float2 yv = y[sorted_row[j]];
        zx += yv.x; zy += yv.y;
    }
    #pragma unroll
    for (int m = 8; m >= 1; m >>= 1) {
        zx += __shfl_xor(zx, m);
        zy += __shfl_xor(zy, m);
    }
    if (l == 0) {
        float2 yi = y[i];                  // self loop
        zx += yi.x; zy += yi.y;
        float dv = dinv[i];
        triple[i] = make_float4(dv * zx, dv * zy, dv, 0.0f);
    }
}

// layer-2 agg + pool: u_r recomputed on the fly from triple_r (16B, L2-resident)
// u_r[f] = t.z * relu(t.x*W1[0][f] + t.y*W1[1][f] + b1[f]);  w_c = dv_c*(u_c + sum u_r)
__global__ void k_agg_pool(const int* __restrict__ row_ptr, const unsigned int* __restrict__ count,
                           const int* __restrict__ sorted_row, const float4* __restrict__ triple,
                           const float* __restrict__ W1, const float* __restrict__ b1,
                           const int* __restrict__ batch, float* __restrict__ pool,
                           float* __restrict__ cnt, int N) {
    __shared__ float sh[16][FDIM];
    __shared__ int sb[16];
    int t = threadIdx.x;
    int n = t >> 4, f2 = t & 15;
    int i = blockIdx.x * 16 + n;
    // per-lane hoisted coefficients (features 2*f2, 2*f2+1)
    int fa = 2 * f2, fb = fa + 1;
    float w0a = W1[fa], w1a = W1[FDIM + fa], ba = b1[fa];
    float w0b = W1[fb], w1b = W1[FDIM + fb], bb = b1[fb];
    float a = 0.0f, b = 0.0f;
    int bt = -1;
    if (i < N) {
        float4 ts = triple[i];              // self
        float dv = ts.z;
        a = ts.z * fmaxf(fmaf(ts.x, w0a, fmaf(ts.y, w1a, ba)), 0.0f);
        b = ts.z * fmaxf(fmaf(ts.x, w0b, fmaf(ts.y, w1b, bb)), 0.0f);
        int s = row_ptr[i];
        int e = s + (int)count[i];
        int j = s;
        for (; j + 4 <= e; j += 4) {
            int r0 = sorted_row[j], r1 = sorted_row[j + 1];
            int r2 = sorted_row[j + 2], r3 = sorted_row[j + 3];
            float4 t0 = triple[r0], t1 = triple[r1], t2 = triple[r2], t3 = triple[r3];
            a += t0.z * fmaxf(fmaf(t0.x, w0a, fmaf(t0.y, w1a, ba)), 0.0f);
            b += t0.z * fmaxf(fmaf(t0.x, w0b, fmaf(t0.y, w1b, bb)), 0.0f);
            a += t1.z * fmaxf(fmaf(t1.x, w0a, fmaf(t1.y, w1a, ba)), 0.0f);
            b += t1.z * fmaxf(fmaf(t1.x, w0b, fmaf(t1.y, w1b, bb)), 0.0f);
            a += t2.z * fmaxf(fmaf(t2.x, w0a, fmaf(t2.y, w1a, ba)), 0.0f);
            b += t2.z * fmaxf(fmaf(t2.x, w0b, fmaf(t2.y, w1b, bb)), 0.0f);
            a += t3.z * fmaxf(fmaf(t3.x, w0a, fmaf(t3.y, w1a, ba)), 0.0f);
            b += t3.z * fmaxf(fmaf(t3.x, w0b, fmaf(t3.y, w1b, bb)), 0.0f);
        }
        for (; j < e; ++j) {
            float4 tr = triple[sorted_row[j]];
            a += tr.z * fmaxf(fmaf(tr.x, w0a, fmaf(tr.y, w1a, ba)), 0.0f);
            b += tr.z * fmaxf(fmaf(tr.x, w0b, fmaf(tr.y, w1b, bb)), 0.0f);
        }
        a *= dv; b *= dv;                   // w = dinv * v_pre  (bias+W2 hoisted to k_out)
        bt = batch[i];
    }
    sh[n][fa] = a;
    sh[n][fb] = b;
    if (f2 == 0) sb[n] = bt;
    __syncthreads();
    if (bt >= 0 && (n == 0 || sb[n - 1] != bt)) {   // segment leader
        float s0 = a, s1 = b;
        int m = n + 1;
        for (; m < 16 && sb[m] == bt; ++m) {
            s0 += sh[m][fa];
            s1 += sh[m][fb];
        }
        atomicAdd(&pool[bt * FDIM + fa], s0);
        atomicAdd(&pool[bt * FDIM + fb], s1);
        if (f2 == 0) atomicAdd(&cnt[bt], (float)(m - n));
    }
}

// out[g] = (pool[g]/cnt[g]) @ W2 + b2   (8 graphs/WG)
__global__ void k_out(const float* __restrict__ pool, const float* __restrict__ cnt,
                      const float* __restrict__ W2, const float* __restrict__ b2,
                      float* __restrict__ out, int G) {
    __shared__ float sW[FDIM * FDIM];
    int t = threadIdx.x;
    for (int k = t; k < FDIM * FDIM; k += 256) sW[k] = W2[k];
    __syncthreads();
    int g = blockIdx.x * 8 + (t >> 5), f = t & 31;
    if (g >= G) return;
    float c = cnt[g];
    float o = 0.0f;
    if (c > 0.0f) {
        float s = 0.0f;
        #pragma unroll
        for (int k = 0; k < FDIM; ++k) s = fmaf(pool[g * FDIM + k], sW[k * FDIM + f], s);
        o = fmaf(s, 1.0f / c, b2[f]);
    }
    out[g * FDIM + f] = o;
}

extern "C" void kernel_launch(void* const* d_in, const int* in_sizes, int n_in,
                              void* d_out, int out_size, void* d_ws, size_t ws_size,
                              hipStream_t stream) {
    const float* x   = (const float*)d_in[0];
    const int*   ei  = (const int*)d_in[1];
    const int* batch = (const int*)d_in[2];
    const float* W1  = (const float*)d_in[4];
    const float* b1  = (const float*)d_in[5];
    const float* W2  = (const float*)d_in[6];
    const float* b2  = (const float*)d_in[7];
    float* out = (float*)d_out;

    int N = in_sizes[0] / 2;
    int E = in_sizes[1] / 2;
    int G = out_size / FDIM;

    const int* row = ei;
    const int* col = ei + E;

    int NB = (N + 255) / 256;
    int NBUK = (N + CMASK) >> BSHIFT;

    // unbuf (u32 units): pairs E  U  triple 4N (float4 per node)
    size_t un = (size_t)(E > 4 * N ? E : 4 * N);
    size_t elemsNew = 2ull * MAXBUK * PAD + (size_t)NBUK + 1 + 3ull * N + (size_t)E
                    + 2ull * N + un + 33ull * G + 4;   // +4 alignment slack
    size_t elemsCSR = 4ull * N + 1024 + (size_t)E + 3ull * N + un + 33ull * G + 4;

    if (ws_size >= elemsNew * 4 && N < (1 << 24) && NBUK <= MAXBUK) {
        unsigned int* bcount = (unsigned int*)d_ws;                  // MAXBUK*PAD
        int* bcur            = (int*)(bcount + (size_t)MAXBUK * PAD);// MAXBUK*PAD
        int* bptr            = bcur + (size_t)MAXBUK * PAD;          // NBUK+1
        unsigned int* count  = (unsigned int*)(bptr + NBUK + 1);     // N
        int* row_ptr         = (int*)(count + N);                    // N
        int* sorted_row      = row_ptr + N;                          // E
        float* dinv          = (float*)(sorted_row + E);             // N
        float2* y            = (float2*)(dinv + N);                  // N float2 (2N u32)
        unsigned int* ualign = (unsigned int*)(y + N);
        // 16B-align the union buffer (float4 access)
        unsigned int* unbuf  = (unsigned int*)(((size_t)ualign + 15) & ~(size_t)15);
        unsigned int* pairs  = unbuf;                                // E (dead after csort)
        float4* triple       = (float4*)unbuf;                       // N float4 (aliases pairs)
        float* pool          = (float*)(unbuf + un);                 // 32G
        float* cnt           = pool + (size_t)G * FDIM;              // G

        hipMemsetAsync(bcount, 0, (size_t)NBUK * PAD * 4, stream);
        hipMemsetAsync(pool, 0, (size_t)(G * FDIM + G) * 4, stream);

        k_bhist<<<(E + BHT - 1) / BHT, 256, 0, stream>>>(col, bcount, E, NBUK);
        k_bscan<<<1, 256, 0, stream>>>(bcount, bptr, bcur, NBUK, E);
        k_binsort<<<(E + BNT - 1) / BNT, 256, 0, stream>>>(row, col, bcur, pairs, E, NBUK);
        k_csort<<<NBUK, 256, 0, stream>>>(pairs, bptr, row_ptr, count, sorted_row, N);

        k_prep<<<NB, 256, 0, stream>>>(x, count, dinv, y, N);
        k_agg1<<<(N + 15) / 16, 256, 0, stream>>>(row_ptr, count, sorted_row, y, dinv,
                                                  triple, N);
        k_agg_pool<<<(N + 15) / 16, 256, 0, stream>>>(row_ptr, count, sorted_row, triple,
                                                      W1, b1, batch, pool, cnt, N);
        k_out<<<(G + 7) / 8, 256, 0, stream>>>(pool, cnt, W2, b2, out, G);
    } else if (ws_size >= elemsCSR * 4) {
        // fallback: R1-proven per-col sort pipeline + new compute kernels
        unsigned int* count  = (unsigned int*)d_ws;                  // N
        int* row_ptr         = (int*)(count + N);                    // N
        int* cursor          = row_ptr + N;                          // N
        unsigned int* bsum   = (unsigned int*)(cursor + N);          // 1024
        int* sorted_row      = (int*)(bsum + 1024);                  // E
        float* dinv          = (float*)(sorted_row + E);             // N
        float2* y            = (float2*)(dinv + N);                  // N float2
        unsigned int* ualign = (unsigned int*)(y + N);
        unsigned int* unbuf  = (unsigned int*)(((size_t)ualign + 15) & ~(size_t)15);
        float4* triple       = (float4*)unbuf;
        float* pool          = (float*)(unbuf + un);
        float* cnt           = pool + (size_t)G * FDIM;

        hipMemsetAsync(count, 0, (size_t)N * 4, stream);
        hipMemsetAsync(pool, 0, (size_t)(G * FDIM + G) * 4, stream);

        k_hist<<<(E + 255) / 256, 256, 0, stream>>>(col, count, E);
        k_scan1<<<NB, 256, 0, stream>>>(count, bsum, N);
        k_scan2<<<1, 256, 0, stream>>>(bsum, NB);
        k_scan3<<<NB, 256, 0, stream>>>(count, bsum, row_ptr, cursor, N);
        k_permute<<<(E + 255) / 256, 256, 0, stream>>>(row, col, cursor, sorted_row, E);

        k_prep<<<NB, 256, 0, stream>>>(x, count, dinv, y, N);
        k_agg1<<<(N + 15) / 16, 256, 0, stream>>>(row_ptr, count, sorted_row, y, dinv,
                                                  triple, N);
        k_agg_pool<<<(N + 15) / 16, 256, 0, stream>>>(row_ptr, count, sorted_row, triple,
                                                      W1, b1, batch, pool, cnt, N);
        k_out<<<(G + 7) / 8, 256, 0, stream>>>(pool, cnt, W2, b2, out, G);
    }
}

// Round 11
// 168.465 us; speedup vs baseline: 14.7247x; 1.0096x over previous
//
#include <hip/hip_runtime.h>

#define FDIM 32
#define BSHIFT 8                 // 256 cols per bucket
#define CPB (1 << BSHIFT)
#define CMASK (CPB - 1)
#define PAD 16                   // cursor stride: 16 u32 = 64B (one cacheline)
#define MAXBUK 512
#define BHT 8192                 // bhist tile (edges per WG)
#define BNT 4096                 // binsort tile (edges per WG, 16/thread)

// ---------- tile-aggregated bucket histogram ----------
__global__ void k_bhist(const int* __restrict__ col, unsigned int* __restrict__ bcount,
                        int E, int NBUK) {
    __shared__ unsigned int lh[MAXBUK];
    int t = threadIdx.x;
    int base = blockIdx.x * BHT;
    for (int b = t; b < NBUK; b += 256) lh[b] = 0u;
    __syncthreads();
    int end = min(base + BHT, E);
    for (int e = base + t; e < end; e += 256)
        atomicAdd(&lh[col[e] >> BSHIFT], 1u);
    __syncthreads();
    for (int b = t; b < NBUK; b += 256) {
        unsigned int c = lh[b];
        if (c) atomicAdd(&bcount[b * PAD], c);
    }
}

// ---------- exclusive scan of bucket counts (1 WG, wave-shuffle) -> bptr, padded bcur ----------
__global__ void k_bscan(const unsigned int* __restrict__ bcount, int* __restrict__ bptr,
                        int* __restrict__ bcur, int NBUK, int E) {
    __shared__ unsigned int swave[4];
    int t = threadIdx.x;
    int w = t >> 6, lane = t & 63;
    int i0 = w * 128 + lane * 2;             // entries i0, i0+1 over [0, 512)
    unsigned int a = (i0     < NBUK) ? bcount[(size_t)i0 * PAD]       : 0u;
    unsigned int b = (i0 + 1 < NBUK) ? bcount[(size_t)(i0 + 1) * PAD] : 0u;
    unsigned int sum = a + b;
    unsigned int sc = sum;
    #pragma unroll
    for (int off = 1; off < 64; off <<= 1) {
        unsigned int u = __shfl_up(sc, off);
        if (lane >= off) sc += u;
    }
    if (lane == 63) swave[w] = sc;
    __syncthreads();
    unsigned int woff = 0;
    for (int k = 0; k < w; ++k) woff += swave[k];
    unsigned int e0 = woff + sc - sum;
    unsigned int e1 = e0 + a;
    if (i0 < NBUK)     { bptr[i0]     = (int)e0; bcur[(size_t)i0 * PAD]       = (int)e0; }
    if (i0 + 1 < NBUK) { bptr[i0 + 1] = (int)e1; bcur[(size_t)(i0 + 1) * PAD] = (int)e1; }
    if (t == 0) bptr[NBUK] = E;
}

// ---------- LDS-staged binning (wave-shuffle scan, reg-cached tile) ----------
// pack: (col & 255) << 24 | row   (needs N < 2^24)
__global__ void k_binsort(const int* __restrict__ row, const int* __restrict__ col,
                          int* bcur, unsigned int* __restrict__ pairs, int E, int NBUK) {
    __shared__ unsigned int lh[MAXBUK];      // hist -> global cursor
    __shared__ int lbase[MAXBUK];            // local exclusive base
    __shared__ int gbase[MAXBUK];            // global segment base
    __shared__ unsigned int swave[4];
    __shared__ unsigned int lpair[BNT];      // staged packed pairs (rank order)
    __shared__ unsigned short lbuk[BNT];     // bucket id per staged entry
    int t = threadIdx.x;
    int w = t >> 6, lane = t & 63;
    int base = blockIdx.x * BNT;
    int end = min(base + BNT, E);

    // zero full 512 (scan covers MAXBUK, zero-padded)
    lh[t] = 0u; lh[t + 256] = 0u;
    __syncthreads();

    // phase 1: tile histogram, caching (col,row) in registers (static idx)
    int cl[16], rw[16];
    #pragma unroll
    for (int k = 0; k < 16; ++k) {
        int e = base + k * 256 + t;
        if (e < end) {
            cl[k] = col[e];
            rw[k] = row[e];
            atomicAdd(&lh[cl[k] >> BSHIFT], 1u);
        }
    }
    __syncthreads();

    // wave-shuffle exclusive scan of lh[0..512) -> lbase
    int i0 = w * 128 + lane * 2;
    unsigned int a = lh[i0], b = lh[i0 + 1];
    unsigned int sum = a + b;
    unsigned int sc = sum;
    #pragma unroll
    for (int off = 1; off < 64; off <<= 1) {
        unsigned int u = __shfl_up(sc, off);
        if (lane >= off) sc += u;
    }
    if (lane == 63) swave[w] = sc;
    __syncthreads();
    unsigned int woff = 0;
    for (int k = 0; k < w; ++k) woff += swave[k];
    lbase[i0]     = (int)(woff + sc - sum);
    lbase[i0 + 1] = (int)(woff + sc - sum + a);
    __syncthreads();

    // phase 2: reserve dense global segments; lh becomes global cursor
    for (int bb = t; bb < MAXBUK; bb += 256) {
        unsigned int c = lh[bb];
        int g = c ? atomicAdd(&bcur[bb * PAD], (int)c) : 0;
        gbase[bb] = g;
        lh[bb] = (unsigned int)g;
    }
    __syncthreads();

    // phase 3a: scatter into LDS by rank (from registers)
    #pragma unroll
    for (int k = 0; k < 16; ++k) {
        int e = base + k * 256 + t;
        if (e < end) {
            int bb = cl[k] >> BSHIFT;
            int gpos = (int)atomicAdd(&lh[bb], 1u);
            int lslot = gpos - gbase[bb] + lbase[bb];
            lpair[lslot] = ((unsigned int)(cl[k] & CMASK) << 24) | (unsigned int)rw[k];
            lbuk[lslot] = (unsigned short)bb;
        }
    }
    __syncthreads();

    // phase 3b: linear LDS -> coalesced global segment writes
    int tilesz = end - base;
    for (int j = t; j < tilesz; j += 256) {
        int bb = lbuk[j];
        pairs[gbase[bb] + (j - lbase[bb])] = lpair[j];
    }
}

// ---------- per-bucket fine counting sort in LDS (wave-shuffle scan) ----------
__global__ void k_csort(const unsigned int* __restrict__ pairs, const int* __restrict__ bptr,
                        int* __restrict__ row_ptr, unsigned int* __restrict__ count,
                        int* __restrict__ sorted_row, int N) {
    __shared__ unsigned int lh[CPB];
    __shared__ int lofs[CPB];
    __shared__ unsigned int swave[4];
    int b = blockIdx.x;
    int t = threadIdx.x;
    int w = t >> 6, lane = t & 63;
    int c0 = b << BSHIFT;
    int s = bptr[b], e = bptr[b + 1];
    lh[t] = 0u;
    __syncthreads();
    for (int j = s + t; j < e; j += 256)
        atomicAdd(&lh[pairs[j] >> 24], 1u);
    __syncthreads();
    unsigned int v = lh[t];
    unsigned int sc = v;
    #pragma unroll
    for (int off = 1; off < 64; off <<= 1) {
        unsigned int u = __shfl_up(sc, off);
        if (lane >= off) sc += u;
    }
    if (lane == 63) swave[w] = sc;
    __syncthreads();
    unsigned int woff = 0;
    for (int k = 0; k < w; ++k) woff += swave[k];
    int excl = s + (int)(woff + sc - v);
    if (c0 + t < N) {
        row_ptr[c0 + t] = excl;
        count[c0 + t] = v;
    }
    lofs[t] = excl;
    __syncthreads();
    for (int j = s + t; j < e; j += 256) {
        unsigned int u = pairs[j];
        int pos = atomicAdd(&lofs[u >> 24], 1);
        sorted_row[pos] = (int)(u & 0x00FFFFFFu);
    }
}

// ================= legacy sort fallback (R1-proven) =================

__global__ void k_hist(const int* __restrict__ col, unsigned int* __restrict__ count, int E) {
    int i = blockIdx.x * blockDim.x + threadIdx.x;
    if (i < E) atomicAdd(&count[col[i]], 1u);
}

__global__ void k_scan1(const unsigned int* __restrict__ count, unsigned int* __restrict__ bsum, int N) {
    __shared__ unsigned int s[256];
    int i = blockIdx.x * 256 + threadIdx.x;
    s[threadIdx.x] = (i < N) ? count[i] : 0u;
    __syncthreads();
    for (int off = 128; off > 0; off >>= 1) {
        if (threadIdx.x < off) s[threadIdx.x] += s[threadIdx.x + off];
        __syncthreads();
    }
    if (threadIdx.x == 0) bsum[blockIdx.x] = s[0];
}

__global__ void k_scan2(unsigned int* bsum, int NB) {
    __shared__ unsigned int s[256];
    __shared__ unsigned int carry;
    int t = threadIdx.x;
    if (t == 0) carry = 0u;
    __syncthreads();
    for (int base = 0; base < NB; base += 256) {
        int i = base + t;
        unsigned int v = (i < NB) ? bsum[i] : 0u;
        s[t] = v;
        __syncthreads();
        for (int off = 1; off < 256; off <<= 1) {
            unsigned int u = (t >= off) ? s[t - off] : 0u;
            __syncthreads();
            s[t] += u;
            __syncthreads();
        }
        unsigned int c = carry;
        if (i < NB) bsum[i] = c + s[t] - v;
        __syncthreads();
        if (t == 255) carry = c + s[255];
        __syncthreads();
    }
}

__global__ void k_scan3(const unsigned int* __restrict__ count, const unsigned int* __restrict__ bsum,
                        int* __restrict__ row_ptr, int* __restrict__ cursor, int N) {
    __shared__ unsigned int s[256];
    int t = threadIdx.x;
    int i = blockIdx.x * 256 + t;
    unsigned int v = (i < N) ? count[i] : 0u;
    s[t] = v;
    __syncthreads();
    for (int off = 1; off < 256; off <<= 1) {
        unsigned int u = (t >= off) ? s[t - off] : 0u;
        __syncthreads();
        s[t] += u;
        __syncthreads();
    }
    if (i < N) {
        int start = (int)(bsum[blockIdx.x] + s[t] - v);
        row_ptr[i] = start;
        cursor[i] = start;
    }
}

__global__ void k_permute(const int* __restrict__ row, const int* __restrict__ col,
                          int* cursor, int* __restrict__ sorted_row, int E) {
    int e = blockIdx.x * blockDim.x + threadIdx.x;
    if (e < E) {
        int c = col[e];
        int pos = atomicAdd(&cursor[c], 1);
        sorted_row[pos] = row[e];
    }
}

// ================= compute pipeline (all f32) =================

// y[i] = dinv_i * x[i]  (R^2);  dinv[i] = rsqrt(deg+1)
__global__ void k_prep(const float* __restrict__ x, const unsigned int* __restrict__ count,
                       float* __restrict__ dinv, float2* __restrict__ y, int N) {
    int i = blockIdx.x * blockDim.x + threadIdx.x;
    if (i >= N) return;
    float dv = rsqrtf((float)count[i] + 1.0f);
    dinv[i] = dv;
    float2 xv = ((const float2*)x)[i];
    y[i] = make_float2(dv * xv.x, dv * xv.y);
}

// layer-1 aggregation in input space: triple[i] = (dv*zx, dv*zy, dv)
__global__ void k_agg1(const int* __restrict__ row_ptr, const unsigned int* __restrict__ count,
                       const int* __restrict__ sorted_row, const float2* __restrict__ y,
                       const float* __restrict__ dinv, float4* __restrict__ triple, int N) {
    int t = threadIdx.x;
    int i = blockIdx.x * 16 + (t >> 4), l = t & 15;
    if (i >= N) return;
    int s = row_ptr[i];
    int e = s + (int)count[i];
    float zx = 0.0f, zy = 0.0f;
    for (int j = s + l; j < e; j += 16) {
        float2 yv = y[sorted_row[j]];
        zx += yv.x; zy += yv.y;
    }
    #pragma unroll
    for (int m = 8; m >= 1; m >>= 1) {
        zx += __shfl_xor(zx, m);
        zy += __shfl_xor(zy, m);
    }
    if (l == 0) {
        float2 yi = y[i];                  // self loop
        zx += yi.x; zy += yi.y;
        float dv = dinv[i];
        triple[i] = make_float4(dv * zx, dv * zy, dv, 0.0f);
    }
}

// layer-2 agg + pool: u_r recomputed on the fly from triple_r (16B, L2-resident)
__global__ void k_agg_pool(const int* __restrict__ row_ptr, const unsigned int* __restrict__ count,
                           const int* __restrict__ sorted_row, const float4* __restrict__ triple,
                           const float* __restrict__ W1, const float* __restrict__ b1,
                           const int* __restrict__ batch, float* __restrict__ pool,
                           float* __restrict__ cnt, int N) {
    __shared__ float sh[16][FDIM];
    __shared__ int sb[16];
    int t = threadIdx.x;
    int n = t >> 4, f2 = t & 15;
    int i = blockIdx.x * 16 + n;
    int fa = 2 * f2, fb = fa + 1;
    float w0a = W1[fa], w1a = W1[FDIM + fa], ba = b1[fa];
    float w0b = W1[fb], w1b = W1[FDIM + fb], bb = b1[fb];
    float a = 0.0f, b = 0.0f;
    int bt = -1;
    if (i < N) {
        float4 ts = triple[i];              // self
        float dv = ts.z;
        a = ts.z * fmaxf(fmaf(ts.x, w0a, fmaf(ts.y, w1a, ba)), 0.0f);
        b = ts.z * fmaxf(fmaf(ts.x, w0b, fmaf(ts.y, w1b, bb)), 0.0f);
        int s = row_ptr[i];
        int e = s + (int)count[i];
        int j = s;
        for (; j + 4 <= e; j += 4) {
            int r0 = sorted_row[j], r1 = sorted_row[j + 1];
            int r2 = sorted_row[j + 2], r3 = sorted_row[j + 3];
            float4 t0 = triple[r0], t1 = triple[r1], t2 = triple[r2], t3 = triple[r3];
            a += t0.z * fmaxf(fmaf(t0.x, w0a, fmaf(t0.y, w1a, ba)), 0.0f);
            b += t0.z * fmaxf(fmaf(t0.x, w0b, fmaf(t0.y, w1b, bb)), 0.0f);
            a += t1.z * fmaxf(fmaf(t1.x, w0a, fmaf(t1.y, w1a, ba)), 0.0f);
            b += t1.z * fmaxf(fmaf(t1.x, w0b, fmaf(t1.y, w1b, bb)), 0.0f);
            a += t2.z * fmaxf(fmaf(t2.x, w0a, fmaf(t2.y, w1a, ba)), 0.0f);
            b += t2.z * fmaxf(fmaf(t2.x, w0b, fmaf(t2.y, w1b, bb)), 0.0f);
            a += t3.z * fmaxf(fmaf(t3.x, w0a, fmaf(t3.y, w1a, ba)), 0.0f);
            b += t3.z * fmaxf(fmaf(t3.x, w0b, fmaf(t3.y, w1b, bb)), 0.0f);
        }
        for (; j < e; ++j) {
            float4 tr = triple[sorted_row[j]];
            a += tr.z * fmaxf(fmaf(tr.x, w0a, fmaf(tr.y, w1a, ba)), 0.0f);
            b += tr.z * fmaxf(fmaf(tr.x, w0b, fmaf(tr.y, w1b, bb)), 0.0f);
        }
        a *= dv; b *= dv;                   // w = dinv * v_pre  (bias+W2 hoisted to k_out)
        bt = batch[i];
    }
    sh[n][fa] = a;
    sh[n][fb] = b;
    if (f2 == 0) sb[n] = bt;
    __syncthreads();
    if (bt >= 0 && (n == 0 || sb[n - 1] != bt)) {   // segment leader
        float s0 = a, s1 = b;
        int m = n + 1;
        for (; m < 16 && sb[m] == bt; ++m) {
            s0 += sh[m][fa];
            s1 += sh[m][fb];
        }
        atomicAdd(&pool[bt * FDIM + fa], s0);
        atomicAdd(&pool[bt * FDIM + fb], s1);
        if (f2 == 0) atomicAdd(&cnt[bt], (float)(m - n));
    }
}

// out[g] = (pool[g]/cnt[g]) @ W2 + b2   (8 graphs/WG)
__global__ void k_out(const float* __restrict__ pool, const float* __restrict__ cnt,
                      const float* __restrict__ W2, const float* __restrict__ b2,
                      float* __restrict__ out, int G) {
    __shared__ float sW[FDIM * FDIM];
    int t = threadIdx.x;
    for (int k = t; k < FDIM * FDIM; k += 256) sW[k] = W2[k];
    __syncthreads();
    int g = blockIdx.x * 8 + (t >> 5), f = t & 31;
    if (g >= G) return;
    float c = cnt[g];
    float o = 0.0f;
    if (c > 0.0f) {
        float s = 0.0f;
        #pragma unroll
        for (int k = 0; k < FDIM; ++k) s = fmaf(pool[g * FDIM + k], sW[k * FDIM + f], s);
        o = fmaf(s, 1.0f / c, b2[f]);
    }
    out[g * FDIM + f] = o;
}

extern "C" void kernel_launch(void* const* d_in, const int* in_sizes, int n_in,
                              void* d_out, int out_size, void* d_ws, size_t ws_size,
                              hipStream_t stream) {
    const float* x   = (const float*)d_in[0];
    const int*   ei  = (const int*)d_in[1];
    const int* batch = (const int*)d_in[2];
    const float* W1  = (const float*)d_in[4];
    const float* b1  = (const float*)d_in[5];
    const float* W2  = (const float*)d_in[6];
    const float* b2  = (const float*)d_in[7];
    float* out = (float*)d_out;

    int N = in_sizes[0] / 2;
    int E = in_sizes[1] / 2;
    int G = out_size / FDIM;

    const int* row = ei;
    const int* col = ei + E;

    int NB = (N + 255) / 256;
    int NBUK = (N + CMASK) >> BSHIFT;

    // unbuf (u32 units): pairs E  U  triple 4N (float4 per node)
    size_t un = (size_t)(E > 4 * N ? E : 4 * N);
    size_t elemsNew = 2ull * MAXBUK * PAD + (size_t)NBUK + 1 + 3ull * N + (size_t)E
                    + 2ull * N + un + 33ull * G + 4;   // +4 alignment slack
    size_t elemsCSR = 4ull * N + 1024 + (size_t)E + 3ull * N + un + 33ull * G + 4;

    if (ws_size >= elemsNew * 4 && N < (1 << 24) && NBUK <= MAXBUK) {
        unsigned int* bcount = (unsigned int*)d_ws;                  // MAXBUK*PAD
        int* bcur            = (int*)(bcount + (size_t)MAXBUK * PAD);// MAXBUK*PAD
        int* bptr            = bcur + (size_t)MAXBUK * PAD;          // NBUK+1
        unsigned int* count  = (unsigned int*)(bptr + NBUK + 1);     // N
        int* row_ptr         = (int*)(count + N);                    // N
        int* sorted_row      = row_ptr + N;                          // E
        float* dinv          = (float*)(sorted_row + E);             // N
        float2* y            = (float2*)(dinv + N);                  // N float2 (2N u32)
        unsigned int* ualign = (unsigned int*)(y + N);
        unsigned int* unbuf  = (unsigned int*)(((size_t)ualign + 15) & ~(size_t)15);
        unsigned int* pairs  = unbuf;                                // E (dead after csort)
        float4* triple       = (float4*)unbuf;                       // N float4 (aliases pairs)
        float* pool          = (float*)(unbuf + un);                 // 32G
        float* cnt           = pool + (size_t)G * FDIM;              // G

        hipMemsetAsync(bcount, 0, (size_t)MAXBUK * PAD * 4, stream);
        hipMemsetAsync(pool, 0, (size_t)(G * FDIM + G) * 4, stream);

        k_bhist<<<(E + BHT - 1) / BHT, 256, 0, stream>>>(col, bcount, E, NBUK);
        k_bscan<<<1, 256, 0, stream>>>(bcount, bptr, bcur, NBUK, E);
        k_binsort<<<(E + BNT - 1) / BNT, 256, 0, stream>>>(row, col, bcur, pairs, E, NBUK);
        k_csort<<<NBUK, 256, 0, stream>>>(pairs, bptr, row_ptr, count, sorted_row, N);

        k_prep<<<NB, 256, 0, stream>>>(x, count, dinv, y, N);
        k_agg1<<<(N + 15) / 16, 256, 0, stream>>>(row_ptr, count, sorted_row, y, dinv,
                                                  triple, N);
        k_agg_pool<<<(N + 15) / 16, 256, 0, stream>>>(row_ptr, count, sorted_row, triple,
                                                      W1, b1, batch, pool, cnt, N);
        k_out<<<(G + 7) / 8, 256, 0, stream>>>(pool, cnt, W2, b2, out, G);
    } else if (ws_size >= elemsCSR * 4) {
        // fallback: R1-proven per-col sort pipeline + new compute kernels
        unsigned int* count  = (unsigned int*)d_ws;                  // N
        int* row_ptr         = (int*)(count + N);                    // N
        int* cursor          = row_ptr + N;                          // N
        unsigned int* bsum   = (unsigned int*)(cursor + N);          // 1024
        int* sorted_row      = (int*)(bsum + 1024);                  // E
        float* dinv          = (float*)(sorted_row + E);             // N
        float2* y            = (float2*)(dinv + N);                  // N float2
        unsigned int* ualign = (unsigned int*)(y + N);
        unsigned int* unbuf  = (unsigned int*)(((size_t)ualign + 15) & ~(size_t)15);
        float4* triple       = (float4*)unbuf;
        float* pool          = (float*)(unbuf + un);
        float* cnt           = pool + (size_t)G * FDIM;

        hipMemsetAsync(count, 0, (size_t)N * 4, stream);
        hipMemsetAsync(pool, 0, (size_t)(G * FDIM + G) * 4, stream);

        k_hist<<<(E + 255) / 256, 256, 0, stream>>>(col, count, E);
        k_scan1<<<NB, 256, 0, stream>>>(count, bsum, N);
        k_scan2<<<1, 256, 0, stream>>>(bsum, NB);
        k_scan3<<<NB, 256, 0, stream>>>(count, bsum, row_ptr, cursor, N);
        k_permute<<<(E + 255) / 256, 256, 0, stream>>>(row, col, cursor, sorted_row, E);

        k_prep<<<NB, 256, 0, stream>>>(x, count, dinv, y, N);
        k_agg1<<<(N + 15) / 16, 256, 0, stream>>>(row_ptr, count, sorted_row, y, dinv,
                                                  triple, N);
        k_agg_pool<<<(N + 15) / 16, 256, 0, stream>>>(row_ptr, count, sorted_row, triple,
                                                      W1, b1, batch, pool, cnt, N);
        k_out<<<(G + 7) / 8, 256, 0, stream>>>(pool, cnt, W2, b2, out, G);
    }
}

// Round 12
// 150.842 us; speedup vs baseline: 16.4450x; 1.1168x over previous
//
#include <hip/hip_runtime.h>

#define FDIM 32
#define BSHIFT 8                 // 256 cols per bucket
#define CPB (1 << BSHIFT)
#define CMASK (CPB - 1)
#define PAD 16                   // cursor stride: 16 u32 = 64B (one cacheline)
#define MAXBUK 512
#define BNT 4096                 // binsort tile (edges per WG, 16/thread)
#define LCAP 12288               // csort LDS staging capacity (48 KB)

// ---------- LDS-staged binning into fixed-capacity bucket regions ----------
// pack: (col & 255) << 24 | row   (needs N < 2^24)
__global__ void k_binsort(const int* __restrict__ row, const int* __restrict__ col,
                          int* bcur, unsigned int* __restrict__ buf, int E, int cap, int NBUK) {
    __shared__ unsigned int lh[MAXBUK];      // hist -> global cursor
    __shared__ int lbase[MAXBUK];            // local exclusive base
    __shared__ int gbase[MAXBUK];            // global segment base
    __shared__ unsigned int swave[4];
    __shared__ unsigned int lpair[BNT];      // staged packed pairs (rank order)
    __shared__ unsigned short lbuk[BNT];     // bucket id per staged entry
    int t = threadIdx.x;
    int w = t >> 6, lane = t & 63;
    int base = blockIdx.x * BNT;
    int end = min(base + BNT, E);

    lh[t] = 0u; lh[t + 256] = 0u;
    __syncthreads();

    // phase 1: tile histogram, caching (col,row) in registers
    int cl[16], rw[16];
    #pragma unroll
    for (int k = 0; k < 16; ++k) {
        int e = base + k * 256 + t;
        if (e < end) {
            cl[k] = col[e];
            rw[k] = row[e];
            atomicAdd(&lh[cl[k] >> BSHIFT], 1u);
        }
    }
    __syncthreads();

    // wave-shuffle exclusive scan of lh[0..512) -> lbase
    int i0 = w * 128 + lane * 2;
    unsigned int a = lh[i0], b = lh[i0 + 1];
    unsigned int sum = a + b;
    unsigned int sc = sum;
    #pragma unroll
    for (int off = 1; off < 64; off <<= 1) {
        unsigned int u = __shfl_up(sc, off);
        if (lane >= off) sc += u;
    }
    if (lane == 63) swave[w] = sc;
    __syncthreads();
    unsigned int woff = 0;
    for (int k = 0; k < w; ++k) woff += swave[k];
    lbase[i0]     = (int)(woff + sc - sum);
    lbase[i0 + 1] = (int)(woff + sc - sum + a);
    __syncthreads();

    // phase 2: reserve dense global segments inside fixed-capacity regions
    for (int bb = t; bb < NBUK; bb += 256) {
        unsigned int c = lh[bb];
        int g = bb * cap + (c ? atomicAdd(&bcur[bb * PAD], (int)c) : 0);
        gbase[bb] = g;
        lh[bb] = (unsigned int)g;
    }
    __syncthreads();

    // phase 3a: scatter into LDS by rank (from registers)
    #pragma unroll
    for (int k = 0; k < 16; ++k) {
        int e = base + k * 256 + t;
        if (e < end) {
            int bb = cl[k] >> BSHIFT;
            int gpos = (int)atomicAdd(&lh[bb], 1u);
            int lslot = gpos - gbase[bb] + lbase[bb];
            lpair[lslot] = ((unsigned int)(cl[k] & CMASK) << 24) | (unsigned int)rw[k];
            lbuk[lslot] = (unsigned short)bb;
        }
    }
    __syncthreads();

    // phase 3b: linear LDS -> coalesced global segment writes
    int tilesz = end - base;
    for (int j = t; j < tilesz; j += 256) {
        int bb = lbuk[j];
        buf[gbase[bb] + (j - lbase[bb])] = lpair[j];
    }
}

// ---------- per-bucket fine counting sort, LDS-staged, in place, 8-padded ----------
__global__ void k_csort(unsigned int* __restrict__ buf, const int* __restrict__ bcur,
                        int* __restrict__ row_ptr, unsigned int* __restrict__ count,
                        int cap, int N) {
    __shared__ unsigned int lp[LCAP];
    __shared__ unsigned int lh[CPB];
    __shared__ int lofs[CPB];
    __shared__ unsigned int swave[4];
    int b = blockIdx.x;
    int t = threadIdx.x;
    int w = t >> 6, lane = t & 63;
    int c0 = b << BSHIFT;
    int s = b * cap;
    int cntb = bcur[b * PAD];
    lh[t] = 0u;
    __syncthreads();
    for (int j = t; j < cntb; j += 256) {
        unsigned int u = buf[s + j];
        lp[j] = u;
        atomicAdd(&lh[u >> 24], 1u);
    }
    __syncthreads();
    unsigned int v = lh[t];
    unsigned int pv = (v + 7u) & ~7u;       // pad each col segment to multiple of 8
    unsigned int sc = pv;
    #pragma unroll
    for (int off = 1; off < 64; off <<= 1) {
        unsigned int u = __shfl_up(sc, off);
        if (lane >= off) sc += u;
    }
    if (lane == 63) swave[w] = sc;
    __syncthreads();
    unsigned int woff = 0;
    for (int k = 0; k < w; ++k) woff += swave[k];
    int excl = s + (int)(woff + sc - pv);
    if (c0 + t < N) {
        row_ptr[c0 + t] = excl;
        count[c0 + t] = v;
    }
    lofs[t] = excl;
    __syncthreads();
    // scatter from LDS back to global (in place; staged so safe)
    for (int j = t; j < cntb; j += 256) {
        unsigned int u = lp[j];
        int pos = atomicAdd(&lofs[u >> 24], 1);
        buf[pos] = u & 0x00FFFFFFu;
    }
    // pad fill: dummy index N (zero triple / zero y)
    for (unsigned int k = v; k < pv; ++k) buf[excl + k] = (unsigned int)N;
}

// ================= compute pipeline (all f32) =================

// dinv = rsqrt(deg+1); y = dinv*x; also zero pad slots y[N], triple[N]
__global__ void k_prep(const float* __restrict__ x, const unsigned int* __restrict__ count,
                       float* __restrict__ dinv, float2* __restrict__ y,
                       float4* __restrict__ triple, int N) {
    int i = blockIdx.x * blockDim.x + threadIdx.x;
    if (i == 0) {
        y[N] = make_float2(0.0f, 0.0f);
        triple[N] = make_float4(0.0f, 0.0f, 0.0f, 0.0f);
    }
    if (i >= N) return;
    float dv = rsqrtf((float)count[i] + 1.0f);
    dinv[i] = dv;
    float2 xv = ((const float2*)x)[i];
    y[i] = make_float2(dv * xv.x, dv * xv.y);
}

// layer-1 aggregation in input space: triple[i] = (dv*zx, dv*zy, dv)
__global__ void k_agg1(const int* __restrict__ row_ptr, const unsigned int* __restrict__ count,
                       const int* __restrict__ sorted_row, const float2* __restrict__ y,
                       const float* __restrict__ dinv, float4* __restrict__ triple, int N) {
    int t = threadIdx.x;
    int i = blockIdx.x * 16 + (t >> 4), l = t & 15;
    if (i >= N) return;
    int s = row_ptr[i];
    int e = s + (int)count[i];
    float zx = 0.0f, zy = 0.0f;
    for (int j = s + l; j < e; j += 16) {
        float2 yv = y[sorted_row[j]];
        zx += yv.x; zy += yv.y;
    }
    #pragma unroll
    for (int m = 8; m >= 1; m >>= 1) {
        zx += __shfl_xor(zx, m);
        zy += __shfl_xor(zy, m);
    }
    if (l == 0) {
        float2 yi = y[i];                  // self loop
        zx += yi.x; zy += yi.y;
        float dv = dinv[i];
        triple[i] = make_float4(dv * zx, dv * zy, dv, 0.0f);
    }
}

__device__ __forceinline__ float2 f2fma(float s, float2 m, float2 a) {
    return make_float2(fmaf(s, m.x, a.x), fmaf(s, m.y, a.y));
}

// layer-2 agg + pool: u_r recomputed from triple_r (L2-resident); packed f32 math,
// unroll 8 with aligned int4 index loads (segments padded to 8, pad idx -> zero triple).
__global__ void __launch_bounds__(256)
k_agg_pool(const int* __restrict__ row_ptr, const unsigned int* __restrict__ count,
           const int* __restrict__ sorted_row, const float4* __restrict__ triple,
           const float* __restrict__ W1, const float* __restrict__ b1,
           const int* __restrict__ batch, float* __restrict__ pool,
           float* __restrict__ cnt, int N) {
    __shared__ float sh[16][FDIM];
    __shared__ int sb[16];
    int t = threadIdx.x;
    int n = t >> 4, f2 = t & 15;
    int i = blockIdx.x * 16 + n;
    int fa = 2 * f2;
    float2 w0 = *(const float2*)(W1 + fa);
    float2 w1 = *(const float2*)(W1 + FDIM + fa);
    float2 bb = *(const float2*)(b1 + fa);
    float2 acc = make_float2(0.0f, 0.0f);
    int bt = -1;
    if (i < N) {
        float4 ts = triple[i];              // self
        float dv = ts.z;
        {
            float2 q = f2fma(ts.x, w0, f2fma(ts.y, w1, bb));
            q.x = fmaxf(q.x, 0.0f); q.y = fmaxf(q.y, 0.0f);
            acc = f2fma(ts.z, q, acc);
        }
        int s = row_ptr[i];
        int pv = ((int)count[i] + 7) & ~7;
        for (int j = s; j < s + pv; j += 8) {
            int4 ra = *(const int4*)(sorted_row + j);
            int4 rb = *(const int4*)(sorted_row + j + 4);
            float4 t0 = triple[ra.x], t1 = triple[ra.y], t2 = triple[ra.z], t3 = triple[ra.w];
            float4 t4 = triple[rb.x], t5 = triple[rb.y], t6 = triple[rb.z], t7 = triple[rb.w];
            float2 q;
            q = f2fma(t0.x, w0, f2fma(t0.y, w1, bb)); q.x = fmaxf(q.x, 0.f); q.y = fmaxf(q.y, 0.f); acc = f2fma(t0.z, q, acc);
            q = f2fma(t1.x, w0, f2fma(t1.y, w1, bb)); q.x = fmaxf(q.x, 0.f); q.y = fmaxf(q.y, 0.f); acc = f2fma(t1.z, q, acc);
            q = f2fma(t2.x, w0, f2fma(t2.y, w1, bb)); q.x = fmaxf(q.x, 0.f); q.y = fmaxf(q.y, 0.f); acc = f2fma(t2.z, q, acc);
            q = f2fma(t3.x, w0, f2fma(t3.y, w1, bb)); q.x = fmaxf(q.x, 0.f); q.y = fmaxf(q.y, 0.f); acc = f2fma(t3.z, q, acc);
            q = f2fma(t4.x, w0, f2fma(t4.y, w1, bb)); q.x = fmaxf(q.x, 0.f); q.y = fmaxf(q.y, 0.f); acc = f2fma(t4.z, q, acc);
            q = f2fma(t5.x, w0, f2fma(t5.y, w1, bb)); q.x = fmaxf(q.x, 0.f); q.y = fmaxf(q.y, 0.f); acc = f2fma(t5.z, q, acc);
            q = f2fma(t6.x, w0, f2fma(t6.y, w1, bb)); q.x = fmaxf(q.x, 0.f); q.y = fmaxf(q.y, 0.f); acc = f2fma(t6.z, q, acc);
            q = f2fma(t7.x, w0, f2fma(t7.y, w1, bb)); q.x = fmaxf(q.x, 0.f); q.y = fmaxf(q.y, 0.f); acc = f2fma(t7.z, q, acc);
        }
        float dv2 = dv;
        acc.x *= dv2; acc.y *= dv2;         // w = dinv * v_pre (bias+W2 hoisted to k_out)
        bt = batch[i];
    }
    sh[n][fa]     = acc.x;
    sh[n][fa + 1] = acc.y;
    if (f2 == 0) sb[n] = bt;
    __syncthreads();
    if (bt >= 0 && (n == 0 || sb[n - 1] != bt)) {   // segment leader
        float s0 = acc.x, s1 = acc.y;
        int m = n + 1;
        for (; m < 16 && sb[m] == bt; ++m) {
            s0 += sh[m][fa];
            s1 += sh[m][fa + 1];
        }
        atomicAdd(&pool[bt * FDIM + fa],     s0);
        atomicAdd(&pool[bt * FDIM + fa + 1], s1);
        if (f2 == 0) atomicAdd(&cnt[bt], (float)(m - n));
    }
}

// out[g] = (pool[g]/cnt[g]) @ W2 + b2   (8 graphs/WG)
__global__ void k_out(const float* __restrict__ pool, const float* __restrict__ cnt,
                      const float* __restrict__ W2, const float* __restrict__ b2,
                      float* __restrict__ out, int G) {
    __shared__ float sW[FDIM * FDIM];
    int t = threadIdx.x;
    for (int k = t; k < FDIM * FDIM; k += 256) sW[k] = W2[k];
    __syncthreads();
    int g = blockIdx.x * 8 + (t >> 5), f = t & 31;
    if (g >= G) return;
    float c = cnt[g];
    float o = 0.0f;
    if (c > 0.0f) {
        float s = 0.0f;
        #pragma unroll
        for (int k = 0; k < FDIM; ++k) s = fmaf(pool[g * FDIM + k], sW[k * FDIM + f], s);
        o = fmaf(s, 1.0f / c, b2[f]);
    }
    out[g * FDIM + f] = o;
}

// ================= compact correct-but-slow fallback (atomic path) =================

__global__ void k_fhist(const int* __restrict__ col, unsigned int* __restrict__ count, int E) {
    int i = blockIdx.x * blockDim.x + threadIdx.x;
    if (i < E) atomicAdd(&count[col[i]], 1u);
}
__global__ void k_fsc2(const int* __restrict__ row, const int* __restrict__ col,
                       const float2* __restrict__ y, float* __restrict__ z, int E) {
    int e = blockIdx.x * blockDim.x + threadIdx.x;
    if (e >= E) return;
    float2 yv = y[row[e]];
    int c = col[e];
    atomicAdd(&z[2 * c],     yv.x);
    atomicAdd(&z[2 * c + 1], yv.y);
}
__global__ void k_fmkt(const float* __restrict__ z, const float2* __restrict__ y,
                       const float* __restrict__ dinv, float4* __restrict__ triple, int N) {
    int i = blockIdx.x * blockDim.x + threadIdx.x;
    if (i >= N) return;
    float dv = dinv[i];
    float2 yi = y[i];
    triple[i] = make_float4(dv * (z[2 * i] + yi.x), dv * (z[2 * i + 1] + yi.y), dv, 0.0f);
}
__global__ void k_fsc32(const int* __restrict__ row, const int* __restrict__ col,
                        const float4* __restrict__ triple, const float* __restrict__ W1,
                        const float* __restrict__ b1, float* __restrict__ v, int total) {
    int idx = blockIdx.x * blockDim.x + threadIdx.x;
    if (idx >= total) return;
    int e = idx >> 5, f = idx & 31;
    float4 tr = triple[row[e]];
    float u = tr.z * fmaxf(fmaf(tr.x, W1[f], fmaf(tr.y, W1[FDIM + f], b1[f])), 0.0f);
    atomicAdd(&v[col[e] * FDIM + f], u);
}
__global__ void k_ffin(const float4* __restrict__ triple, const float* __restrict__ v,
                       const float* __restrict__ W1, const float* __restrict__ b1,
                       const int* __restrict__ batch, float* __restrict__ pool,
                       float* __restrict__ cnt, int N) {
    int idx = blockIdx.x * blockDim.x + threadIdx.x;
    int i = idx >> 5, f = idx & 31;
    if (i >= N) return;
    float4 tr = triple[i];
    float u = tr.z * fmaxf(fmaf(tr.x, W1[f], fmaf(tr.y, W1[FDIM + f], b1[f])), 0.0f);
    float w = tr.z * (u + v[i * FDIM + f]);
    int b = batch[i];
    atomicAdd(&pool[b * FDIM + f], w);
    if (f == 0) atomicAdd(&cnt[b], 1.0f);
}

extern "C" void kernel_launch(void* const* d_in, const int* in_sizes, int n_in,
                              void* d_out, int out_size, void* d_ws, size_t ws_size,
                              hipStream_t stream) {
    const float* x   = (const float*)d_in[0];
    const int*   ei  = (const int*)d_in[1];
    const int* batch = (const int*)d_in[2];
    const float* W1  = (const float*)d_in[4];
    const float* b1  = (const float*)d_in[5];
    const float* W2  = (const float*)d_in[6];
    const float* b2  = (const float*)d_in[7];
    float* out = (float*)d_out;

    int N = in_sizes[0] / 2;
    int E = in_sizes[1] / 2;
    int G = out_size / FDIM;

    const int* row = ei;
    const int* col = ei + E;

    int NB = (N + 255) / 256;
    int NBUK = (N + CMASK) >> BSHIFT;

    // fixed bucket capacity: avg + 12.5% + 2048, rounded to 8
    int capBase = (E + NBUK - 1) / NBUK;
    int cap = capBase + capBase / 8 + 2048;
    cap = (cap + 7) & ~7;

    // primary layout (u32 units)
    size_t off = 0;
    size_t o_bcur = off;  off += (size_t)NBUK * PAD;
    size_t o_cnt  = off;  off += N;           // count
    size_t o_rp   = off;  off += N;           // row_ptr
    size_t o_dv   = off;  off += N;           // dinv
    size_t o_y    = off;  off += 2ull * (N + 1);
    off = (off + 3) & ~(size_t)3;             // 16B align
    size_t o_tr   = off;  off += 4ull * (N + 1);
    size_t o_buf  = off;  off += (size_t)NBUK * cap;
    size_t o_pool = off;  off += 32ull * G;
    size_t o_cg   = off;  off += G;
    size_t elemsNew = off;

    unsigned int* W = (unsigned int*)d_ws;

    if (ws_size >= elemsNew * 4 && N < (1 << 24) && NBUK <= MAXBUK && cap <= LCAP) {
        int* bcur           = (int*)(W + o_bcur);
        unsigned int* count = (unsigned int*)(W + o_cnt);
        int* row_ptr        = (int*)(W + o_rp);
        float* dinv         = (float*)(W + o_dv);
        float2* y           = (float2*)(W + o_y);
        float4* triple      = (float4*)(W + o_tr);
        unsigned int* buf   = W + o_buf;      // pairs, then sorted_row in place
        float* pool         = (float*)(W + o_pool);
        float* cntg         = (float*)(W + o_cg);

        hipMemsetAsync(bcur, 0, (size_t)NBUK * PAD * 4, stream);
        hipMemsetAsync(pool, 0, (size_t)(G * FDIM + G) * 4, stream);

        k_binsort<<<(E + BNT - 1) / BNT, 256, 0, stream>>>(row, col, bcur, buf, E, cap, NBUK);
        k_csort<<<NBUK, 256, 0, stream>>>(buf, bcur, row_ptr, count, cap, N);

        k_prep<<<NB, 256, 0, stream>>>(x, count, dinv, y, triple, N);
        k_agg1<<<(N + 15) / 16, 256, 0, stream>>>(row_ptr, count, (const int*)buf, y, dinv,
                                                  triple, N);
        k_agg_pool<<<(N + 15) / 16, 256, 0, stream>>>(row_ptr, count, (const int*)buf, triple,
                                                      W1, b1, batch, pool, cntg, N);
        k_out<<<(G + 7) / 8, 256, 0, stream>>>(pool, cntg, W2, b2, out, G);
    } else {
        // compact fallback: atomic scatter (correct, slow; not expected to run)
        unsigned int* count = (unsigned int*)d_ws;             // N
        float* dinv         = (float*)(count + N);             // N
        float2* y           = (float2*)(dinv + N);             // N+1
        float* z            = (float*)(y + N + 1);             // 2N
        size_t toff = ((size_t)(z + 2 * N - (float*)d_ws) + 3) & ~(size_t)3;
        float4* triple      = (float4*)((float*)d_ws + toff);  // N+1
        float* v            = (float*)(triple + N + 1);        // 32N
        float* pool         = v + 32ull * N;                   // 32G
        float* cntg         = pool + 32ull * G;                // G

        hipMemsetAsync(count, 0, (size_t)N * 4, stream);
        hipMemsetAsync(z, 0, (size_t)N * 8, stream);
        hipMemsetAsync(v, 0, (size_t)N * FDIM * 4, stream);
        hipMemsetAsync(pool, 0, (size_t)(G * FDIM + G) * 4, stream);

        k_fhist<<<(E + 255) / 256, 256, 0, stream>>>(col, count, E);
        k_prep<<<NB, 256, 0, stream>>>(x, count, dinv, y, triple, N);
        k_fsc2<<<(E + 255) / 256, 256, 0, stream>>>(row, col, y, z, E);
        k_fmkt<<<NB, 256, 0, stream>>>(z, y, dinv, triple, N);
        int ts = E * FDIM;
        k_fsc32<<<(ts + 255) / 256, 256, 0, stream>>>(row, col, triple, W1, b1, v, ts);
        k_ffin<<<(N * FDIM + 255) / 256, 256, 0, stream>>>(triple, v, W1, b1, batch, pool, cntg, N);
        k_out<<<(G + 7) / 8, 256, 0, stream>>>(pool, cntg, W2, b2, out, G);
    }
}

// Round 13
// 132.959 us; speedup vs baseline: 18.6568x; 1.1345x over previous
//
#include <hip/hip_runtime.h>

#define FDIM 32
#define BSHIFT 8                 // 256 cols per bucket
#define CPB (1 << BSHIFT)
#define CMASK (CPB - 1)
#define PAD 16                   // cursor stride: 16 u32 = 64B (one cacheline)
#define MAXBUK 512
#define BNT 4096                 // binsort tile (edges per WG, 16/thread)
#define LCAP 12288               // csort LDS staging capacity (48 KB)

// ---------- LDS-staged binning into fixed-capacity bucket regions ----------
// pack: (col & 255) << 24 | row   (needs N < 2^24)
__global__ void k_binsort(const int* __restrict__ row, const int* __restrict__ col,
                          int* bcur, unsigned int* __restrict__ buf, int E, int cap, int NBUK) {
    __shared__ unsigned int lh[MAXBUK];      // hist -> global cursor
    __shared__ int lbase[MAXBUK];            // local exclusive base
    __shared__ int gbase[MAXBUK];            // global segment base
    __shared__ unsigned int swave[4];
    __shared__ unsigned int lpair[BNT];      // staged packed pairs (rank order)
    __shared__ unsigned short lbuk[BNT];     // bucket id per staged entry
    int t = threadIdx.x;
    int w = t >> 6, lane = t & 63;
    int base = blockIdx.x * BNT;
    int end = min(base + BNT, E);
    int E4 = E >> 2;                         // edges coverable by int4

    lh[t] = 0u; lh[t + 256] = 0u;
    __syncthreads();

    // phase 1: tile histogram; int4-vectorized (col,row) loads cached in registers.
    int cl[16], rw[16];
    #pragma unroll
    for (int k = 0; k < 4; ++k) {
        int e4 = (base >> 2) + k * 256 + t;       // edge block [4*e4, 4*e4+4)
        int eb = 4 * e4;
        if (eb + 3 < end) {
            int4 c4 = *(const int4*)(col + eb);
            int4 r4 = *(const int4*)(row + eb);
            cl[4*k] = c4.x; cl[4*k+1] = c4.y; cl[4*k+2] = c4.z; cl[4*k+3] = c4.w;
            rw[4*k] = r4.x; rw[4*k+1] = r4.y; rw[4*k+2] = r4.z; rw[4*k+3] = r4.w;
            atomicAdd(&lh[c4.x >> BSHIFT], 1u);
            atomicAdd(&lh[c4.y >> BSHIFT], 1u);
            atomicAdd(&lh[c4.z >> BSHIFT], 1u);
            atomicAdd(&lh[c4.w >> BSHIFT], 1u);
        } else {
            #pragma unroll
            for (int q = 0; q < 4; ++q) {
                int e = eb + q;
                if (e < end) {
                    cl[4*k+q] = col[e];
                    rw[4*k+q] = row[e];
                    atomicAdd(&lh[cl[4*k+q] >> BSHIFT], 1u);
                } else cl[4*k+q] = -1;
            }
        }
    }
    __syncthreads();

    // wave-shuffle exclusive scan of lh[0..512) -> lbase
    int i0 = w * 128 + lane * 2;
    unsigned int a = lh[i0], b = lh[i0 + 1];
    unsigned int sum = a + b;
    unsigned int sc = sum;
    #pragma unroll
    for (int off = 1; off < 64; off <<= 1) {
        unsigned int u = __shfl_up(sc, off);
        if (lane >= off) sc += u;
    }
    if (lane == 63) swave[w] = sc;
    __syncthreads();
    unsigned int woff = 0;
    for (int k = 0; k < w; ++k) woff += swave[k];
    lbase[i0]     = (int)(woff + sc - sum);
    lbase[i0 + 1] = (int)(woff + sc - sum + a);
    __syncthreads();

    // phase 2: reserve dense global segments inside fixed-capacity regions
    for (int bb = t; bb < NBUK; bb += 256) {
        unsigned int c = lh[bb];
        int g = bb * cap + (c ? atomicAdd(&bcur[bb * PAD], (int)c) : 0);
        gbase[bb] = g;
        lh[bb] = (unsigned int)g;
    }
    __syncthreads();

    // phase 3a: scatter into LDS by rank (from registers)
    #pragma unroll
    for (int k = 0; k < 16; ++k) {
        if (cl[k] >= 0) {
            int bb = cl[k] >> BSHIFT;
            int gpos = (int)atomicAdd(&lh[bb], 1u);
            int lslot = gpos - gbase[bb] + lbase[bb];
            lpair[lslot] = ((unsigned int)(cl[k] & CMASK) << 24) | (unsigned int)rw[k];
            lbuk[lslot] = (unsigned short)bb;
        }
    }
    __syncthreads();

    // phase 3b: linear LDS -> coalesced global segment writes
    int tilesz = end - base;
    for (int j = t; j < tilesz; j += 256) {
        int bb = lbuk[j];
        buf[gbase[bb] + (j - lbase[bb])] = lpair[j];
    }
    (void)E4;
}

// ---------- per-bucket fine sort (in place, 8-padded) + fused node prep ----------
__global__ void k_csort(unsigned int* __restrict__ buf, const int* __restrict__ bcur,
                        int* __restrict__ row_ptr, unsigned int* __restrict__ count,
                        const float* __restrict__ x, float* __restrict__ dinv,
                        float2* __restrict__ y, float4* __restrict__ triple,
                        int cap, int N) {
    __shared__ unsigned int lp[LCAP];
    __shared__ unsigned int lh[CPB];
    __shared__ int lofs[CPB];
    __shared__ unsigned int swave[4];
    int b = blockIdx.x;
    int t = threadIdx.x;
    int w = t >> 6, lane = t & 63;
    int c0 = b << BSHIFT;
    int s = b * cap;
    int cntb = bcur[b * PAD];
    lh[t] = 0u;
    if (b == 0 && t == 0) {                  // zero pad slots
        y[N] = make_float2(0.0f, 0.0f);
        triple[N] = make_float4(0.0f, 0.0f, 0.0f, 0.0f);
    }
    __syncthreads();
    for (int j = t; j < cntb; j += 256) {
        unsigned int u = buf[s + j];
        lp[j] = u;
        atomicAdd(&lh[u >> 24], 1u);
    }
    __syncthreads();
    unsigned int v = lh[t];
    unsigned int pv = (v + 7u) & ~7u;       // pad each col segment to multiple of 8
    unsigned int sc = pv;
    #pragma unroll
    for (int off = 1; off < 64; off <<= 1) {
        unsigned int u = __shfl_up(sc, off);
        if (lane >= off) sc += u;
    }
    if (lane == 63) swave[w] = sc;
    __syncthreads();
    unsigned int woff = 0;
    for (int k = 0; k < w; ++k) woff += swave[k];
    int excl = s + (int)(woff + sc - pv);
    int c = c0 + t;
    if (c < N) {
        row_ptr[c] = excl;
        count[c] = v;
        // fused prep: dinv = rsqrt(deg+1); y = dinv * x
        float dv = rsqrtf((float)v + 1.0f);
        dinv[c] = dv;
        float2 xv = ((const float2*)x)[c];
        y[c] = make_float2(dv * xv.x, dv * xv.y);
    }
    lofs[t] = excl;
    __syncthreads();
    for (int j = t; j < cntb; j += 256) {
        unsigned int u = lp[j];
        int pos = atomicAdd(&lofs[u >> 24], 1);
        buf[pos] = u & 0x00FFFFFFu;
    }
    for (unsigned int k = v; k < pv; ++k) buf[excl + k] = (unsigned int)N;
}

// ================= compute pipeline (all f32) =================

// fallback-only prep
__global__ void k_prep(const float* __restrict__ x, const unsigned int* __restrict__ count,
                       float* __restrict__ dinv, float2* __restrict__ y,
                       float4* __restrict__ triple, int N) {
    int i = blockIdx.x * blockDim.x + threadIdx.x;
    if (i == 0) {
        y[N] = make_float2(0.0f, 0.0f);
        triple[N] = make_float4(0.0f, 0.0f, 0.0f, 0.0f);
    }
    if (i >= N) return;
    float dv = rsqrtf((float)count[i] + 1.0f);
    dinv[i] = dv;
    float2 xv = ((const float2*)x)[i];
    y[i] = make_float2(dv * xv.x, dv * xv.y);
}

// layer-1 aggregation in input space: triple[i] = (dv*zx, dv*zy, dv); 8 lanes/node
__global__ void k_agg1(const int* __restrict__ row_ptr, const unsigned int* __restrict__ count,
                       const int* __restrict__ sorted_row, const float2* __restrict__ y,
                       const float* __restrict__ dinv, float4* __restrict__ triple, int N) {
    int t = threadIdx.x;
    int i = blockIdx.x * 32 + (t >> 3), l = t & 7;
    if (i >= N) return;
    int s = row_ptr[i];
    int e = s + (int)count[i];
    float zx = 0.0f, zy = 0.0f;
    for (int j = s + l; j < e; j += 8) {
        float2 yv = y[sorted_row[j]];
        zx += yv.x; zy += yv.y;
    }
    #pragma unroll
    for (int m = 4; m >= 1; m >>= 1) {
        zx += __shfl_xor(zx, m);
        zy += __shfl_xor(zy, m);
    }
    if (l == 0) {
        float2 yi = y[i];                  // self loop
        zx += yi.x; zy += yi.y;
        float dv = dinv[i];
        triple[i] = make_float4(dv * zx, dv * zy, dv, 0.0f);
    }
}

__device__ __forceinline__ float4 f4fma(float s, float4 m, float4 a) {
    return make_float4(fmaf(s, m.x, a.x), fmaf(s, m.y, a.y),
                       fmaf(s, m.z, a.z), fmaf(s, m.w, a.w));
}
__device__ __forceinline__ float4 f4relu(float4 q) {
    return make_float4(fmaxf(q.x, 0.f), fmaxf(q.y, 0.f), fmaxf(q.z, 0.f), fmaxf(q.w, 0.f));
}

// layer-2 agg + pool: 8 lanes/node (4 features/lane as float4), unroll 8.
__global__ void __launch_bounds__(256)
k_agg_pool(const int* __restrict__ row_ptr, const unsigned int* __restrict__ count,
           const int* __restrict__ sorted_row, const float4* __restrict__ triple,
           const float* __restrict__ W1, const float* __restrict__ b1,
           const int* __restrict__ batch, float* __restrict__ pool,
           float* __restrict__ cnt, int N) {
    __shared__ float sh[32][FDIM];
    __shared__ int sb[32];
    int t = threadIdx.x;
    int n = t >> 3, l = t & 7;
    int i = blockIdx.x * 32 + n;
    int fa = 4 * l;
    float4 w0 = *(const float4*)(W1 + fa);
    float4 w1 = *(const float4*)(W1 + FDIM + fa);
    float4 bb = *(const float4*)(b1 + fa);
    float4 acc = make_float4(0.f, 0.f, 0.f, 0.f);
    int bt = -1;
    if (i < N) {
        float4 ts = triple[i];              // self
        float dv = ts.z;
        acc = f4fma(ts.z, f4relu(f4fma(ts.x, w0, f4fma(ts.y, w1, bb))), acc);
        int s = row_ptr[i];
        int pv = ((int)count[i] + 7) & ~7;
        for (int j = s; j < s + pv; j += 8) {
            int4 ra = *(const int4*)(sorted_row + j);
            int4 rb = *(const int4*)(sorted_row + j + 4);
            float4 t0 = triple[ra.x], t1 = triple[ra.y], t2 = triple[ra.z], t3 = triple[ra.w];
            float4 t4 = triple[rb.x], t5 = triple[rb.y], t6 = triple[rb.z], t7 = triple[rb.w];
            acc = f4fma(t0.z, f4relu(f4fma(t0.x, w0, f4fma(t0.y, w1, bb))), acc);
            acc = f4fma(t1.z, f4relu(f4fma(t1.x, w0, f4fma(t1.y, w1, bb))), acc);
            acc = f4fma(t2.z, f4relu(f4fma(t2.x, w0, f4fma(t2.y, w1, bb))), acc);
            acc = f4fma(t3.z, f4relu(f4fma(t3.x, w0, f4fma(t3.y, w1, bb))), acc);
            acc = f4fma(t4.z, f4relu(f4fma(t4.x, w0, f4fma(t4.y, w1, bb))), acc);
            acc = f4fma(t5.z, f4relu(f4fma(t5.x, w0, f4fma(t5.y, w1, bb))), acc);
            acc = f4fma(t6.z, f4relu(f4fma(t6.x, w0, f4fma(t6.y, w1, bb))), acc);
            acc = f4fma(t7.z, f4relu(f4fma(t7.x, w0, f4fma(t7.y, w1, bb))), acc);
        }
        acc.x *= dv; acc.y *= dv; acc.z *= dv; acc.w *= dv;
        bt = batch[i];
    }
    *(float4*)&sh[n][fa] = acc;
    if (l == 0) sb[n] = bt;
    __syncthreads();
    if (bt >= 0 && (n == 0 || sb[n - 1] != bt)) {   // segment leader
        float4 ssum = acc;
        int m = n + 1;
        for (; m < 32 && sb[m] == bt; ++m) {
            float4 o = *(const float4*)&sh[m][fa];
            ssum.x += o.x; ssum.y += o.y; ssum.z += o.z; ssum.w += o.w;
        }
        atomicAdd(&pool[bt * FDIM + fa],     ssum.x);
        atomicAdd(&pool[bt * FDIM + fa + 1], ssum.y);
        atomicAdd(&pool[bt * FDIM + fa + 2], ssum.z);
        atomicAdd(&pool[bt * FDIM + fa + 3], ssum.w);
        if (l == 0) atomicAdd(&cnt[bt], (float)(m - n));
    }
}

// out[g] = (pool[g]/cnt[g]) @ W2 + b2   (8 graphs/WG)
__global__ void k_out(const float* __restrict__ pool, const float* __restrict__ cnt,
                      const float* __restrict__ W2, const float* __restrict__ b2,
                      float* __restrict__ out, int G) {
    __shared__ float sW[FDIM * FDIM];
    int t = threadIdx.x;
    for (int k = t; k < FDIM * FDIM; k += 256) sW[k] = W2[k];
    __syncthreads();
    int g = blockIdx.x * 8 + (t >> 5), f = t & 31;
    if (g >= G) return;
    float c = cnt[g];
    float o = 0.0f;
    if (c > 0.0f) {
        float s = 0.0f;
        #pragma unroll
        for (int k = 0; k < FDIM; ++k) s = fmaf(pool[g * FDIM + k], sW[k * FDIM + f], s);
        o = fmaf(s, 1.0f / c, b2[f]);
    }
    out[g * FDIM + f] = o;
}

// ================= compact correct-but-slow fallback (atomic path) =================

__global__ void k_fhist(const int* __restrict__ col, unsigned int* __restrict__ count, int E) {
    int i = blockIdx.x * blockDim.x + threadIdx.x;
    if (i < E) atomicAdd(&count[col[i]], 1u);
}
__global__ void k_fsc2(const int* __restrict__ row, const int* __restrict__ col,
                       const float2* __restrict__ y, float* __restrict__ z, int E) {
    int e = blockIdx.x * blockDim.x + threadIdx.x;
    if (e >= E) return;
    float2 yv = y[row[e]];
    int c = col[e];
    atomicAdd(&z[2 * c],     yv.x);
    atomicAdd(&z[2 * c + 1], yv.y);
}
__global__ void k_fmkt(const float* __restrict__ z, const float2* __restrict__ y,
                       const float* __restrict__ dinv, float4* __restrict__ triple, int N) {
    int i = blockIdx.x * blockDim.x + threadIdx.x;
    if (i >= N) return;
    float dv = dinv[i];
    float2 yi = y[i];
    triple[i] = make_float4(dv * (z[2 * i] + yi.x), dv * (z[2 * i + 1] + yi.y), dv, 0.0f);
}
__global__ void k_fsc32(const int* __restrict__ row, const int* __restrict__ col,
                        const float4* __restrict__ triple, const float* __restrict__ W1,
                        const float* __restrict__ b1, float* __restrict__ v, int total) {
    int idx = blockIdx.x * blockDim.x + threadIdx.x;
    if (idx >= total) return;
    int e = idx >> 5, f = idx & 31;
    float4 tr = triple[row[e]];
    float u = tr.z * fmaxf(fmaf(tr.x, W1[f], fmaf(tr.y, W1[FDIM + f], b1[f])), 0.0f);
    atomicAdd(&v[col[e] * FDIM + f], u);
}
__global__ void k_ffin(const float4* __restrict__ triple, const float* __restrict__ v,
                       const float* __restrict__ W1, const float* __restrict__ b1,
                       const int* __restrict__ batch, float* __restrict__ pool,
                       float* __restrict__ cnt, int N) {
    int idx = blockIdx.x * blockDim.x + threadIdx.x;
    int i = idx >> 5, f = idx & 31;
    if (i >= N) return;
    float4 tr = triple[i];
    float u = tr.z * fmaxf(fmaf(tr.x, W1[f], fmaf(tr.y, W1[FDIM + f], b1[f])), 0.0f);
    float w = tr.z * (u + v[i * FDIM + f]);
    int b = batch[i];
    atomicAdd(&pool[b * FDIM + f], w);
    if (f == 0) atomicAdd(&cnt[b], 1.0f);
}

extern "C" void kernel_launch(void* const* d_in, const int* in_sizes, int n_in,
                              void* d_out, int out_size, void* d_ws, size_t ws_size,
                              hipStream_t stream) {
    const float* x   = (const float*)d_in[0];
    const int*   ei  = (const int*)d_in[1];
    const int* batch = (const int*)d_in[2];
    const float* W1  = (const float*)d_in[4];
    const float* b1  = (const float*)d_in[5];
    const float* W2  = (const float*)d_in[6];
    const float* b2  = (const float*)d_in[7];
    float* out = (float*)d_out;

    int N = in_sizes[0] / 2;
    int E = in_sizes[1] / 2;
    int G = out_size / FDIM;

    const int* row = ei;
    const int* col = ei + E;

    int NB = (N + 255) / 256;
    int NBUK = (N + CMASK) >> BSHIFT;

    // fixed bucket capacity: avg + 12.5% + 2048, rounded to 8
    int capBase = (E + NBUK - 1) / NBUK;
    int cap = capBase + capBase / 8 + 2048;
    cap = (cap + 7) & ~7;

    // primary layout (u32 units)
    size_t off = 0;
    size_t o_bcur = off;  off += (size_t)NBUK * PAD;
    size_t o_cnt  = off;  off += N;           // count
    size_t o_rp   = off;  off += N;           // row_ptr
    size_t o_dv   = off;  off += N;           // dinv
    size_t o_y    = off;  off += 2ull * (N + 1);
    off = (off + 3) & ~(size_t)3;             // 16B align
    size_t o_tr   = off;  off += 4ull * (N + 1);
    size_t o_buf  = off;  off += (size_t)NBUK * cap;
    size_t o_pool = off;  off += 32ull * G;
    size_t o_cg   = off;  off += G;
    size_t elemsNew = off;

    unsigned int* W = (unsigned int*)d_ws;

    if (ws_size >= elemsNew * 4 && N < (1 << 24) && NBUK <= MAXBUK && cap <= LCAP) {
        int* bcur           = (int*)(W + o_bcur);
        unsigned int* count = (unsigned int*)(W + o_cnt);
        int* row_ptr        = (int*)(W + o_rp);
        float* dinv         = (float*)(W + o_dv);
        float2* y           = (float2*)(W + o_y);
        float4* triple      = (float4*)(W + o_tr);
        unsigned int* buf   = W + o_buf;      // pairs, then sorted_row in place
        float* pool         = (float*)(W + o_pool);
        float* cntg         = (float*)(W + o_cg);

        hipMemsetAsync(bcur, 0, (size_t)NBUK * PAD * 4, stream);
        hipMemsetAsync(pool, 0, (size_t)(G * FDIM + G) * 4, stream);

        k_binsort<<<(E + BNT - 1) / BNT, 256, 0, stream>>>(row, col, bcur, buf, E, cap, NBUK);
        k_csort<<<NBUK, 256, 0, stream>>>(buf, bcur, row_ptr, count, x, dinv, y, triple, cap, N);

        k_agg1<<<(N + 31) / 32, 256, 0, stream>>>(row_ptr, count, (const int*)buf, y, dinv,
                                                  triple, N);
        k_agg_pool<<<(N + 31) / 32, 256, 0, stream>>>(row_ptr, count, (const int*)buf, triple,
                                                      W1, b1, batch, pool, cntg, N);
        k_out<<<(G + 7) / 8, 256, 0, stream>>>(pool, cntg, W2, b2, out, G);
    } else {
        // compact fallback: atomic scatter (correct, slow; not expected to run)
        unsigned int* count = (unsigned int*)d_ws;             // N
        float* dinv         = (float*)(count + N);             // N
        float2* y           = (float2*)(dinv + N);             // N+1
        float* z            = (float*)(y + N + 1);             // 2N
        size_t toff = ((size_t)(z + 2 * N - (float*)d_ws) + 3) & ~(size_t)3;
        float4* triple      = (float4*)((float*)d_ws + toff);  // N+1
        float* v            = (float*)(triple + N + 1);        // 32N
        float* pool         = v + 32ull * N;                   // 32G
        float* cntg         = pool + 32ull * G;                // G

        hipMemsetAsync(count, 0, (size_t)N * 4, stream);
        hipMemsetAsync(z, 0, (size_t)N * 8, stream);
        hipMemsetAsync(v, 0, (size_t)N * FDIM * 4, stream);
        hipMemsetAsync(pool, 0, (size_t)(G * FDIM + G) * 4, stream);

        k_fhist<<<(E + 255) / 256, 256, 0, stream>>>(col, count, E);
        k_prep<<<NB, 256, 0, stream>>>(x, count, dinv, y, triple, N);
        k_fsc2<<<(E + 255) / 256, 256, 0, stream>>>(row, col, y, z, E);
        k_fmkt<<<NB, 256, 0, stream>>>(z, y, dinv, triple, N);
        int ts = E * FDIM;
        k_fsc32<<<(ts + 255) / 256, 256, 0, stream>>>(row, col, triple, W1, b1, v, ts);
        k_ffin<<<(N * FDIM + 255) / 256, 256, 0, stream>>>(triple, v, W1, b1, batch, pool, cntg, N);
        k_out<<<(G + 7) / 8, 256, 0, stream>>>(pool, cntg, W2, b2, out, G);
    }
}